// Round 11
// baseline (478.242 us; speedup 1.0000x reference)
//
#include <hip/hip_runtime.h>
#include <hip/hip_bf16.h>
#include <math.h>

// ---------------- problem constants ----------------
#define BATCH   32
#define LSEQ    512
#define ENC_IN  8
#define MARKD   4
#define DMODEL  512
#define DSTATE  16
#define DINNER  1024
#define DTRANK  32
#define PREDLEN 96
#define MROWS   (BATCH * LSEQ)          // 16384
#define TSTART  (LSEQ - PREDLEN)        // 416
#define NCHUNK  8                       // chunks over [0,416): 56,56,56,56,48,48,48,48

// ---------------- workspace layout (float units), total 107.5 MiB ----------------
#define OFF_XN    ((size_t)0)            // 131072
#define OFF_MEAN  ((size_t)131072)       // 256
#define OFF_STD   ((size_t)131328)       // 256
#define OFF_WF    ((size_t)131584)       // 1024
#define OFF_WBX   ((size_t)132608)       // x_proj_w bf16: 32768 f
#define OFF_DPWB  ((size_t)165376)       // dt_proj_w bf16: 16384 f
#define OFF_XB    ((size_t)919040)       // 16384x512 bf16 = 4194304 f (beta overlays)
#define OFF_WB    ((size_t)5113344)      // 2048x512 bf16 = 524288 f
#define OFF_DTIN  ((size_t)5637632)      // dt_in bf16 = 262144 f (wfp early, asum late)
#define OFF_BT    ((size_t)6161920)      // 32x16x512 fp32 = 262144 f
#define OFF_CT    ((size_t)6424064)      // 262144 f
#define OFF_GST   ((size_t)6686208)      // 32x1024x96 fp32 (g -> gw -> outputs in place)
#define OFF_XIT   ((size_t)9831936)      // [b][d][t] bf16 = 8388608 f (dtT overlays)
#define OFF_UT    ((size_t)18220544)     // [b][d][t] bf16 = 8388608 f
#define OFF_C0    ((size_t)26609152)     // 32x1024x96 bf16 = 1572864 f
#define OFF_DTT   OFF_XIT
#define OFF_BETA  OFF_XB                 // 32*1024*8*16 fp32 = 4194304 f exact fit
#define OFF_ASUM  OFF_DTIN               // 32*1024*8 fp32 = 262144 f exact fit
#define OFF_WFP   OFF_DTIN
// end: 28182016 floats = 107.5 MiB

typedef __bf16 bf16_8 __attribute__((ext_vector_type(8)));
typedef float  f32x4  __attribute__((ext_vector_type(4)));

#define EXP2F(x) __builtin_amdgcn_exp2f(x)
#define LOG2F(x) __builtin_amdgcn_logf(x)

typedef __attribute__((address_space(3))) unsigned lds_u32;
typedef const __attribute__((address_space(1))) unsigned glb_u32;
#define ASYNC_LDS16(gsrc, ldst) \
    __builtin_amdgcn_global_load_lds((glb_u32*)(gsrc), (lds_u32*)(ldst), 16, 0, 0)

static __device__ __forceinline__ float b2f(unsigned short h) {
    union { float f; unsigned u; } v; v.u = ((unsigned)h) << 16; return v.f;
}
static __device__ __forceinline__ unsigned short f2b(float f) {
    __hip_bfloat16 h = __float2bfloat16(f);   // RNE
    union { __hip_bfloat16 b; unsigned short s; } v; v.b = h; return v.s;
}
static __device__ __forceinline__ float blo(unsigned v) {
    union { float f; unsigned u; } x; x.u = v << 16; return x.f;
}
static __device__ __forceinline__ float bhi(unsigned v) {
    union { float f; unsigned u; } x; x.u = v & 0xffff0000u; return x.f;
}

// ============ k_front: fusew-partials | w2b x3 | norm ============
__global__ __launch_bounds__(256) void k_front(const float* __restrict__ opw,
                                               const float* __restrict__ ow,
                                               const float* __restrict__ in_proj_w,
                                               const float* __restrict__ x_proj_w,
                                               const float* __restrict__ dpw,
                                               const float* __restrict__ xe,
                                               float* __restrict__ wfp,
                                               unsigned short* __restrict__ wb,
                                               unsigned short* __restrict__ wbx,
                                               unsigned short* __restrict__ dpwb,
                                               float* __restrict__ xn,
                                               float* __restrict__ meanv,
                                               float* __restrict__ stdv) {
    int bid = blockIdx.x;
    int tid = threadIdx.x;
    if (bid < 16) {
        int q = bid >> 2;
        int i = (bid & 3) * 256 + tid;
        float acc = 0.f;
        for (int dd = q * 128; dd < q * 128 + 128; ++dd)
            acc += opw[(size_t)dd * DINNER + i] * ow[dd];
        wfp[(size_t)q * DINNER + i] = acc;
    } else if (bid < 1040) {
        int i = ((bid - 16) * 256 + tid) * 4;
        float4 v = *(const float4*)(in_proj_w + i);
        ushort4 o; o.x = f2b(v.x); o.y = f2b(v.y); o.z = f2b(v.z); o.w = f2b(v.w);
        *(ushort4*)(wb + i) = o;
    } else if (bid < 1104) {
        int i = ((bid - 1040) * 256 + tid) * 4;
        float4 v = *(const float4*)(x_proj_w + i);
        ushort4 o; o.x = f2b(v.x); o.y = f2b(v.y); o.z = f2b(v.z); o.w = f2b(v.w);
        *(ushort4*)(wbx + i) = o;
    } else if (bid < 1136) {
        int i = ((bid - 1104) * 256 + tid) * 4;
        float4 v = *(const float4*)(dpw + i);
        ushort4 o; o.x = f2b(v.x); o.y = f2b(v.y); o.z = f2b(v.z); o.w = f2b(v.w);
        *(ushort4*)(dpwb + i) = o;
    } else {
        int wv   = tid >> 6;
        int lane = tid & 63;
        int idx  = (bid - 1136) * 4 + wv;
        int c = idx & 7, b = idx >> 3;
        const float* p = xe + ((size_t)b * LSEQ) * ENC_IN + c;
        float vals[8];
        float s = 0.f, s2 = 0.f;
#pragma unroll
        for (int i = 0; i < 8; ++i) {
            float v = p[(size_t)(lane + i * 64) * ENC_IN];
            vals[i] = v; s += v; s2 += v * v;
        }
#pragma unroll
        for (int off = 32; off; off >>= 1) {
            s  += __shfl_xor(s,  off);
            s2 += __shfl_xor(s2, off);
        }
        float mean = s * (1.f / LSEQ);
        float var  = s2 * (1.f / LSEQ) - mean * mean;
        float sd   = sqrtf(var + 1e-5f);
        float rstd = 1.f / sd;
        if (lane == 0) { meanv[b * ENC_IN + c] = mean; stdv[b * ENC_IN + c] = sd; }
#pragma unroll
        for (int i = 0; i < 8; ++i)
            xn[((size_t)b * LSEQ + lane + i * 64) * ENC_IN + c] = (vals[i] - mean) * rstd;
    }
}

// ============ k_front2: build_x + fusew2 ============
__global__ __launch_bounds__(256) void k_front2(const float* __restrict__ xn,
                                                const float* __restrict__ xmark,
                                                const float* __restrict__ convw,
                                                const float* __restrict__ tempw,
                                                const float* __restrict__ wfp,
                                                unsigned short* __restrict__ xb,
                                                float* __restrict__ wfv) {
    int bid = blockIdx.x;
    int tid = threadIdx.x;
    if (bid >= 32768) {
        int i = (bid - 32768) * 256 + tid;
        wfv[i] = wfp[i] + wfp[DINNER + i] + wfp[2 * DINNER + i] + wfp[3 * DINNER + i];
        return;
    }
    int d = (bid & 1) * 256 + tid;
    int l = (bid >> 1) & (LSEQ - 1);
    int b = bid >> 10;
    int lm = (l + LSEQ - 1) & (LSEQ - 1);
    int lp = (l + 1) & (LSEQ - 1);
    const float* r0 = xn + ((size_t)b * LSEQ + lm) * ENC_IN;
    const float* r1 = xn + ((size_t)b * LSEQ + l ) * ENC_IN;
    const float* r2 = xn + ((size_t)b * LSEQ + lp) * ENC_IN;
    const float* w  = convw + (size_t)d * (ENC_IN * 3);
    float acc = 0.f;
#pragma unroll
    for (int i = 0; i < ENC_IN; ++i)
        acc += r0[i] * w[i * 3 + 0] + r1[i] * w[i * 3 + 1] + r2[i] * w[i * 3 + 2];
    const float* tw = tempw + (size_t)d * MARKD;
    const float* xm = xmark + ((size_t)b * LSEQ + l) * MARKD;
    acc += xm[0] * tw[0] + xm[1] * tw[1] + xm[2] * tw[2] + xm[3] * tw[3];
    float freq = __expf(-(float)(d & ~1) * (9.210340371976184f / (float)DMODEL));
    float rev  = (float)l * freq * 0.15915494309189535f;
    rev = rev - floorf(rev);
    acc += (d & 1) ? __builtin_amdgcn_cosf(rev) : __builtin_amdgcn_sinf(rev);
    xb[((size_t)b * LSEQ + l) * DMODEL + d] = f2b(acc);
}

// ============ Kernel C: in_proj GEMM via bf16 MFMA (async LDS staging) ============
#define TP_STRIDE 136
__global__ __launch_bounds__(256) void k_gemm_inproj(const unsigned short* __restrict__ xb,
                                                     const unsigned short* __restrict__ wb,
                                                     unsigned short* __restrict__ xiT,
                                                     float* __restrict__ gsT) {
    int n0 = blockIdx.x * 128;
    int m0 = blockIdx.y * 128;
    if (n0 >= DINNER && (m0 & (LSEQ - 1)) != 384) return;

    __shared__ unsigned char smem[128 * TP_STRIDE * 2];
    uint4* As4 = (uint4*)smem;
    uint4* Bs4 = As4 + 512;
    unsigned short* T = (unsigned short*)smem;

    int tid  = threadIdx.x;
    int lane = tid & 63;
    int w    = tid >> 6;
    int wm   = (w & 1) * 64;
    int wn   = (w >> 1) * 64;
    f32x4 acc[4][4] = {};

    for (int k0 = 0; k0 < DMODEL; k0 += 32) {
#pragma unroll
        for (int hh = 0; hh < 2; ++hh) {
            int c  = tid + hh * 256;
            int im = c >> 6;
            int lc = c & 63;
            int r  = im * 16 + (lc & 15);
            int kq = lc >> 4;
            ASYNC_LDS16(xb + (size_t)(m0 + r) * DMODEL + k0 + kq * 8,
                        As4 + (w * 64 + hh * 256));
            ASYNC_LDS16(wb + (size_t)(n0 + r) * DMODEL + k0 + kq * 8,
                        Bs4 + (w * 64 + hh * 256));
        }
        __syncthreads();
        bf16_8 af[4], bf[4];
#pragma unroll
        for (int i = 0; i < 4; ++i) {
            af[i] = ((const bf16_8*)As4)[((wm >> 4) + i) * 64 + lane];
            bf[i] = ((const bf16_8*)Bs4)[((wn >> 4) + i) * 64 + lane];
        }
#pragma unroll
        for (int i = 0; i < 4; ++i)
#pragma unroll
            for (int j = 0; j < 4; ++j)
                acc[i][j] = __builtin_amdgcn_mfma_f32_16x16x32_bf16(af[i], bf[j], acc[i][j], 0, 0, 0);
        __syncthreads();
    }

    int col  = lane & 15;
    int quad = lane >> 4;
    if (n0 < DINNER) {
#pragma unroll
        for (int i = 0; i < 4; ++i) {
#pragma unroll
            for (int j = 0; j < 4; ++j) {
                int nn = wn + j * 16 + col;
                int mm = wm + i * 16 + quad * 4;
                ushort4 o;
                o.x = f2b(acc[i][j][0]); o.y = f2b(acc[i][j][1]);
                o.z = f2b(acc[i][j][2]); o.w = f2b(acc[i][j][3]);
                *(ushort4*)&T[nn * TP_STRIDE + mm] = o;
            }
        }
        __syncthreads();
        int bI = m0 >> 9;
        int tglob = m0 & (LSEQ - 1);
#pragma unroll
        for (int it = 0; it < 8; ++it) {
            int c  = tid + it * 256;
            int nn = c >> 4;
            int tc = c & 15;
            uint4 v = *(const uint4*)&T[nn * TP_STRIDE + tc * 8];
            *(uint4*)(xiT + ((size_t)bI * DINNER + n0 + nn) * LSEQ + tglob + tc * 8) = v;
        }
    } else {
#pragma unroll
        for (int i = 0; i < 4; ++i) {
#pragma unroll
            for (int j = 0; j < 4; ++j) {
                int m = m0 + wm + i * 16 + quad * 4;
                int t = m & (LSEQ - 1);
                if (t < TSTART) continue;
                int b = m >> 9;
                int nz = n0 - DINNER + wn + j * 16 + col;
                float4 g;
                float v0 = acc[i][j][0], v1 = acc[i][j][1], v2 = acc[i][j][2], v3 = acc[i][j][3];
                g.x = v0 / (1.f + __expf(-v0));
                g.y = v1 / (1.f + __expf(-v1));
                g.z = v2 / (1.f + __expf(-v2));
                g.w = v3 / (1.f + __expf(-v3));
                *(float4*)(gsT + ((size_t)b * DINNER + nz) * PREDLEN + (t - TSTART)) = g;
            }
        }
    }
}

// ============ Kernel D: depthwise conv + silu; gw=g*wf in place; c0=u*D*g*wf ============
__global__ __launch_bounds__(256) void k_dwconv_silu(const unsigned short* __restrict__ xiT,
                                                     const float* __restrict__ cw,
                                                     const float* __restrict__ cb,
                                                     const float* __restrict__ wfv,
                                                     const float* __restrict__ Dvec,
                                                     float* __restrict__ gsT,
                                                     unsigned short* __restrict__ c0,
                                                     unsigned short* __restrict__ uT) {
    int lane = threadIdx.x & 63;
    int w    = threadIdx.x >> 6;
    int d = blockIdx.x * 4 + w;
    int b = blockIdx.y;
    const unsigned short* src = xiT + ((size_t)b * DINNER + d) * LSEQ;
    uint4 cur = *(const uint4*)(src + lane * 8);
    unsigned pw = (unsigned)__shfl_up((int)cur.w, 1);
    unsigned pz = (unsigned)__shfl_up((int)cur.z, 1);
    if (lane == 0) { pw = 0u; pz = 0u; }
    float4 w4 = *(const float4*)(cw + (size_t)d * 4);
    float bias = cb[d];
    float win[11];
    win[0] = bhi(pz); win[1] = blo(pw); win[2] = bhi(pw);
    const unsigned* cp = (const unsigned*)&cur;
#pragma unroll
    for (int q = 0; q < 4; ++q) {
        win[3 + 2 * q] = blo(cp[q]);
        win[4 + 2 * q] = bhi(cp[q]);
    }
    float uvf[8];
    unsigned ov[4];
#pragma unroll
    for (int tt = 0; tt < 8; ++tt) {
        float a = bias + win[tt] * w4.x + win[tt + 1] * w4.y
                       + win[tt + 2] * w4.z + win[tt + 3] * w4.w;
        float uv = a / (1.f + __expf(-a));
        uvf[tt] = uv;
        unsigned short us = f2b(uv);
        if (tt & 1) ov[tt >> 1] |= ((unsigned)us) << 16;
        else        ov[tt >> 1]  = us;
    }
    *(uint4*)(uT + ((size_t)b * DINNER + d) * LSEQ + lane * 8) = *(uint4*)ov;
    if (lane >= 52) {
        int tl0 = lane * 8 - TSTART;
        float wfd = wfv[d];
        float Dd  = Dvec[d];
        float* gp = gsT + ((size_t)b * DINNER + d) * PREDLEN + tl0;
        float4 g0 = *(const float4*)gp;
        float4 g1 = *(const float4*)(gp + 4);
        float gg[8] = {g0.x, g0.y, g0.z, g0.w, g1.x, g1.y, g1.z, g1.w};
        unsigned cv[4];
#pragma unroll
        for (int j = 0; j < 8; ++j) {
            float gw = gg[j] * wfd;
            gg[j] = gw;
            unsigned short us = f2b(uvf[j] * Dd * gw);
            if (j & 1) cv[j >> 1] |= ((unsigned)us) << 16;
            else       cv[j >> 1]  = us;
        }
        *(float4*)gp       = make_float4(gg[0], gg[1], gg[2], gg[3]);
        *(float4*)(gp + 4) = make_float4(gg[4], gg[5], gg[6], gg[7]);
        *(uint4*)(c0 + ((size_t)b * DINNER + d) * PREDLEN + tl0) = *(uint4*)cv;
    }
}

// ============ Kernel E: x_proj GEMM via bf16 MFMA (prefetched A staging) ============
#define XPS 66
__global__ __launch_bounds__(256) void k_gemm_xproj2(const unsigned short* __restrict__ uT,
                                                     const unsigned short* __restrict__ wbx,
                                                     unsigned short* __restrict__ dt_in,
                                                     float* __restrict__ Bt,
                                                     float* __restrict__ Ct) {
    __shared__ unsigned short Asl[32 * XPS];
    int tid  = threadIdx.x;
    int lane = tid & 63;
    int w    = tid >> 6;
    int quad = lane >> 4;
    int col  = lane & 15;
    int m0 = blockIdx.x * 64;
    int b  = m0 >> 9;
    int t0 = m0 & (LSEQ - 1);
    int sk  = tid >> 3;
    int smc = (tid & 7) * 8;
    f32x4 acc[4] = {};
    uint4 v = *(const uint4*)(uT + ((size_t)b * DINNER + sk) * LSEQ + t0 + smc);
    for (int k0 = 0; k0 < DINNER; k0 += 32) {
        unsigned* dst = (unsigned*)&Asl[sk * XPS + smc];
        dst[0] = v.x; dst[1] = v.y; dst[2] = v.z; dst[3] = v.w;
        __syncthreads();
        if (k0 + 32 < DINNER)   // prefetch next K block while MFMAs run
            v = *(const uint4*)(uT + ((size_t)b * DINNER + k0 + 32 + sk) * LSEQ + t0 + smc);
        bf16_8 bf[4];
#pragma unroll
        for (int j = 0; j < 4; ++j)
            bf[j] = *((const bf16_8*)(wbx + (size_t)(j * 16 + col) * DINNER + k0 + quad * 8));
        union { bf16_8 v; unsigned short u[8]; } af;
#pragma unroll
        for (int j8 = 0; j8 < 8; ++j8)
            af.u[j8] = Asl[(quad * 8 + j8) * XPS + w * 16 + col];
#pragma unroll
        for (int j = 0; j < 4; ++j)
            acc[j] = __builtin_amdgcn_mfma_f32_16x16x32_bf16(af.v, bf[j], acc[j], 0, 0, 0);
        __syncthreads();
    }
    int mrow = m0 + w * 16 + quad * 4;
#pragma unroll
    for (int j = 0; j < 2; ++j)
#pragma unroll
        for (int r = 0; r < 4; ++r)
            dt_in[(size_t)(mrow + r) * DTRANK + j * 16 + col] = f2b(acc[j][r]);
    int t = t0 + w * 16 + quad * 4;
    *(float4*)(Bt + ((size_t)b * DSTATE + col) * LSEQ + t) =
        make_float4(acc[2][0], acc[2][1], acc[2][2], acc[2][3]);
    *(float4*)(Ct + ((size_t)b * DSTATE + col) * LSEQ + t) =
        make_float4(acc[3][0], acc[3][1], acc[3][2], acc[3][3]);
}

// ============ Kernel F: dt_proj as MFMA GEMM (K=32) + softplus + transpose store ============
__global__ __launch_bounds__(256) void k_dtproj2(const unsigned short* __restrict__ dt_in,
                                                 const unsigned short* __restrict__ dpwb,
                                                 const float* __restrict__ dpb,
                                                 unsigned short* __restrict__ dtT) {
    __shared__ unsigned char smem[128 * TP_STRIDE * 2];
    uint4* As4 = (uint4*)smem;
    uint4* Bs4 = As4 + 512;
    unsigned short* T = (unsigned short*)smem;
    int tid  = threadIdx.x;
    int lane = tid & 63;
    int w    = tid >> 6;
    int wm   = (w & 1) * 64;
    int wn   = (w >> 1) * 64;
    int n0 = blockIdx.x * 128;
    int m0 = blockIdx.y * 128;
#pragma unroll
    for (int hh = 0; hh < 2; ++hh) {
        int c  = tid + hh * 256;
        int im = c >> 6;
        int lc = c & 63;
        int r  = im * 16 + (lc & 15);
        int kq = lc >> 4;
        As4[c] = *(const uint4*)(dt_in + (size_t)(m0 + r) * DTRANK + kq * 8);
        Bs4[c] = *(const uint4*)(dpwb + (size_t)(n0 + r) * DTRANK + kq * 8);
    }
    __syncthreads();
    f32x4 acc[4][4] = {};
    bf16_8 af[4], bf[4];
#pragma unroll
    for (int i = 0; i < 4; ++i) {
        af[i] = ((const bf16_8*)As4)[((wm >> 4) + i) * 64 + lane];
        bf[i] = ((const bf16_8*)Bs4)[((wn >> 4) + i) * 64 + lane];
    }
#pragma unroll
    for (int i = 0; i < 4; ++i)
#pragma unroll
        for (int j = 0; j < 4; ++j)
            acc[i][j] = __builtin_amdgcn_mfma_f32_16x16x32_bf16(af[i], bf[j], acc[i][j], 0, 0, 0);
    __syncthreads();
    int col  = lane & 15;
    int quad = lane >> 4;
#pragma unroll
    for (int i = 0; i < 4; ++i) {
#pragma unroll
        for (int j = 0; j < 4; ++j) {
            int nn = wn + j * 16 + col;
            int mm = wm + i * 16 + quad * 4;
            float bias = dpb[n0 + nn];
            ushort4 o;
            unsigned short* op = (unsigned short*)&o;
#pragma unroll
            for (int r = 0; r < 4; ++r) {
                float a = acc[i][j][r] + bias;
                float sp = (a > 20.f) ? a
                         : 0.6931471805599453f * LOG2F(1.f + EXP2F(a * 1.44269504088896f));
                op[r] = f2b(sp);
            }
            *(ushort4*)&T[nn * TP_STRIDE + mm] = o;
        }
    }
    __syncthreads();
    int bI = m0 >> 9;
    int tglob = m0 & (LSEQ - 1);
#pragma unroll
    for (int it = 0; it < 8; ++it) {
        int c  = tid + it * 256;
        int nn = c >> 4;
        int tc = c & 15;
        uint4 v = *(const uint4*)&T[nn * TP_STRIDE + tc * 8];
        *(uint4*)(dtT + ((size_t)bI * DINNER + n0 + nn) * LSEQ + tglob + tc * 8) = v;
    }
}

// ============ Kernel G1: scan phase 1 — 8 chunks (56/48 steps), group-parallel exps ============
// writes beta[b][d][c][s] fp32 and asum[b][d][c] (alpha recomputed in p3).
__global__ __launch_bounds__(256) void k_scan_p1(const unsigned short* __restrict__ uT,
                                                 const unsigned short* __restrict__ dtT,
                                                 const float* __restrict__ Bt,
                                                 const float* __restrict__ A_log,
                                                 float* __restrict__ betav,
                                                 float* __restrict__ asumv) {
    int b = blockIdx.y;
    int c = blockIdx.z;
    int tid  = threadIdx.x;
    int lane = tid & 63;
    int w    = tid >> 6;
    int q    = lane & 3;
    int dloc = lane >> 2;
    int d    = blockIdx.x * 64 + w * 16 + dloc;
    float4 al = *(const float4*)(A_log + (size_t)d * DSTATE + q * 4);
    float As2[4];
    As2[0] = -__expf(al.x) * 1.44269504088896f;
    As2[1] = -__expf(al.y) * 1.44269504088896f;
    As2[2] = -__expf(al.z) * 1.44269504088896f;
    As2[3] = -__expf(al.w) * 1.44269504088896f;
    float beta[4] = {0.f, 0.f, 0.f, 0.f};
    float asum = 0.f;
    const unsigned short* up = uT  + ((size_t)b * DINNER + d) * LSEQ;
    const unsigned short* dp = dtT + ((size_t)b * DINNER + d) * LSEQ;
    const float* Bp = Bt + ((size_t)b * DSTATE + q * 4) * LSEQ;
    int tbeg = c * 56 - ((c > 4) ? (c - 4) * 8 : 0);
    int tend = tbeg + ((c < 4) ? 56 : 48);
    for (int t8 = tbeg; t8 < tend; t8 += 8) {
        uint4 uq = *(const uint4*)(up + t8);
        uint4 dq = *(const uint4*)(dp + t8);
        float uu[8], dd[8];
        const unsigned* uqp = (const unsigned*)&uq;
        const unsigned* dqp = (const unsigned*)&dq;
#pragma unroll
        for (int p = 0; p < 4; ++p) {
            uu[p * 2] = blo(uqp[p]); uu[p * 2 + 1] = bhi(uqp[p]);
            dd[p * 2] = blo(dqp[p]); dd[p * 2 + 1] = bhi(dqp[p]);
        }
        float S[8];
        S[0] = dd[0];
#pragma unroll
        for (int j = 1; j < 8; ++j) S[j] = S[j - 1] + dd[j];
        float G = S[7];
        float w8[8], p8[8];
#pragma unroll
        for (int j = 0; j < 8; ++j) {
            w8[j] = dd[j] * uu[j];
            p8[j] = G - S[j];
        }
        float4 B00 = *(const float4*)(Bp + 0 * LSEQ + t8);
        float4 B01 = *(const float4*)(Bp + 0 * LSEQ + t8 + 4);
        float4 B10 = *(const float4*)(Bp + 1 * LSEQ + t8);
        float4 B11 = *(const float4*)(Bp + 1 * LSEQ + t8 + 4);
        float4 B20 = *(const float4*)(Bp + 2 * LSEQ + t8);
        float4 B21 = *(const float4*)(Bp + 2 * LSEQ + t8 + 4);
        float4 B30 = *(const float4*)(Bp + 3 * LSEQ + t8);
        float4 B31 = *(const float4*)(Bp + 3 * LSEQ + t8 + 4);
        float Bv0[8] = {B00.x, B00.y, B00.z, B00.w, B01.x, B01.y, B01.z, B01.w};
        float Bv1[8] = {B10.x, B10.y, B10.z, B10.w, B11.x, B11.y, B11.z, B11.w};
        float Bv2[8] = {B20.x, B20.y, B20.z, B20.w, B21.x, B21.y, B21.z, B21.w};
        float Bv3[8] = {B30.x, B30.y, B30.z, B30.w, B31.x, B31.y, B31.z, B31.w};
        float g0 = 0.f, g1 = 0.f, g2 = 0.f, g3 = 0.f;
#pragma unroll
        for (int j = 0; j < 8; ++j) {
            g0 += EXP2F(As2[0] * p8[j]) * (w8[j] * Bv0[j]);
            g1 += EXP2F(As2[1] * p8[j]) * (w8[j] * Bv1[j]);
            g2 += EXP2F(As2[2] * p8[j]) * (w8[j] * Bv2[j]);
            g3 += EXP2F(As2[3] * p8[j]) * (w8[j] * Bv3[j]);
        }
        beta[0] = EXP2F(As2[0] * G) * beta[0] + g0;
        beta[1] = EXP2F(As2[1] * G) * beta[1] + g1;
        beta[2] = EXP2F(As2[2] * G) * beta[2] + g2;
        beta[3] = EXP2F(As2[3] * G) * beta[3] + g3;
        asum += G;
    }
    *(float4*)(betav + ((size_t)(b * DINNER + d) * NCHUNK + c) * DSTATE + q * 4) =
        make_float4(beta[0], beta[1], beta[2], beta[3]);
    if (q == 0) asumv[(size_t)(b * DINNER + d) * NCHUNK + c] = asum;
}

// ============ Kernel G2: stitch h(416) from 8 chunks, run [416,512), in-place out ============
__global__ __launch_bounds__(256) void k_scan_p3(const unsigned short* __restrict__ uT,
                                                 const unsigned short* __restrict__ dtT,
                                                 const float* __restrict__ Bt,
                                                 const float* __restrict__ Ct,
                                                 const float* __restrict__ A_log,
                                                 float* __restrict__ gsT,
                                                 const unsigned short* __restrict__ c0,
                                                 const float* __restrict__ betav,
                                                 const float* __restrict__ asumv) {
    int b    = blockIdx.y;
    int tid  = threadIdx.x;
    int s    = tid & 15;
    int dloc = tid >> 4;
    int d    = blockIdx.x * 16 + dloc;
    float As2 = -__expf(A_log[(size_t)d * DSTATE + s]) * 1.44269504088896f;
    const float* bp2 = betav + (size_t)(b * DINNER + d) * NCHUNK * DSTATE + s;
    const float* ap2 = asumv + (size_t)(b * DINNER + d) * NCHUNK;
    float h = 0.f;
#pragma unroll
    for (int c = 0; c < NCHUNK; ++c)
        h = bp2[c * DSTATE] + EXP2F(As2 * ap2[c]) * h;
    const unsigned short* up = uT  + ((size_t)b * DINNER + d) * LSEQ;
    const unsigned short* dp = dtT + ((size_t)b * DINNER + d) * LSEQ;
    const float* Bp = Bt + ((size_t)b * DSTATE + s) * LSEQ;
    const float* Cp = Ct + ((size_t)b * DSTATE + s) * LSEQ;
    float* gp = gsT + ((size_t)b * DINNER + d) * PREDLEN;
    const unsigned short* cp0 = c0 + ((size_t)b * DINNER + d) * PREDLEN;
    for (int t8 = TSTART; t8 < LSEQ; t8 += 8) {
        int tl0 = t8 - TSTART;
        uint4 uq = *(const uint4*)(up + t8);
        uint4 dq = *(const uint4*)(dp + t8);
        float4 B0 = *(const float4*)(Bp + t8);
        float4 B1 = *(const float4*)(Bp + t8 + 4);
        float4 C0 = *(const float4*)(Cp + t8);
        float4 C1 = *(const float4*)(Cp + t8 + 4);
        float4 g0 = *(const float4*)(gp + tl0);
        float4 g1 = *(const float4*)(gp + tl0 + 4);
        uint4 cq = *(const uint4*)(cp0 + tl0);
        float uu[8], dd[8];
        const unsigned* uqp = (const unsigned*)&uq;
        const unsigned* dqp = (const unsigned*)&dq;
#pragma unroll
        for (int p = 0; p < 4; ++p) {
            uu[p * 2] = blo(uqp[p]); uu[p * 2 + 1] = bhi(uqp[p]);
            dd[p * 2] = blo(dqp[p]); dd[p * 2 + 1] = bhi(dqp[p]);
        }
        float Bv[8] = {B0.x, B0.y, B0.z, B0.w, B1.x, B1.y, B1.z, B1.w};
        float Cv[8] = {C0.x, C0.y, C0.z, C0.w, C1.x, C1.y, C1.z, C1.w};
        float y[8];
#pragma unroll
        for (int j = 0; j < 8; ++j) {
            h = EXP2F(dd[j] * As2) * h + (dd[j] * uu[j]) * Bv[j];
            y[j] = h * Cv[j];
        }
#pragma unroll
        for (int j = 0; j < 8; ++j) y[j] += __shfl_xor(y[j], 1);
#pragma unroll
        for (int j = 0; j < 8; ++j) y[j] += __shfl_xor(y[j], 2);
#pragma unroll
        for (int j = 0; j < 8; ++j) y[j] += __shfl_xor(y[j], 4);
#pragma unroll
        for (int j = 0; j < 8; ++j) y[j] += __shfl_xor(y[j], 8);
        if (s < 8) {
            float gv[8] = {g0.x, g0.y, g0.z, g0.w, g1.x, g1.y, g1.z, g1.w};
            const unsigned* cqp = (const unsigned*)&cq;
            float cf = (s & 1) ? bhi(cqp[s >> 1]) : blo(cqp[s >> 1]);
            gp[tl0 + s] = y[s] * gv[s] + cf;
        }
    }
}

// ============ Kernel H: reduce 1024 per-d outputs + de-normalize ============
__global__ __launch_bounds__(256) void k_final2(const float* __restrict__ gsT,
                                                const float* __restrict__ meanv,
                                                const float* __restrict__ stdv,
                                                float* __restrict__ out) {
    int tl = blockIdx.x;
    int b  = blockIdx.y;
    int tid = threadIdx.x;
    const float* gp = gsT + (size_t)b * DINNER * PREDLEN + tl;
    float acc = 0.f;
#pragma unroll
    for (int k = 0; k < 4; ++k)
        acc += gp[(size_t)(tid + k * 256) * PREDLEN];
#pragma unroll
    for (int off = 32; off; off >>= 1) acc += __shfl_xor(acc, off);
    __shared__ float red[4];
    if ((tid & 63) == 0) red[tid >> 6] = acc;
    __syncthreads();
    if (tid == 0) {
        float tot = red[0] + red[1] + red[2] + red[3];
        out[b * PREDLEN + tl] = tot * stdv[b * ENC_IN] + meanv[b * ENC_IN];
    }
}

// ---------------- launch ----------------
extern "C" void kernel_launch(void* const* d_in, const int* in_sizes, int n_in,
                              void* d_out, int out_size, void* d_ws, size_t ws_size,
                              hipStream_t stream) {
    const float* x_enc     = (const float*)d_in[0];
    const float* x_mark    = (const float*)d_in[1];
    const float* conv_w    = (const float*)d_in[2];
    const float* temp_w    = (const float*)d_in[3];
    const float* in_proj_w = (const float*)d_in[4];
    const float* conv1d_w  = (const float*)d_in[5];
    const float* conv1d_b  = (const float*)d_in[6];
    const float* x_proj_w  = (const float*)d_in[7];
    const float* dt_proj_w = (const float*)d_in[8];
    const float* dt_proj_b = (const float*)d_in[9];
    const float* A_log     = (const float*)d_in[10];
    const float* Dvec      = (const float*)d_in[11];
    const float* out_proj_w= (const float*)d_in[12];
    const float* out_w     = (const float*)d_in[13];
    float* ws  = (float*)d_ws;
    float* out = (float*)d_out;

    float* xn    = ws + OFF_XN;
    float* meanv = ws + OFF_MEAN;
    float* stdv  = ws + OFF_STD;
    float* wfv   = ws + OFF_WF;
    float* wfp   = ws + OFF_WFP;
    float* Btv   = ws + OFF_BT;
    float* Ctv   = ws + OFF_CT;
    float* gsT   = ws + OFF_GST;
    float* betav = ws + OFF_BETA;
    float* asumv = ws + OFF_ASUM;
    unsigned short* xb    = (unsigned short*)(ws + OFF_XB);
    unsigned short* wb    = (unsigned short*)(ws + OFF_WB);
    unsigned short* wbx   = (unsigned short*)(ws + OFF_WBX);
    unsigned short* dpwb  = (unsigned short*)(ws + OFF_DPWB);
    unsigned short* dtinb = (unsigned short*)(ws + OFF_DTIN);
    unsigned short* xiT   = (unsigned short*)(ws + OFF_XIT);
    unsigned short* uT    = (unsigned short*)(ws + OFF_UT);
    unsigned short* dtT   = (unsigned short*)(ws + OFF_DTT);
    unsigned short* c0    = (unsigned short*)(ws + OFF_C0);

    k_front<<<dim3(1200), 256, 0, stream>>>(out_proj_w, out_w, in_proj_w, x_proj_w, dt_proj_w,
                                            x_enc, wfp, wb, wbx, dpwb, xn, meanv, stdv);
    k_front2<<<dim3(32772), 256, 0, stream>>>(xn, x_mark, conv_w, temp_w, wfp, xb, wfv);
    k_gemm_inproj<<<dim3(16, 128), 256, 0, stream>>>(xb, wb, xiT, gsT);
    k_dwconv_silu<<<dim3(DINNER / 4, BATCH), 256, 0, stream>>>(xiT, conv1d_w, conv1d_b,
                                                               wfv, Dvec, gsT, c0, uT);
    k_gemm_xproj2<<<dim3(MROWS / 64), 256, 0, stream>>>(uT, wbx, dtinb, Btv, Ctv);
    k_dtproj2<<<dim3(8, 128), 256, 0, stream>>>(dtinb, dpwb, dt_proj_b, dtT);
    k_scan_p1<<<dim3(DINNER / 64, BATCH, NCHUNK), 256, 0, stream>>>(uT, dtT, Btv, A_log,
                                                                    betav, asumv);
    k_scan_p3<<<dim3(DINNER / 16, BATCH), 256, 0, stream>>>(uT, dtT, Btv, Ctv, A_log,
                                                            gsT, c0, betav, asumv);
    k_final2<<<dim3(PREDLEN, BATCH), 256, 0, stream>>>(gsT, meanv, stdv, out);
}

// Round 12
// 390.683 us; speedup vs baseline: 1.2241x; 1.2241x over previous
//
#include <hip/hip_runtime.h>
#include <hip/hip_bf16.h>
#include <math.h>

// ---------------- problem constants ----------------
#define BATCH   32
#define LSEQ    512
#define ENC_IN  8
#define MARKD   4
#define DMODEL  512
#define DSTATE  16
#define DINNER  1024
#define DTRANK  32
#define PREDLEN 96
#define MROWS   (BATCH * LSEQ)          // 16384
#define TSTART  (LSEQ - PREDLEN)        // 416
#define NCHUNK  4                       // 4 x 104 steps over [0,416)
#define CHUNKT  104

// ---------------- workspace layout (float units), total 107.5 MiB ----------------
#define OFF_XN    ((size_t)0)            // 131072
#define OFF_MEAN  ((size_t)131072)       // 256
#define OFF_STD   ((size_t)131328)       // 256
#define OFF_WF    ((size_t)131584)       // 1024
#define OFF_WBX   ((size_t)132608)       // x_proj_w bf16: 32768 f
#define OFF_DPWB  ((size_t)165376)       // dt_proj_w bf16: 16384 f
#define OFF_XB    ((size_t)919040)       // 16384x512 bf16 = 4194304 f (ab overlays)
#define OFF_WB    ((size_t)5113344)      // 2048x512 bf16 = 524288 f
#define OFF_DTIN  ((size_t)5637632)      // dt_in bf16 = 262144 f (wfp overlays early)
#define OFF_BT    ((size_t)6161920)      // B [b][t][s] fp32 = 262144 f
#define OFF_CT    ((size_t)6424064)      // C [b][t][s] fp32 = 262144 f
#define OFF_GST   ((size_t)6686208)      // 32x1024x96 fp32 (g -> gw -> outputs in place)
#define OFF_XIT   ((size_t)9831936)      // [b][d][t] bf16 = 8388608 f (dtT overlays)
#define OFF_UT    ((size_t)18220544)     // [b][d][t] bf16 = 8388608 f
#define OFF_C0    ((size_t)26609152)     // 32x1024x96 bf16 = 1572864 f
#define OFF_DTT   OFF_XIT
#define OFF_AB    OFF_XB                 // 32*1024*4*16*2 fp32 = 4194304 f exact fit
#define OFF_WFP   OFF_DTIN
// end: 28182016 floats = 107.5 MiB

typedef __bf16 bf16_8 __attribute__((ext_vector_type(8)));
typedef float  f32x4  __attribute__((ext_vector_type(4)));

#define EXP2F(x) __builtin_amdgcn_exp2f(x)
#define LOG2F(x) __builtin_amdgcn_logf(x)

typedef __attribute__((address_space(3))) unsigned lds_u32;
typedef const __attribute__((address_space(1))) unsigned glb_u32;
#define ASYNC_LDS16(gsrc, ldst) \
    __builtin_amdgcn_global_load_lds((glb_u32*)(gsrc), (lds_u32*)(ldst), 16, 0, 0)

static __device__ __forceinline__ float b2f(unsigned short h) {
    union { float f; unsigned u; } v; v.u = ((unsigned)h) << 16; return v.f;
}
static __device__ __forceinline__ unsigned short f2b(float f) {
    __hip_bfloat16 h = __float2bfloat16(f);   // RNE
    union { __hip_bfloat16 b; unsigned short s; } v; v.b = h; return v.s;
}
static __device__ __forceinline__ float blo(unsigned v) {
    union { float f; unsigned u; } x; x.u = v << 16; return x.f;
}
static __device__ __forceinline__ float bhi(unsigned v) {
    union { float f; unsigned u; } x; x.u = v & 0xffff0000u; return x.f;
}

// ============ k_front: fusew-partials | w2b x3 | norm ============
__global__ __launch_bounds__(256) void k_front(const float* __restrict__ opw,
                                               const float* __restrict__ ow,
                                               const float* __restrict__ in_proj_w,
                                               const float* __restrict__ x_proj_w,
                                               const float* __restrict__ dpw,
                                               const float* __restrict__ xe,
                                               float* __restrict__ wfp,
                                               unsigned short* __restrict__ wb,
                                               unsigned short* __restrict__ wbx,
                                               unsigned short* __restrict__ dpwb,
                                               float* __restrict__ xn,
                                               float* __restrict__ meanv,
                                               float* __restrict__ stdv) {
    int bid = blockIdx.x;
    int tid = threadIdx.x;
    if (bid < 16) {
        int q = bid >> 2;
        int i = (bid & 3) * 256 + tid;
        float acc = 0.f;
        for (int dd = q * 128; dd < q * 128 + 128; ++dd)
            acc += opw[(size_t)dd * DINNER + i] * ow[dd];
        wfp[(size_t)q * DINNER + i] = acc;
    } else if (bid < 1040) {
        int i = ((bid - 16) * 256 + tid) * 4;
        float4 v = *(const float4*)(in_proj_w + i);
        ushort4 o; o.x = f2b(v.x); o.y = f2b(v.y); o.z = f2b(v.z); o.w = f2b(v.w);
        *(ushort4*)(wb + i) = o;
    } else if (bid < 1104) {
        int i = ((bid - 1040) * 256 + tid) * 4;
        float4 v = *(const float4*)(x_proj_w + i);
        ushort4 o; o.x = f2b(v.x); o.y = f2b(v.y); o.z = f2b(v.z); o.w = f2b(v.w);
        *(ushort4*)(wbx + i) = o;
    } else if (bid < 1136) {
        int i = ((bid - 1104) * 256 + tid) * 4;
        float4 v = *(const float4*)(dpw + i);
        ushort4 o; o.x = f2b(v.x); o.y = f2b(v.y); o.z = f2b(v.z); o.w = f2b(v.w);
        *(ushort4*)(dpwb + i) = o;
    } else {
        int wv   = tid >> 6;
        int lane = tid & 63;
        int idx  = (bid - 1136) * 4 + wv;
        int c = idx & 7, b = idx >> 3;
        const float* p = xe + ((size_t)b * LSEQ) * ENC_IN + c;
        float vals[8];
        float s = 0.f, s2 = 0.f;
#pragma unroll
        for (int i = 0; i < 8; ++i) {
            float v = p[(size_t)(lane + i * 64) * ENC_IN];
            vals[i] = v; s += v; s2 += v * v;
        }
#pragma unroll
        for (int off = 32; off; off >>= 1) {
            s  += __shfl_xor(s,  off);
            s2 += __shfl_xor(s2, off);
        }
        float mean = s * (1.f / LSEQ);
        float var  = s2 * (1.f / LSEQ) - mean * mean;
        float sd   = sqrtf(var + 1e-5f);
        float rstd = 1.f / sd;
        if (lane == 0) { meanv[b * ENC_IN + c] = mean; stdv[b * ENC_IN + c] = sd; }
#pragma unroll
        for (int i = 0; i < 8; ++i)
            xn[((size_t)b * LSEQ + lane + i * 64) * ENC_IN + c] = (vals[i] - mean) * rstd;
    }
}

// ============ k_front2: build_x + fusew2 ============
__global__ __launch_bounds__(256) void k_front2(const float* __restrict__ xn,
                                                const float* __restrict__ xmark,
                                                const float* __restrict__ convw,
                                                const float* __restrict__ tempw,
                                                const float* __restrict__ wfp,
                                                unsigned short* __restrict__ xb,
                                                float* __restrict__ wfv) {
    int bid = blockIdx.x;
    int tid = threadIdx.x;
    if (bid >= 32768) {
        int i = (bid - 32768) * 256 + tid;
        wfv[i] = wfp[i] + wfp[DINNER + i] + wfp[2 * DINNER + i] + wfp[3 * DINNER + i];
        return;
    }
    int d = (bid & 1) * 256 + tid;
    int l = (bid >> 1) & (LSEQ - 1);
    int b = bid >> 10;
    int lm = (l + LSEQ - 1) & (LSEQ - 1);
    int lp = (l + 1) & (LSEQ - 1);
    const float* r0 = xn + ((size_t)b * LSEQ + lm) * ENC_IN;
    const float* r1 = xn + ((size_t)b * LSEQ + l ) * ENC_IN;
    const float* r2 = xn + ((size_t)b * LSEQ + lp) * ENC_IN;
    const float* w  = convw + (size_t)d * (ENC_IN * 3);
    float acc = 0.f;
#pragma unroll
    for (int i = 0; i < ENC_IN; ++i)
        acc += r0[i] * w[i * 3 + 0] + r1[i] * w[i * 3 + 1] + r2[i] * w[i * 3 + 2];
    const float* tw = tempw + (size_t)d * MARKD;
    const float* xm = xmark + ((size_t)b * LSEQ + l) * MARKD;
    acc += xm[0] * tw[0] + xm[1] * tw[1] + xm[2] * tw[2] + xm[3] * tw[3];
    float freq = __expf(-(float)(d & ~1) * (9.210340371976184f / (float)DMODEL));
    float rev  = (float)l * freq * 0.15915494309189535f;
    rev = rev - floorf(rev);
    acc += (d & 1) ? __builtin_amdgcn_cosf(rev) : __builtin_amdgcn_sinf(rev);
    xb[((size_t)b * LSEQ + l) * DMODEL + d] = f2b(acc);
}

// ============ Kernel C: in_proj GEMM via bf16 MFMA (async LDS staging) ============
#define TP_STRIDE 136
__global__ __launch_bounds__(256) void k_gemm_inproj(const unsigned short* __restrict__ xb,
                                                     const unsigned short* __restrict__ wb,
                                                     unsigned short* __restrict__ xiT,
                                                     float* __restrict__ gsT) {
    int n0 = blockIdx.x * 128;
    int m0 = blockIdx.y * 128;
    if (n0 >= DINNER && (m0 & (LSEQ - 1)) != 384) return;

    __shared__ unsigned char smem[128 * TP_STRIDE * 2];
    uint4* As4 = (uint4*)smem;
    uint4* Bs4 = As4 + 512;
    unsigned short* T = (unsigned short*)smem;

    int tid  = threadIdx.x;
    int lane = tid & 63;
    int w    = tid >> 6;
    int wm   = (w & 1) * 64;
    int wn   = (w >> 1) * 64;
    f32x4 acc[4][4] = {};

    for (int k0 = 0; k0 < DMODEL; k0 += 32) {
#pragma unroll
        for (int hh = 0; hh < 2; ++hh) {
            int c  = tid + hh * 256;
            int im = c >> 6;
            int lc = c & 63;
            int r  = im * 16 + (lc & 15);
            int kq = lc >> 4;
            ASYNC_LDS16(xb + (size_t)(m0 + r) * DMODEL + k0 + kq * 8,
                        As4 + (w * 64 + hh * 256));
            ASYNC_LDS16(wb + (size_t)(n0 + r) * DMODEL + k0 + kq * 8,
                        Bs4 + (w * 64 + hh * 256));
        }
        __syncthreads();
        bf16_8 af[4], bf[4];
#pragma unroll
        for (int i = 0; i < 4; ++i) {
            af[i] = ((const bf16_8*)As4)[((wm >> 4) + i) * 64 + lane];
            bf[i] = ((const bf16_8*)Bs4)[((wn >> 4) + i) * 64 + lane];
        }
#pragma unroll
        for (int i = 0; i < 4; ++i)
#pragma unroll
            for (int j = 0; j < 4; ++j)
                acc[i][j] = __builtin_amdgcn_mfma_f32_16x16x32_bf16(af[i], bf[j], acc[i][j], 0, 0, 0);
        __syncthreads();
    }

    int col  = lane & 15;
    int quad = lane >> 4;
    if (n0 < DINNER) {
#pragma unroll
        for (int i = 0; i < 4; ++i) {
#pragma unroll
            for (int j = 0; j < 4; ++j) {
                int nn = wn + j * 16 + col;
                int mm = wm + i * 16 + quad * 4;
                ushort4 o;
                o.x = f2b(acc[i][j][0]); o.y = f2b(acc[i][j][1]);
                o.z = f2b(acc[i][j][2]); o.w = f2b(acc[i][j][3]);
                *(ushort4*)&T[nn * TP_STRIDE + mm] = o;
            }
        }
        __syncthreads();
        int bI = m0 >> 9;
        int tglob = m0 & (LSEQ - 1);
#pragma unroll
        for (int it = 0; it < 8; ++it) {
            int c  = tid + it * 256;
            int nn = c >> 4;
            int tc = c & 15;
            uint4 v = *(const uint4*)&T[nn * TP_STRIDE + tc * 8];
            *(uint4*)(xiT + ((size_t)bI * DINNER + n0 + nn) * LSEQ + tglob + tc * 8) = v;
        }
    } else {
#pragma unroll
        for (int i = 0; i < 4; ++i) {
#pragma unroll
            for (int j = 0; j < 4; ++j) {
                int m = m0 + wm + i * 16 + quad * 4;
                int t = m & (LSEQ - 1);
                if (t < TSTART) continue;
                int b = m >> 9;
                int nz = n0 - DINNER + wn + j * 16 + col;
                float4 g;
                float v0 = acc[i][j][0], v1 = acc[i][j][1], v2 = acc[i][j][2], v3 = acc[i][j][3];
                g.x = v0 / (1.f + __expf(-v0));
                g.y = v1 / (1.f + __expf(-v1));
                g.z = v2 / (1.f + __expf(-v2));
                g.w = v3 / (1.f + __expf(-v3));
                *(float4*)(gsT + ((size_t)b * DINNER + nz) * PREDLEN + (t - TSTART)) = g;
            }
        }
    }
}

// ============ Kernel D: depthwise conv + silu; gw=g*wf in place; c0=u*D*g*wf ============
__global__ __launch_bounds__(256) void k_dwconv_silu(const unsigned short* __restrict__ xiT,
                                                     const float* __restrict__ cw,
                                                     const float* __restrict__ cb,
                                                     const float* __restrict__ wfv,
                                                     const float* __restrict__ Dvec,
                                                     float* __restrict__ gsT,
                                                     unsigned short* __restrict__ c0,
                                                     unsigned short* __restrict__ uT) {
    int lane = threadIdx.x & 63;
    int w    = threadIdx.x >> 6;
    int d = blockIdx.x * 4 + w;
    int b = blockIdx.y;
    const unsigned short* src = xiT + ((size_t)b * DINNER + d) * LSEQ;
    uint4 cur = *(const uint4*)(src + lane * 8);
    unsigned pw = (unsigned)__shfl_up((int)cur.w, 1);
    unsigned pz = (unsigned)__shfl_up((int)cur.z, 1);
    if (lane == 0) { pw = 0u; pz = 0u; }
    float4 w4 = *(const float4*)(cw + (size_t)d * 4);
    float bias = cb[d];
    float win[11];
    win[0] = bhi(pz); win[1] = blo(pw); win[2] = bhi(pw);
    const unsigned* cp = (const unsigned*)&cur;
#pragma unroll
    for (int q = 0; q < 4; ++q) {
        win[3 + 2 * q] = blo(cp[q]);
        win[4 + 2 * q] = bhi(cp[q]);
    }
    float uvf[8];
    unsigned ov[4];
#pragma unroll
    for (int tt = 0; tt < 8; ++tt) {
        float a = bias + win[tt] * w4.x + win[tt + 1] * w4.y
                       + win[tt + 2] * w4.z + win[tt + 3] * w4.w;
        float uv = a / (1.f + __expf(-a));
        uvf[tt] = uv;
        unsigned short us = f2b(uv);
        if (tt & 1) ov[tt >> 1] |= ((unsigned)us) << 16;
        else        ov[tt >> 1]  = us;
    }
    *(uint4*)(uT + ((size_t)b * DINNER + d) * LSEQ + lane * 8) = *(uint4*)ov;
    if (lane >= 52) {
        int tl0 = lane * 8 - TSTART;
        float wfd = wfv[d];
        float Dd  = Dvec[d];
        float* gp = gsT + ((size_t)b * DINNER + d) * PREDLEN + tl0;
        float4 g0 = *(const float4*)gp;
        float4 g1 = *(const float4*)(gp + 4);
        float gg[8] = {g0.x, g0.y, g0.z, g0.w, g1.x, g1.y, g1.z, g1.w};
        unsigned cv[4];
#pragma unroll
        for (int j = 0; j < 8; ++j) {
            float gw = gg[j] * wfd;
            gg[j] = gw;
            unsigned short us = f2b(uvf[j] * Dd * gw);
            if (j & 1) cv[j >> 1] |= ((unsigned)us) << 16;
            else       cv[j >> 1]  = us;
        }
        *(float4*)gp       = make_float4(gg[0], gg[1], gg[2], gg[3]);
        *(float4*)(gp + 4) = make_float4(gg[4], gg[5], gg[6], gg[7]);
        *(uint4*)(c0 + ((size_t)b * DINNER + d) * PREDLEN + tl0) = *(uint4*)cv;
    }
}

// ============ Kernel E: x_proj GEMM via bf16 MFMA; B/C stored [b][t][s] ============
#define XPS 66
__global__ __launch_bounds__(256) void k_gemm_xproj2(const unsigned short* __restrict__ uT,
                                                     const unsigned short* __restrict__ wbx,
                                                     unsigned short* __restrict__ dt_in,
                                                     float* __restrict__ Bt2,
                                                     float* __restrict__ Ct2) {
    __shared__ unsigned short Asl[32 * XPS];
    int tid  = threadIdx.x;
    int lane = tid & 63;
    int w    = tid >> 6;
    int quad = lane >> 4;
    int col  = lane & 15;
    int m0 = blockIdx.x * 64;
    int b  = m0 >> 9;
    int t0 = m0 & (LSEQ - 1);
    int sk  = tid >> 3;
    int smc = (tid & 7) * 8;
    f32x4 acc[4] = {};
    uint4 v = *(const uint4*)(uT + ((size_t)b * DINNER + sk) * LSEQ + t0 + smc);
    for (int k0 = 0; k0 < DINNER; k0 += 32) {
        unsigned* dst = (unsigned*)&Asl[sk * XPS + smc];
        dst[0] = v.x; dst[1] = v.y; dst[2] = v.z; dst[3] = v.w;
        __syncthreads();
        if (k0 + 32 < DINNER)
            v = *(const uint4*)(uT + ((size_t)b * DINNER + k0 + 32 + sk) * LSEQ + t0 + smc);
        bf16_8 bf[4];
#pragma unroll
        for (int j = 0; j < 4; ++j)
            bf[j] = *((const bf16_8*)(wbx + (size_t)(j * 16 + col) * DINNER + k0 + quad * 8));
        union { bf16_8 v; unsigned short u[8]; } af;
#pragma unroll
        for (int j8 = 0; j8 < 8; ++j8)
            af.u[j8] = Asl[(quad * 8 + j8) * XPS + w * 16 + col];
#pragma unroll
        for (int j = 0; j < 4; ++j)
            acc[j] = __builtin_amdgcn_mfma_f32_16x16x32_bf16(af.v, bf[j], acc[j], 0, 0, 0);
        __syncthreads();
    }
    int mrow = m0 + w * 16 + quad * 4;
#pragma unroll
    for (int j = 0; j < 2; ++j)
#pragma unroll
        for (int r = 0; r < 4; ++r)
            dt_in[(size_t)(mrow + r) * DTRANK + j * 16 + col] = f2b(acc[j][r]);
    int t = t0 + w * 16 + quad * 4;
#pragma unroll
    for (int r = 0; r < 4; ++r) {
        Bt2[((size_t)b * LSEQ + t + r) * DSTATE + col] = acc[2][r];
        Ct2[((size_t)b * LSEQ + t + r) * DSTATE + col] = acc[3][r];
    }
}

// ============ Kernel F: dt_proj as MFMA GEMM (K=32) + softplus + transpose store ============
__global__ __launch_bounds__(256) void k_dtproj2(const unsigned short* __restrict__ dt_in,
                                                 const unsigned short* __restrict__ dpwb,
                                                 const float* __restrict__ dpb,
                                                 unsigned short* __restrict__ dtT) {
    __shared__ unsigned char smem[128 * TP_STRIDE * 2];
    uint4* As4 = (uint4*)smem;
    uint4* Bs4 = As4 + 512;
    unsigned short* T = (unsigned short*)smem;
    int tid  = threadIdx.x;
    int lane = tid & 63;
    int w    = tid >> 6;
    int wm   = (w & 1) * 64;
    int wn   = (w >> 1) * 64;
    int n0 = blockIdx.x * 128;
    int m0 = blockIdx.y * 128;
#pragma unroll
    for (int hh = 0; hh < 2; ++hh) {
        int c  = tid + hh * 256;
        int im = c >> 6;
        int lc = c & 63;
        int r  = im * 16 + (lc & 15);
        int kq = lc >> 4;
        As4[c] = *(const uint4*)(dt_in + (size_t)(m0 + r) * DTRANK + kq * 8);
        Bs4[c] = *(const uint4*)(dpwb + (size_t)(n0 + r) * DTRANK + kq * 8);
    }
    __syncthreads();
    f32x4 acc[4][4] = {};
    bf16_8 af[4], bf[4];
#pragma unroll
    for (int i = 0; i < 4; ++i) {
        af[i] = ((const bf16_8*)As4)[((wm >> 4) + i) * 64 + lane];
        bf[i] = ((const bf16_8*)Bs4)[((wn >> 4) + i) * 64 + lane];
    }
#pragma unroll
    for (int i = 0; i < 4; ++i)
#pragma unroll
        for (int j = 0; j < 4; ++j)
            acc[i][j] = __builtin_amdgcn_mfma_f32_16x16x32_bf16(af[i], bf[j], acc[i][j], 0, 0, 0);
    __syncthreads();
    int col  = lane & 15;
    int quad = lane >> 4;
#pragma unroll
    for (int i = 0; i < 4; ++i) {
#pragma unroll
        for (int j = 0; j < 4; ++j) {
            int nn = wn + j * 16 + col;
            int mm = wm + i * 16 + quad * 4;
            float bias = dpb[n0 + nn];
            ushort4 o;
            unsigned short* op = (unsigned short*)&o;
#pragma unroll
            for (int r = 0; r < 4; ++r) {
                float a = acc[i][j][r] + bias;
                float sp = (a > 20.f) ? a
                         : 0.6931471805599453f * LOG2F(1.f + EXP2F(a * 1.44269504088896f));
                op[r] = f2b(sp);
            }
            *(ushort4*)&T[nn * TP_STRIDE + mm] = o;
        }
    }
    __syncthreads();
    int bI = m0 >> 9;
    int tglob = m0 & (LSEQ - 1);
#pragma unroll
    for (int it = 0; it < 8; ++it) {
        int c  = tid + it * 256;
        int nn = c >> 4;
        int tc = c & 15;
        uint4 v = *(const uint4*)&T[nn * TP_STRIDE + tc * 8];
        *(uint4*)(dtT + ((size_t)bI * DINNER + n0 + nn) * LSEQ + tglob + tc * 8) = v;
    }
}

// ============ Kernel G1: scan phase 1 — group-parallel exps, B from [b][t][s] ============
__global__ __launch_bounds__(256) void k_scan_p1(const unsigned short* __restrict__ uT,
                                                 const unsigned short* __restrict__ dtT,
                                                 const float* __restrict__ Bt2,
                                                 const float* __restrict__ A_log,
                                                 float2* __restrict__ ab) {
    int b = blockIdx.y;
    int c = blockIdx.z;
    int tid  = threadIdx.x;
    int lane = tid & 63;
    int w    = tid >> 6;
    int q    = lane & 3;
    int dloc = lane >> 2;
    int d    = blockIdx.x * 64 + w * 16 + dloc;
    float4 al = *(const float4*)(A_log + (size_t)d * DSTATE + q * 4);
    float As2[4];
    As2[0] = -__expf(al.x) * 1.44269504088896f;
    As2[1] = -__expf(al.y) * 1.44269504088896f;
    As2[2] = -__expf(al.z) * 1.44269504088896f;
    As2[3] = -__expf(al.w) * 1.44269504088896f;
    float beta[4] = {0.f, 0.f, 0.f, 0.f};
    float asum = 0.f;
    const unsigned short* up = uT  + ((size_t)b * DINNER + d) * LSEQ;
    const unsigned short* dp = dtT + ((size_t)b * DINNER + d) * LSEQ;
    const float* Bp = Bt2 + (size_t)b * LSEQ * DSTATE + q * 4;
    int tbeg = c * CHUNKT;
    for (int t8 = tbeg; t8 < tbeg + CHUNKT; t8 += 8) {
        uint4 uq = *(const uint4*)(up + t8);
        uint4 dq = *(const uint4*)(dp + t8);
        float4 Bq[8];
#pragma unroll
        for (int j = 0; j < 8; ++j)
            Bq[j] = *(const float4*)(Bp + (size_t)(t8 + j) * DSTATE);   // 1 line/instr
        float uu[8], dd[8];
        const unsigned* uqp = (const unsigned*)&uq;
        const unsigned* dqp = (const unsigned*)&dq;
#pragma unroll
        for (int p = 0; p < 4; ++p) {
            uu[p * 2] = blo(uqp[p]); uu[p * 2 + 1] = bhi(uqp[p]);
            dd[p * 2] = blo(dqp[p]); dd[p * 2 + 1] = bhi(dqp[p]);
        }
        float S[8];
        S[0] = dd[0];
#pragma unroll
        for (int j = 1; j < 8; ++j) S[j] = S[j - 1] + dd[j];
        float G = S[7];
        float g0 = 0.f, g1 = 0.f, g2 = 0.f, g3 = 0.f;
#pragma unroll
        for (int j = 0; j < 8; ++j) {
            float w8 = dd[j] * uu[j];
            float p8 = G - S[j];
            g0 += EXP2F(As2[0] * p8) * (w8 * Bq[j].x);
            g1 += EXP2F(As2[1] * p8) * (w8 * Bq[j].y);
            g2 += EXP2F(As2[2] * p8) * (w8 * Bq[j].z);
            g3 += EXP2F(As2[3] * p8) * (w8 * Bq[j].w);
        }
        beta[0] = EXP2F(As2[0] * G) * beta[0] + g0;
        beta[1] = EXP2F(As2[1] * G) * beta[1] + g1;
        beta[2] = EXP2F(As2[2] * G) * beta[2] + g2;
        beta[3] = EXP2F(As2[3] * G) * beta[3] + g3;
        asum += G;
    }
    float2* abp = ab + ((size_t)(b * DINNER + d) * NCHUNK + c) * DSTATE + q * 4;
#pragma unroll
    for (int si = 0; si < 4; ++si)
        abp[si] = make_float2(EXP2F(asum * As2[si]), beta[si]);
}

// ============ Kernel G2: stitch h(416), run [416,512), B/C from [b][t][s] ============
__global__ __launch_bounds__(256) void k_scan_p3(const unsigned short* __restrict__ uT,
                                                 const unsigned short* __restrict__ dtT,
                                                 const float* __restrict__ Bt2,
                                                 const float* __restrict__ Ct2,
                                                 const float* __restrict__ A_log,
                                                 float* __restrict__ gsT,
                                                 const unsigned short* __restrict__ c0,
                                                 const float2* __restrict__ ab) {
    int b    = blockIdx.y;
    int tid  = threadIdx.x;
    int s    = tid & 15;
    int dloc = tid >> 4;
    int d    = blockIdx.x * 16 + dloc;
    float As2 = -__expf(A_log[(size_t)d * DSTATE + s]) * 1.44269504088896f;
    const float2* abp = ab + (size_t)(b * DINNER + d) * NCHUNK * DSTATE + s;
    float h = 0.f;
#pragma unroll
    for (int c = 0; c < NCHUNK; ++c) {
        float2 v = abp[c * DSTATE];
        h = v.y + v.x * h;
    }
    const unsigned short* up = uT  + ((size_t)b * DINNER + d) * LSEQ;
    const unsigned short* dp = dtT + ((size_t)b * DINNER + d) * LSEQ;
    const float* Bp = Bt2 + (size_t)b * LSEQ * DSTATE + s;
    const float* Cp = Ct2 + (size_t)b * LSEQ * DSTATE + s;
    float* gp = gsT + ((size_t)b * DINNER + d) * PREDLEN;
    const unsigned short* cp0 = c0 + ((size_t)b * DINNER + d) * PREDLEN;
    for (int t8 = TSTART; t8 < LSEQ; t8 += 8) {
        int tl0 = t8 - TSTART;
        uint4 uq = *(const uint4*)(up + t8);
        uint4 dq = *(const uint4*)(dp + t8);
        float Bv[8], Cv[8];
#pragma unroll
        for (int j = 0; j < 8; ++j) {
            Bv[j] = Bp[(size_t)(t8 + j) * DSTATE];   // 1 line/instr (16 contiguous s)
            Cv[j] = Cp[(size_t)(t8 + j) * DSTATE];
        }
        float4 g0 = *(const float4*)(gp + tl0);
        float4 g1 = *(const float4*)(gp + tl0 + 4);
        uint4 cq = *(const uint4*)(cp0 + tl0);
        float uu[8], dd[8];
        const unsigned* uqp = (const unsigned*)&uq;
        const unsigned* dqp = (const unsigned*)&dq;
#pragma unroll
        for (int p = 0; p < 4; ++p) {
            uu[p * 2] = blo(uqp[p]); uu[p * 2 + 1] = bhi(uqp[p]);
            dd[p * 2] = blo(dqp[p]); dd[p * 2 + 1] = bhi(dqp[p]);
        }
        float y[8];
#pragma unroll
        for (int j = 0; j < 8; ++j) {
            h = EXP2F(dd[j] * As2) * h + (dd[j] * uu[j]) * Bv[j];
            y[j] = h * Cv[j];
        }
#pragma unroll
        for (int j = 0; j < 8; ++j) y[j] += __shfl_xor(y[j], 1);
#pragma unroll
        for (int j = 0; j < 8; ++j) y[j] += __shfl_xor(y[j], 2);
#pragma unroll
        for (int j = 0; j < 8; ++j) y[j] += __shfl_xor(y[j], 4);
#pragma unroll
        for (int j = 0; j < 8; ++j) y[j] += __shfl_xor(y[j], 8);
        if (s < 8) {
            float gv[8] = {g0.x, g0.y, g0.z, g0.w, g1.x, g1.y, g1.z, g1.w};
            const unsigned* cqp = (const unsigned*)&cq;
            float cf = (s & 1) ? bhi(cqp[s >> 1]) : blo(cqp[s >> 1]);
            gp[tl0 + s] = y[s] * gv[s] + cf;
        }
    }
}

// ============ Kernel H: reduce 1024 per-d outputs + de-normalize ============
__global__ __launch_bounds__(256) void k_final2(const float* __restrict__ gsT,
                                                const float* __restrict__ meanv,
                                                const float* __restrict__ stdv,
                                                float* __restrict__ out) {
    int tl = blockIdx.x;
    int b  = blockIdx.y;
    int tid = threadIdx.x;
    const float* gp = gsT + (size_t)b * DINNER * PREDLEN + tl;
    float acc = 0.f;
#pragma unroll
    for (int k = 0; k < 4; ++k)
        acc += gp[(size_t)(tid + k * 256) * PREDLEN];
#pragma unroll
    for (int off = 32; off; off >>= 1) acc += __shfl_xor(acc, off);
    __shared__ float red[4];
    if ((tid & 63) == 0) red[tid >> 6] = acc;
    __syncthreads();
    if (tid == 0) {
        float tot = red[0] + red[1] + red[2] + red[3];
        out[b * PREDLEN + tl] = tot * stdv[b * ENC_IN] + meanv[b * ENC_IN];
    }
}

// ---------------- launch ----------------
extern "C" void kernel_launch(void* const* d_in, const int* in_sizes, int n_in,
                              void* d_out, int out_size, void* d_ws, size_t ws_size,
                              hipStream_t stream) {
    const float* x_enc     = (const float*)d_in[0];
    const float* x_mark    = (const float*)d_in[1];
    const float* conv_w    = (const float*)d_in[2];
    const float* temp_w    = (const float*)d_in[3];
    const float* in_proj_w = (const float*)d_in[4];
    const float* conv1d_w  = (const float*)d_in[5];
    const float* conv1d_b  = (const float*)d_in[6];
    const float* x_proj_w  = (const float*)d_in[7];
    const float* dt_proj_w = (const float*)d_in[8];
    const float* dt_proj_b = (const float*)d_in[9];
    const float* A_log     = (const float*)d_in[10];
    const float* Dvec      = (const float*)d_in[11];
    const float* out_proj_w= (const float*)d_in[12];
    const float* out_w     = (const float*)d_in[13];
    float* ws  = (float*)d_ws;
    float* out = (float*)d_out;

    float* xn    = ws + OFF_XN;
    float* meanv = ws + OFF_MEAN;
    float* stdv  = ws + OFF_STD;
    float* wfv   = ws + OFF_WF;
    float* wfp   = ws + OFF_WFP;
    float* Btv   = ws + OFF_BT;
    float* Ctv   = ws + OFF_CT;
    float* gsT   = ws + OFF_GST;
    unsigned short* xb    = (unsigned short*)(ws + OFF_XB);
    unsigned short* wb    = (unsigned short*)(ws + OFF_WB);
    unsigned short* wbx   = (unsigned short*)(ws + OFF_WBX);
    unsigned short* dpwb  = (unsigned short*)(ws + OFF_DPWB);
    unsigned short* dtinb = (unsigned short*)(ws + OFF_DTIN);
    unsigned short* xiT   = (unsigned short*)(ws + OFF_XIT);
    unsigned short* uT    = (unsigned short*)(ws + OFF_UT);
    unsigned short* dtT   = (unsigned short*)(ws + OFF_DTT);
    unsigned short* c0    = (unsigned short*)(ws + OFF_C0);
    float2* ab = (float2*)(ws + OFF_AB);

    k_front<<<dim3(1200), 256, 0, stream>>>(out_proj_w, out_w, in_proj_w, x_proj_w, dt_proj_w,
                                            x_enc, wfp, wb, wbx, dpwb, xn, meanv, stdv);
    k_front2<<<dim3(32772), 256, 0, stream>>>(xn, x_mark, conv_w, temp_w, wfp, xb, wfv);
    k_gemm_inproj<<<dim3(16, 128), 256, 0, stream>>>(xb, wb, xiT, gsT);
    k_dwconv_silu<<<dim3(DINNER / 4, BATCH), 256, 0, stream>>>(xiT, conv1d_w, conv1d_b,
                                                               wfv, Dvec, gsT, c0, uT);
    k_gemm_xproj2<<<dim3(MROWS / 64), 256, 0, stream>>>(uT, wbx, dtinb, Btv, Ctv);
    k_dtproj2<<<dim3(8, 128), 256, 0, stream>>>(dtinb, dpwb, dt_proj_b, dtT);
    k_scan_p1<<<dim3(DINNER / 64, BATCH, NCHUNK), 256, 0, stream>>>(uT, dtT, Btv, A_log, ab);
    k_scan_p3<<<dim3(DINNER / 16, BATCH), 256, 0, stream>>>(uT, dtT, Btv, Ctv, A_log,
                                                            gsT, c0, ab);
    k_final2<<<dim3(PREDLEN, BATCH), 256, 0, stream>>>(gsT, meanv, stdv, out);
}

// Round 13
// 355.425 us; speedup vs baseline: 1.3455x; 1.0992x over previous
//
#include <hip/hip_runtime.h>
#include <hip/hip_bf16.h>
#include <math.h>

// ---------------- problem constants ----------------
#define BATCH   32
#define LSEQ    512
#define ENC_IN  8
#define MARKD   4
#define DMODEL  512
#define DSTATE  16
#define DINNER  1024
#define DTRANK  32
#define PREDLEN 96
#define MROWS   (BATCH * LSEQ)          // 16384
#define TSTART  (LSEQ - PREDLEN)        // 416
#define NCHUNK  4                       // 4 x 104 steps over [0,416)
#define CHUNKT  104

// ---------------- workspace layout (float units), total 107.5 MiB ----------------
#define OFF_XN    ((size_t)0)            // 131072
#define OFF_MEAN  ((size_t)131072)       // 256
#define OFF_STD   ((size_t)131328)       // 256
#define OFF_WF    ((size_t)131584)       // 1024
#define OFF_WBX   ((size_t)132608)       // x_proj_w bf16: 32768 f
#define OFF_DPWB  ((size_t)165376)       // dt_proj_w bf16: 16384 f
#define OFF_OACC  ((size_t)181760)       // 32*96 fp32 atomic accumulator = 3072 f
#define OFF_XB    ((size_t)919040)       // 16384x512 bf16 = 4194304 f (ab overlays)
#define OFF_WB    ((size_t)5113344)      // 2048x512 bf16 = 524288 f
#define OFF_DTIN  ((size_t)5637632)      // dt_in bf16 = 262144 f (wfp overlays early)
#define OFF_BT    ((size_t)6161920)      // B [b][t][s] fp32 = 262144 f
#define OFF_CT    ((size_t)6424064)      // C [b][t][s] fp32 = 262144 f
#define OFF_GST   ((size_t)6686208)      // 32x1024x96 fp32 (g -> gw, read-only in scan)
#define OFF_XIT   ((size_t)9831936)      // [b][d][t] bf16 = 8388608 f (dtT overlays)
#define OFF_UT    ((size_t)18220544)     // [b][d][t] bf16 = 8388608 f
#define OFF_C0    ((size_t)26609152)     // 32x1024x96 bf16 = 1572864 f
#define OFF_DTT   OFF_XIT
#define OFF_AB    OFF_XB                 // 32*1024*4*16*2 fp32 = 4194304 f exact fit
#define OFF_WFP   OFF_DTIN
// end: 28182016 floats = 107.5 MiB

typedef __bf16 bf16_8 __attribute__((ext_vector_type(8)));
typedef float  f32x4  __attribute__((ext_vector_type(4)));

#define EXP2F(x) __builtin_amdgcn_exp2f(x)
#define LOG2F(x) __builtin_amdgcn_logf(x)

typedef __attribute__((address_space(3))) unsigned lds_u32;
typedef const __attribute__((address_space(1))) unsigned glb_u32;
#define ASYNC_LDS16(gsrc, ldst) \
    __builtin_amdgcn_global_load_lds((glb_u32*)(gsrc), (lds_u32*)(ldst), 16, 0, 0)

static __device__ __forceinline__ float b2f(unsigned short h) {
    union { float f; unsigned u; } v; v.u = ((unsigned)h) << 16; return v.f;
}
static __device__ __forceinline__ unsigned short f2b(float f) {
    __hip_bfloat16 h = __float2bfloat16(f);   // RNE
    union { __hip_bfloat16 b; unsigned short s; } v; v.b = h; return v.s;
}
static __device__ __forceinline__ float blo(unsigned v) {
    union { float f; unsigned u; } x; x.u = v << 16; return x.f;
}
static __device__ __forceinline__ float bhi(unsigned v) {
    union { float f; unsigned u; } x; x.u = v & 0xffff0000u; return x.f;
}

// ============ k_front: fusew-partials | w2b x3 | norm | zero oacc ============
__global__ __launch_bounds__(256) void k_front(const float* __restrict__ opw,
                                               const float* __restrict__ ow,
                                               const float* __restrict__ in_proj_w,
                                               const float* __restrict__ x_proj_w,
                                               const float* __restrict__ dpw,
                                               const float* __restrict__ xe,
                                               float* __restrict__ wfp,
                                               unsigned short* __restrict__ wb,
                                               unsigned short* __restrict__ wbx,
                                               unsigned short* __restrict__ dpwb,
                                               float* __restrict__ xn,
                                               float* __restrict__ meanv,
                                               float* __restrict__ stdv,
                                               float* __restrict__ oacc) {
    int bid = blockIdx.x;
    int tid = threadIdx.x;
    if (bid < 16) {
        int q = bid >> 2;
        int i = (bid & 3) * 256 + tid;
        float acc = 0.f;
        for (int dd = q * 128; dd < q * 128 + 128; ++dd)
            acc += opw[(size_t)dd * DINNER + i] * ow[dd];
        wfp[(size_t)q * DINNER + i] = acc;
    } else if (bid < 1040) {
        int i = ((bid - 16) * 256 + tid) * 4;
        float4 v = *(const float4*)(in_proj_w + i);
        ushort4 o; o.x = f2b(v.x); o.y = f2b(v.y); o.z = f2b(v.z); o.w = f2b(v.w);
        *(ushort4*)(wb + i) = o;
    } else if (bid < 1104) {
        int i = ((bid - 1040) * 256 + tid) * 4;
        float4 v = *(const float4*)(x_proj_w + i);
        ushort4 o; o.x = f2b(v.x); o.y = f2b(v.y); o.z = f2b(v.z); o.w = f2b(v.w);
        *(ushort4*)(wbx + i) = o;
    } else if (bid < 1136) {
        int i = ((bid - 1104) * 256 + tid) * 4;
        float4 v = *(const float4*)(dpw + i);
        ushort4 o; o.x = f2b(v.x); o.y = f2b(v.y); o.z = f2b(v.z); o.w = f2b(v.w);
        *(ushort4*)(dpwb + i) = o;
    } else if (bid < 1200) {
        int wv   = tid >> 6;
        int lane = tid & 63;
        int idx  = (bid - 1136) * 4 + wv;
        int c = idx & 7, b = idx >> 3;
        const float* p = xe + ((size_t)b * LSEQ) * ENC_IN + c;
        float vals[8];
        float s = 0.f, s2 = 0.f;
#pragma unroll
        for (int i = 0; i < 8; ++i) {
            float v = p[(size_t)(lane + i * 64) * ENC_IN];
            vals[i] = v; s += v; s2 += v * v;
        }
#pragma unroll
        for (int off = 32; off; off >>= 1) {
            s  += __shfl_xor(s,  off);
            s2 += __shfl_xor(s2, off);
        }
        float mean = s * (1.f / LSEQ);
        float var  = s2 * (1.f / LSEQ) - mean * mean;
        float sd   = sqrtf(var + 1e-5f);
        float rstd = 1.f / sd;
        if (lane == 0) { meanv[b * ENC_IN + c] = mean; stdv[b * ENC_IN + c] = sd; }
#pragma unroll
        for (int i = 0; i < 8; ++i)
            xn[((size_t)b * LSEQ + lane + i * 64) * ENC_IN + c] = (vals[i] - mean) * rstd;
    } else {
        // zero the output atomic accumulator (3072 floats)
        for (int i = tid; i < BATCH * PREDLEN; i += 256) oacc[i] = 0.f;
    }
}

// ============ k_front2: build_x + fusew2 ============
__global__ __launch_bounds__(256) void k_front2(const float* __restrict__ xn,
                                                const float* __restrict__ xmark,
                                                const float* __restrict__ convw,
                                                const float* __restrict__ tempw,
                                                const float* __restrict__ wfp,
                                                unsigned short* __restrict__ xb,
                                                float* __restrict__ wfv) {
    int bid = blockIdx.x;
    int tid = threadIdx.x;
    if (bid >= 32768) {
        int i = (bid - 32768) * 256 + tid;
        wfv[i] = wfp[i] + wfp[DINNER + i] + wfp[2 * DINNER + i] + wfp[3 * DINNER + i];
        return;
    }
    int d = (bid & 1) * 256 + tid;
    int l = (bid >> 1) & (LSEQ - 1);
    int b = bid >> 10;
    int lm = (l + LSEQ - 1) & (LSEQ - 1);
    int lp = (l + 1) & (LSEQ - 1);
    const float* r0 = xn + ((size_t)b * LSEQ + lm) * ENC_IN;
    const float* r1 = xn + ((size_t)b * LSEQ + l ) * ENC_IN;
    const float* r2 = xn + ((size_t)b * LSEQ + lp) * ENC_IN;
    const float* w  = convw + (size_t)d * (ENC_IN * 3);
    float acc = 0.f;
#pragma unroll
    for (int i = 0; i < ENC_IN; ++i)
        acc += r0[i] * w[i * 3 + 0] + r1[i] * w[i * 3 + 1] + r2[i] * w[i * 3 + 2];
    const float* tw = tempw + (size_t)d * MARKD;
    const float* xm = xmark + ((size_t)b * LSEQ + l) * MARKD;
    acc += xm[0] * tw[0] + xm[1] * tw[1] + xm[2] * tw[2] + xm[3] * tw[3];
    float freq = __expf(-(float)(d & ~1) * (9.210340371976184f / (float)DMODEL));
    float rev  = (float)l * freq * 0.15915494309189535f;
    rev = rev - floorf(rev);
    acc += (d & 1) ? __builtin_amdgcn_cosf(rev) : __builtin_amdgcn_sinf(rev);
    xb[((size_t)b * LSEQ + l) * DMODEL + d] = f2b(acc);
}

// ============ Kernel C: in_proj GEMM via bf16 MFMA (async LDS staging) ============
#define TP_STRIDE 136
__global__ __launch_bounds__(256) void k_gemm_inproj(const unsigned short* __restrict__ xb,
                                                     const unsigned short* __restrict__ wb,
                                                     unsigned short* __restrict__ xiT,
                                                     float* __restrict__ gsT) {
    int n0 = blockIdx.x * 128;
    int m0 = blockIdx.y * 128;
    if (n0 >= DINNER && (m0 & (LSEQ - 1)) != 384) return;

    __shared__ unsigned char smem[128 * TP_STRIDE * 2];
    uint4* As4 = (uint4*)smem;
    uint4* Bs4 = As4 + 512;
    unsigned short* T = (unsigned short*)smem;

    int tid  = threadIdx.x;
    int lane = tid & 63;
    int w    = tid >> 6;
    int wm   = (w & 1) * 64;
    int wn   = (w >> 1) * 64;
    f32x4 acc[4][4] = {};

    for (int k0 = 0; k0 < DMODEL; k0 += 32) {
#pragma unroll
        for (int hh = 0; hh < 2; ++hh) {
            int c  = tid + hh * 256;
            int im = c >> 6;
            int lc = c & 63;
            int r  = im * 16 + (lc & 15);
            int kq = lc >> 4;
            ASYNC_LDS16(xb + (size_t)(m0 + r) * DMODEL + k0 + kq * 8,
                        As4 + (w * 64 + hh * 256));
            ASYNC_LDS16(wb + (size_t)(n0 + r) * DMODEL + k0 + kq * 8,
                        Bs4 + (w * 64 + hh * 256));
        }
        __syncthreads();
        bf16_8 af[4], bf[4];
#pragma unroll
        for (int i = 0; i < 4; ++i) {
            af[i] = ((const bf16_8*)As4)[((wm >> 4) + i) * 64 + lane];
            bf[i] = ((const bf16_8*)Bs4)[((wn >> 4) + i) * 64 + lane];
        }
#pragma unroll
        for (int i = 0; i < 4; ++i)
#pragma unroll
            for (int j = 0; j < 4; ++j)
                acc[i][j] = __builtin_amdgcn_mfma_f32_16x16x32_bf16(af[i], bf[j], acc[i][j], 0, 0, 0);
        __syncthreads();
    }

    int col  = lane & 15;
    int quad = lane >> 4;
    if (n0 < DINNER) {
#pragma unroll
        for (int i = 0; i < 4; ++i) {
#pragma unroll
            for (int j = 0; j < 4; ++j) {
                int nn = wn + j * 16 + col;
                int mm = wm + i * 16 + quad * 4;
                ushort4 o;
                o.x = f2b(acc[i][j][0]); o.y = f2b(acc[i][j][1]);
                o.z = f2b(acc[i][j][2]); o.w = f2b(acc[i][j][3]);
                *(ushort4*)&T[nn * TP_STRIDE + mm] = o;
            }
        }
        __syncthreads();
        int bI = m0 >> 9;
        int tglob = m0 & (LSEQ - 1);
#pragma unroll
        for (int it = 0; it < 8; ++it) {
            int c  = tid + it * 256;
            int nn = c >> 4;
            int tc = c & 15;
            uint4 v = *(const uint4*)&T[nn * TP_STRIDE + tc * 8];
            *(uint4*)(xiT + ((size_t)bI * DINNER + n0 + nn) * LSEQ + tglob + tc * 8) = v;
        }
    } else {
#pragma unroll
        for (int i = 0; i < 4; ++i) {
#pragma unroll
            for (int j = 0; j < 4; ++j) {
                int m = m0 + wm + i * 16 + quad * 4;
                int t = m & (LSEQ - 1);
                if (t < TSTART) continue;
                int b = m >> 9;
                int nz = n0 - DINNER + wn + j * 16 + col;
                float4 g;
                float v0 = acc[i][j][0], v1 = acc[i][j][1], v2 = acc[i][j][2], v3 = acc[i][j][3];
                g.x = v0 / (1.f + __expf(-v0));
                g.y = v1 / (1.f + __expf(-v1));
                g.z = v2 / (1.f + __expf(-v2));
                g.w = v3 / (1.f + __expf(-v3));
                *(float4*)(gsT + ((size_t)b * DINNER + nz) * PREDLEN + (t - TSTART)) = g;
            }
        }
    }
}

// ============ Kernel D: depthwise conv + silu; gw=g*wf in place; c0=u*D*g*wf ============
__global__ __launch_bounds__(256) void k_dwconv_silu(const unsigned short* __restrict__ xiT,
                                                     const float* __restrict__ cw,
                                                     const float* __restrict__ cb,
                                                     const float* __restrict__ wfv,
                                                     const float* __restrict__ Dvec,
                                                     float* __restrict__ gsT,
                                                     unsigned short* __restrict__ c0,
                                                     unsigned short* __restrict__ uT) {
    int lane = threadIdx.x & 63;
    int w    = threadIdx.x >> 6;
    int d = blockIdx.x * 4 + w;
    int b = blockIdx.y;
    const unsigned short* src = xiT + ((size_t)b * DINNER + d) * LSEQ;
    uint4 cur = *(const uint4*)(src + lane * 8);
    unsigned pw = (unsigned)__shfl_up((int)cur.w, 1);
    unsigned pz = (unsigned)__shfl_up((int)cur.z, 1);
    if (lane == 0) { pw = 0u; pz = 0u; }
    float4 w4 = *(const float4*)(cw + (size_t)d * 4);
    float bias = cb[d];
    float win[11];
    win[0] = bhi(pz); win[1] = blo(pw); win[2] = bhi(pw);
    const unsigned* cp = (const unsigned*)&cur;
#pragma unroll
    for (int q = 0; q < 4; ++q) {
        win[3 + 2 * q] = blo(cp[q]);
        win[4 + 2 * q] = bhi(cp[q]);
    }
    float uvf[8];
    unsigned ov[4];
#pragma unroll
    for (int tt = 0; tt < 8; ++tt) {
        float a = bias + win[tt] * w4.x + win[tt + 1] * w4.y
                       + win[tt + 2] * w4.z + win[tt + 3] * w4.w;
        float uv = a / (1.f + __expf(-a));
        uvf[tt] = uv;
        unsigned short us = f2b(uv);
        if (tt & 1) ov[tt >> 1] |= ((unsigned)us) << 16;
        else        ov[tt >> 1]  = us;
    }
    *(uint4*)(uT + ((size_t)b * DINNER + d) * LSEQ + lane * 8) = *(uint4*)ov;
    if (lane >= 52) {
        int tl0 = lane * 8 - TSTART;
        float wfd = wfv[d];
        float Dd  = Dvec[d];
        float* gp = gsT + ((size_t)b * DINNER + d) * PREDLEN + tl0;
        float4 g0 = *(const float4*)gp;
        float4 g1 = *(const float4*)(gp + 4);
        float gg[8] = {g0.x, g0.y, g0.z, g0.w, g1.x, g1.y, g1.z, g1.w};
        unsigned cv[4];
#pragma unroll
        for (int j = 0; j < 8; ++j) {
            float gw = gg[j] * wfd;
            gg[j] = gw;
            unsigned short us = f2b(uvf[j] * Dd * gw);
            if (j & 1) cv[j >> 1] |= ((unsigned)us) << 16;
            else       cv[j >> 1]  = us;
        }
        *(float4*)gp       = make_float4(gg[0], gg[1], gg[2], gg[3]);
        *(float4*)(gp + 4) = make_float4(gg[4], gg[5], gg[6], gg[7]);
        *(uint4*)(c0 + ((size_t)b * DINNER + d) * PREDLEN + tl0) = *(uint4*)cv;
    }
}

// ============ Kernel E: x_proj GEMM via bf16 MFMA; B/C stored [b][t][s] ============
#define XPS 66
__global__ __launch_bounds__(256) void k_gemm_xproj2(const unsigned short* __restrict__ uT,
                                                     const unsigned short* __restrict__ wbx,
                                                     unsigned short* __restrict__ dt_in,
                                                     float* __restrict__ Bt2,
                                                     float* __restrict__ Ct2) {
    __shared__ unsigned short Asl[32 * XPS];
    int tid  = threadIdx.x;
    int lane = tid & 63;
    int w    = tid >> 6;
    int quad = lane >> 4;
    int col  = lane & 15;
    int m0 = blockIdx.x * 64;
    int b  = m0 >> 9;
    int t0 = m0 & (LSEQ - 1);
    int sk  = tid >> 3;
    int smc = (tid & 7) * 8;
    f32x4 acc[4] = {};
    uint4 v = *(const uint4*)(uT + ((size_t)b * DINNER + sk) * LSEQ + t0 + smc);
    for (int k0 = 0; k0 < DINNER; k0 += 32) {
        unsigned* dst = (unsigned*)&Asl[sk * XPS + smc];
        dst[0] = v.x; dst[1] = v.y; dst[2] = v.z; dst[3] = v.w;
        __syncthreads();
        if (k0 + 32 < DINNER)
            v = *(const uint4*)(uT + ((size_t)b * DINNER + k0 + 32 + sk) * LSEQ + t0 + smc);
        bf16_8 bf[4];
#pragma unroll
        for (int j = 0; j < 4; ++j)
            bf[j] = *((const bf16_8*)(wbx + (size_t)(j * 16 + col) * DINNER + k0 + quad * 8));
        union { bf16_8 v; unsigned short u[8]; } af;
#pragma unroll
        for (int j8 = 0; j8 < 8; ++j8)
            af.u[j8] = Asl[(quad * 8 + j8) * XPS + w * 16 + col];
#pragma unroll
        for (int j = 0; j < 4; ++j)
            acc[j] = __builtin_amdgcn_mfma_f32_16x16x32_bf16(af.v, bf[j], acc[j], 0, 0, 0);
        __syncthreads();
    }
    int mrow = m0 + w * 16 + quad * 4;
#pragma unroll
    for (int j = 0; j < 2; ++j)
#pragma unroll
        for (int r = 0; r < 4; ++r)
            dt_in[(size_t)(mrow + r) * DTRANK + j * 16 + col] = f2b(acc[j][r]);
    int t = t0 + w * 16 + quad * 4;
#pragma unroll
    for (int r = 0; r < 4; ++r) {
        Bt2[((size_t)b * LSEQ + t + r) * DSTATE + col] = acc[2][r];
        Ct2[((size_t)b * LSEQ + t + r) * DSTATE + col] = acc[3][r];
    }
}

// ============ Kernel F: dt_proj as MFMA GEMM (K=32) + softplus + transpose store ============
__global__ __launch_bounds__(256) void k_dtproj2(const unsigned short* __restrict__ dt_in,
                                                 const unsigned short* __restrict__ dpwb,
                                                 const float* __restrict__ dpb,
                                                 unsigned short* __restrict__ dtT) {
    __shared__ unsigned char smem[128 * TP_STRIDE * 2];
    uint4* As4 = (uint4*)smem;
    uint4* Bs4 = As4 + 512;
    unsigned short* T = (unsigned short*)smem;
    int tid  = threadIdx.x;
    int lane = tid & 63;
    int w    = tid >> 6;
    int wm   = (w & 1) * 64;
    int wn   = (w >> 1) * 64;
    int n0 = blockIdx.x * 128;
    int m0 = blockIdx.y * 128;
#pragma unroll
    for (int hh = 0; hh < 2; ++hh) {
        int c  = tid + hh * 256;
        int im = c >> 6;
        int lc = c & 63;
        int r  = im * 16 + (lc & 15);
        int kq = lc >> 4;
        As4[c] = *(const uint4*)(dt_in + (size_t)(m0 + r) * DTRANK + kq * 8);
        Bs4[c] = *(const uint4*)(dpwb + (size_t)(n0 + r) * DTRANK + kq * 8);
    }
    __syncthreads();
    f32x4 acc[4][4] = {};
    bf16_8 af[4], bf[4];
#pragma unroll
    for (int i = 0; i < 4; ++i) {
        af[i] = ((const bf16_8*)As4)[((wm >> 4) + i) * 64 + lane];
        bf[i] = ((const bf16_8*)Bs4)[((wn >> 4) + i) * 64 + lane];
    }
#pragma unroll
    for (int i = 0; i < 4; ++i)
#pragma unroll
        for (int j = 0; j < 4; ++j)
            acc[i][j] = __builtin_amdgcn_mfma_f32_16x16x32_bf16(af[i], bf[j], acc[i][j], 0, 0, 0);
    __syncthreads();
    int col  = lane & 15;
    int quad = lane >> 4;
#pragma unroll
    for (int i = 0; i < 4; ++i) {
#pragma unroll
        for (int j = 0; j < 4; ++j) {
            int nn = wn + j * 16 + col;
            int mm = wm + i * 16 + quad * 4;
            float bias = dpb[n0 + nn];
            ushort4 o;
            unsigned short* op = (unsigned short*)&o;
#pragma unroll
            for (int r = 0; r < 4; ++r) {
                float a = acc[i][j][r] + bias;
                float sp = (a > 20.f) ? a
                         : 0.6931471805599453f * LOG2F(1.f + EXP2F(a * 1.44269504088896f));
                op[r] = f2b(sp);
            }
            *(ushort4*)&T[nn * TP_STRIDE + mm] = o;
        }
    }
    __syncthreads();
    int bI = m0 >> 9;
    int tglob = m0 & (LSEQ - 1);
#pragma unroll
    for (int it = 0; it < 8; ++it) {
        int c  = tid + it * 256;
        int nn = c >> 4;
        int tc = c & 15;
        uint4 v = *(const uint4*)&T[nn * TP_STRIDE + tc * 8];
        *(uint4*)(dtT + ((size_t)bI * DINNER + n0 + nn) * LSEQ + tglob + tc * 8) = v;
    }
}

// ============ Kernel G1: scan phase 1 — group-parallel exps, B from [b][t][s] ============
__global__ __launch_bounds__(256) void k_scan_p1(const unsigned short* __restrict__ uT,
                                                 const unsigned short* __restrict__ dtT,
                                                 const float* __restrict__ Bt2,
                                                 const float* __restrict__ A_log,
                                                 float2* __restrict__ ab) {
    int b = blockIdx.y;
    int c = blockIdx.z;
    int tid  = threadIdx.x;
    int lane = tid & 63;
    int w    = tid >> 6;
    int q    = lane & 3;
    int dloc = lane >> 2;
    int d    = blockIdx.x * 64 + w * 16 + dloc;
    float4 al = *(const float4*)(A_log + (size_t)d * DSTATE + q * 4);
    float As2[4];
    As2[0] = -__expf(al.x) * 1.44269504088896f;
    As2[1] = -__expf(al.y) * 1.44269504088896f;
    As2[2] = -__expf(al.z) * 1.44269504088896f;
    As2[3] = -__expf(al.w) * 1.44269504088896f;
    float beta[4] = {0.f, 0.f, 0.f, 0.f};
    float asum = 0.f;
    const unsigned short* up = uT  + ((size_t)b * DINNER + d) * LSEQ;
    const unsigned short* dp = dtT + ((size_t)b * DINNER + d) * LSEQ;
    const float* Bp = Bt2 + (size_t)b * LSEQ * DSTATE + q * 4;
    int tbeg = c * CHUNKT;
    for (int t8 = tbeg; t8 < tbeg + CHUNKT; t8 += 8) {
        uint4 uq = *(const uint4*)(up + t8);
        uint4 dq = *(const uint4*)(dp + t8);
        float4 Bq[8];
#pragma unroll
        for (int j = 0; j < 8; ++j)
            Bq[j] = *(const float4*)(Bp + (size_t)(t8 + j) * DSTATE);
        float uu[8], dd[8];
        const unsigned* uqp = (const unsigned*)&uq;
        const unsigned* dqp = (const unsigned*)&dq;
#pragma unroll
        for (int p = 0; p < 4; ++p) {
            uu[p * 2] = blo(uqp[p]); uu[p * 2 + 1] = bhi(uqp[p]);
            dd[p * 2] = blo(dqp[p]); dd[p * 2 + 1] = bhi(dqp[p]);
        }
        float S[8];
        S[0] = dd[0];
#pragma unroll
        for (int j = 1; j < 8; ++j) S[j] = S[j - 1] + dd[j];
        float G = S[7];
        float g0 = 0.f, g1 = 0.f, g2 = 0.f, g3 = 0.f;
#pragma unroll
        for (int j = 0; j < 8; ++j) {
            float w8 = dd[j] * uu[j];
            float p8 = G - S[j];
            g0 += EXP2F(As2[0] * p8) * (w8 * Bq[j].x);
            g1 += EXP2F(As2[1] * p8) * (w8 * Bq[j].y);
            g2 += EXP2F(As2[2] * p8) * (w8 * Bq[j].z);
            g3 += EXP2F(As2[3] * p8) * (w8 * Bq[j].w);
        }
        beta[0] = EXP2F(As2[0] * G) * beta[0] + g0;
        beta[1] = EXP2F(As2[1] * G) * beta[1] + g1;
        beta[2] = EXP2F(As2[2] * G) * beta[2] + g2;
        beta[3] = EXP2F(As2[3] * G) * beta[3] + g3;
        asum += G;
    }
    float2* abp = ab + ((size_t)(b * DINNER + d) * NCHUNK + c) * DSTATE + q * 4;
#pragma unroll
    for (int si = 0; si < 4; ++si)
        abp[si] = make_float2(EXP2F(asum * As2[si]), beta[si]);
}

// ============ Kernel G2: stitch h(416), run [416,512); LDS B/C; block-reduce + atomic ============
__global__ __launch_bounds__(256) void k_scan_p3(const unsigned short* __restrict__ uT,
                                                 const unsigned short* __restrict__ dtT,
                                                 const float* __restrict__ Bt2,
                                                 const float* __restrict__ Ct2,
                                                 const float* __restrict__ A_log,
                                                 const float* __restrict__ gsT,   // gw (read-only)
                                                 const unsigned short* __restrict__ c0,
                                                 const float2* __restrict__ ab,
                                                 float* __restrict__ oacc) {
    __shared__ float BsL[PREDLEN * DSTATE];     // 6 KB
    __shared__ float CsL[PREDLEN * DSTATE];     // 6 KB
    __shared__ float accL[16][100];             // 6.4 KB, pad 100 breaks bank aliasing
    int b    = blockIdx.y;
    int tid  = threadIdx.x;
    int s    = tid & 15;
    int dloc = (tid >> 4) & 3;
    int w    = tid >> 6;
    int d    = blockIdx.x * 16 + (tid >> 4);
    // stage B/C tail [416,512) into LDS, coalesced
    for (int i = tid; i < (PREDLEN * DSTATE) / 4; i += 256) {
        ((float4*)BsL)[i] = *((const float4*)(Bt2 + ((size_t)b * LSEQ + TSTART) * DSTATE) + i);
        ((float4*)CsL)[i] = *((const float4*)(Ct2 + ((size_t)b * LSEQ + TSTART) * DSTATE) + i);
    }
    float As2 = -__expf(A_log[(size_t)d * DSTATE + s]) * 1.44269504088896f;
    const float2* abp = ab + (size_t)(b * DINNER + d) * NCHUNK * DSTATE + s;
    float h = 0.f;
#pragma unroll
    for (int c = 0; c < NCHUNK; ++c) {
        float2 v = abp[c * DSTATE];
        h = v.y + v.x * h;
    }
    const unsigned short* up = uT  + ((size_t)b * DINNER + d) * LSEQ;
    const unsigned short* dp = dtT + ((size_t)b * DINNER + d) * LSEQ;
    const float* gp = gsT + ((size_t)b * DINNER + d) * PREDLEN;
    const unsigned short* cp0 = c0 + ((size_t)b * DINNER + d) * PREDLEN;
    __syncthreads();
    for (int t8 = TSTART; t8 < LSEQ; t8 += 8) {
        int tl0 = t8 - TSTART;
        uint4 uq = *(const uint4*)(up + t8);
        uint4 dq = *(const uint4*)(dp + t8);
        float4 g0 = *(const float4*)(gp + tl0);
        float4 g1 = *(const float4*)(gp + tl0 + 4);
        uint4 cq = *(const uint4*)(cp0 + tl0);
        float Bv[8], Cv[8];
#pragma unroll
        for (int j = 0; j < 8; ++j) {
            Bv[j] = BsL[(tl0 + j) * DSTATE + s];
            Cv[j] = CsL[(tl0 + j) * DSTATE + s];
        }
        float uu[8], dd[8];
        const unsigned* uqp = (const unsigned*)&uq;
        const unsigned* dqp = (const unsigned*)&dq;
#pragma unroll
        for (int p = 0; p < 4; ++p) {
            uu[p * 2] = blo(uqp[p]); uu[p * 2 + 1] = bhi(uqp[p]);
            dd[p * 2] = blo(dqp[p]); dd[p * 2 + 1] = bhi(dqp[p]);
        }
        float y[8];
#pragma unroll
        for (int j = 0; j < 8; ++j) {
            h = EXP2F(dd[j] * As2) * h + (dd[j] * uu[j]) * Bv[j];
            y[j] = h * Cv[j];
        }
        // s-butterfly: 8 independent chains
#pragma unroll
        for (int j = 0; j < 8; ++j) y[j] += __shfl_xor(y[j], 1);
#pragma unroll
        for (int j = 0; j < 8; ++j) y[j] += __shfl_xor(y[j], 2);
#pragma unroll
        for (int j = 0; j < 8; ++j) y[j] += __shfl_xor(y[j], 4);
#pragma unroll
        for (int j = 0; j < 8; ++j) y[j] += __shfl_xor(y[j], 8);
        // apply gate weight + D-term, write per-(wave,dloc) partials
        float gv[8] = {g0.x, g0.y, g0.z, g0.w, g1.x, g1.y, g1.z, g1.w};
        const unsigned* cqp = (const unsigned*)&cq;
#pragma unroll
        for (int j = 0; j < 8; ++j) {
            float cf = (j & 1) ? bhi(cqp[j >> 1]) : blo(cqp[j >> 1]);
            float z  = y[j] * gv[j] + cf;
            if (s == 0) accL[w * 4 + dloc][tl0 + j] = z;
        }
    }
    __syncthreads();
    if (tid < PREDLEN) {
        float tot = 0.f;
#pragma unroll
        for (int k = 0; k < 16; ++k) tot += accL[k][tid];
        atomicAdd(&oacc[b * PREDLEN + tid], tot);
    }
}

// ============ Kernel H: scale accumulated outputs + de-normalize ============
__global__ __launch_bounds__(256) void k_final3(const float* __restrict__ oacc,
                                                const float* __restrict__ meanv,
                                                const float* __restrict__ stdv,
                                                float* __restrict__ out) {
    int idx = blockIdx.x * 256 + threadIdx.x;   // 0..3071
    int b = idx / PREDLEN;
    out[idx] = oacc[idx] * stdv[b * ENC_IN] + meanv[b * ENC_IN];
}

// ---------------- launch ----------------
extern "C" void kernel_launch(void* const* d_in, const int* in_sizes, int n_in,
                              void* d_out, int out_size, void* d_ws, size_t ws_size,
                              hipStream_t stream) {
    const float* x_enc     = (const float*)d_in[0];
    const float* x_mark    = (const float*)d_in[1];
    const float* conv_w    = (const float*)d_in[2];
    const float* temp_w    = (const float*)d_in[3];
    const float* in_proj_w = (const float*)d_in[4];
    const float* conv1d_w  = (const float*)d_in[5];
    const float* conv1d_b  = (const float*)d_in[6];
    const float* x_proj_w  = (const float*)d_in[7];
    const float* dt_proj_w = (const float*)d_in[8];
    const float* dt_proj_b = (const float*)d_in[9];
    const float* A_log     = (const float*)d_in[10];
    const float* Dvec      = (const float*)d_in[11];
    const float* out_proj_w= (const float*)d_in[12];
    const float* out_w     = (const float*)d_in[13];
    float* ws  = (float*)d_ws;
    float* out = (float*)d_out;

    float* xn    = ws + OFF_XN;
    float* meanv = ws + OFF_MEAN;
    float* stdv  = ws + OFF_STD;
    float* wfv   = ws + OFF_WF;
    float* wfp   = ws + OFF_WFP;
    float* oacc  = ws + OFF_OACC;
    float* Btv   = ws + OFF_BT;
    float* Ctv   = ws + OFF_CT;
    float* gsT   = ws + OFF_GST;
    unsigned short* xb    = (unsigned short*)(ws + OFF_XB);
    unsigned short* wb    = (unsigned short*)(ws + OFF_WB);
    unsigned short* wbx   = (unsigned short*)(ws + OFF_WBX);
    unsigned short* dpwb  = (unsigned short*)(ws + OFF_DPWB);
    unsigned short* dtinb = (unsigned short*)(ws + OFF_DTIN);
    unsigned short* xiT   = (unsigned short*)(ws + OFF_XIT);
    unsigned short* uT    = (unsigned short*)(ws + OFF_UT);
    unsigned short* dtT   = (unsigned short*)(ws + OFF_DTT);
    unsigned short* c0    = (unsigned short*)(ws + OFF_C0);
    float2* ab = (float2*)(ws + OFF_AB);

    k_front<<<dim3(1201), 256, 0, stream>>>(out_proj_w, out_w, in_proj_w, x_proj_w, dt_proj_w,
                                            x_enc, wfp, wb, wbx, dpwb, xn, meanv, stdv, oacc);
    k_front2<<<dim3(32772), 256, 0, stream>>>(xn, x_mark, conv_w, temp_w, wfp, xb, wfv);
    k_gemm_inproj<<<dim3(16, 128), 256, 0, stream>>>(xb, wb, xiT, gsT);
    k_dwconv_silu<<<dim3(DINNER / 4, BATCH), 256, 0, stream>>>(xiT, conv1d_w, conv1d_b,
                                                               wfv, Dvec, gsT, c0, uT);
    k_gemm_xproj2<<<dim3(MROWS / 64), 256, 0, stream>>>(uT, wbx, dtinb, Btv, Ctv);
    k_dtproj2<<<dim3(8, 128), 256, 0, stream>>>(dtinb, dpwb, dt_proj_b, dtT);
    k_scan_p1<<<dim3(DINNER / 64, BATCH, NCHUNK), 256, 0, stream>>>(uT, dtT, Btv, A_log, ab);
    k_scan_p3<<<dim3(DINNER / 16, BATCH), 256, 0, stream>>>(uT, dtT, Btv, Ctv, A_log,
                                                            gsT, c0, ab, oacc);
    k_final3<<<dim3((BATCH * PREDLEN) / 256), 256, 0, stream>>>(oacc, meanv, stdv, out);
}

// Round 14
// 334.845 us; speedup vs baseline: 1.4282x; 1.0615x over previous
//
#include <hip/hip_runtime.h>
#include <hip/hip_bf16.h>
#include <math.h>

// ---------------- problem constants ----------------
#define BATCH   32
#define LSEQ    512
#define ENC_IN  8
#define MARKD   4
#define DMODEL  512
#define DSTATE  16
#define DINNER  1024
#define DTRANK  32
#define PREDLEN 96
#define MROWS   (BATCH * LSEQ)          // 16384
#define TSTART  (LSEQ - PREDLEN)        // 416
#define NCHUNK  4                       // 4 x 104 steps over [0,416)
#define CHUNKT  104

// ---------------- workspace layout (float units), total 107.5 MiB ----------------
#define OFF_XN    ((size_t)0)            // 131072
#define OFF_MEAN  ((size_t)131072)       // 256
#define OFF_STD   ((size_t)131328)       // 256
#define OFF_WF    ((size_t)131584)       // 1024
#define OFF_WBX   ((size_t)132608)       // x_proj_w bf16: 32768 f
#define OFF_DPWB  ((size_t)165376)       // dt_proj_w bf16: 16384 f
#define OFF_OACC  ((size_t)181760)       // 32*96 fp32 atomic accumulator = 3072 f
#define OFF_XB    ((size_t)919040)       // 16384x512 bf16 = 4194304 f (ab overlays)
#define OFF_WB    ((size_t)5113344)      // 2048x512 bf16 = 524288 f
#define OFF_DTIN  ((size_t)5637632)      // dt_in bf16 = 262144 f (wfp overlays early)
#define OFF_BT    ((size_t)6161920)      // B [b][t][s] fp32 = 262144 f
#define OFF_CT    ((size_t)6424064)      // C [b][t][s] fp32 = 262144 f
#define OFF_GST   ((size_t)6686208)      // 32x1024x96 fp32 (g -> gw, read-only in scan)
#define OFF_XIT   ((size_t)9831936)      // [b][d][t] bf16 = 8388608 f (dtT overlays)
#define OFF_UT    ((size_t)18220544)     // [b][d][t] bf16 = 8388608 f
#define OFF_C0    ((size_t)26609152)     // 32x1024x96 bf16 = 1572864 f
#define OFF_DTT   OFF_XIT
#define OFF_AB    OFF_XB                 // 32*1024*4*16*2 fp32 = 4194304 f exact fit
#define OFF_WFP   OFF_DTIN
// end: 28182016 floats = 107.5 MiB

typedef __bf16 bf16_8 __attribute__((ext_vector_type(8)));
typedef float  f32x4  __attribute__((ext_vector_type(4)));

#define EXP2F(x) __builtin_amdgcn_exp2f(x)
#define LOG2F(x) __builtin_amdgcn_logf(x)

typedef __attribute__((address_space(3))) unsigned lds_u32;
typedef const __attribute__((address_space(1))) unsigned glb_u32;
#define ASYNC_LDS16(gsrc, ldst) \
    __builtin_amdgcn_global_load_lds((glb_u32*)(gsrc), (lds_u32*)(ldst), 16, 0, 0)

static __device__ __forceinline__ float b2f(unsigned short h) {
    union { float f; unsigned u; } v; v.u = ((unsigned)h) << 16; return v.f;
}
static __device__ __forceinline__ unsigned short f2b(float f) {
    __hip_bfloat16 h = __float2bfloat16(f);   // RNE
    union { __hip_bfloat16 b; unsigned short s; } v; v.b = h; return v.s;
}
static __device__ __forceinline__ float blo(unsigned v) {
    union { float f; unsigned u; } x; x.u = v << 16; return x.f;
}
static __device__ __forceinline__ float bhi(unsigned v) {
    union { float f; unsigned u; } x; x.u = v & 0xffff0000u; return x.f;
}

// ============ k_front: fusew-partials | w2b x3 | norm | zero oacc ============
__global__ __launch_bounds__(256) void k_front(const float* __restrict__ opw,
                                               const float* __restrict__ ow,
                                               const float* __restrict__ in_proj_w,
                                               const float* __restrict__ x_proj_w,
                                               const float* __restrict__ dpw,
                                               const float* __restrict__ xe,
                                               float* __restrict__ wfp,
                                               unsigned short* __restrict__ wb,
                                               unsigned short* __restrict__ wbx,
                                               unsigned short* __restrict__ dpwb,
                                               float* __restrict__ xn,
                                               float* __restrict__ meanv,
                                               float* __restrict__ stdv,
                                               float* __restrict__ oacc) {
    int bid = blockIdx.x;
    int tid = threadIdx.x;
    if (bid < 16) {
        int q = bid >> 2;
        int i = (bid & 3) * 256 + tid;
        float acc = 0.f;
        for (int dd = q * 128; dd < q * 128 + 128; ++dd)
            acc += opw[(size_t)dd * DINNER + i] * ow[dd];
        wfp[(size_t)q * DINNER + i] = acc;
    } else if (bid < 1040) {
        int i = ((bid - 16) * 256 + tid) * 4;
        float4 v = *(const float4*)(in_proj_w + i);
        ushort4 o; o.x = f2b(v.x); o.y = f2b(v.y); o.z = f2b(v.z); o.w = f2b(v.w);
        *(ushort4*)(wb + i) = o;
    } else if (bid < 1104) {
        int i = ((bid - 1040) * 256 + tid) * 4;
        float4 v = *(const float4*)(x_proj_w + i);
        ushort4 o; o.x = f2b(v.x); o.y = f2b(v.y); o.z = f2b(v.z); o.w = f2b(v.w);
        *(ushort4*)(wbx + i) = o;
    } else if (bid < 1136) {
        int i = ((bid - 1104) * 256 + tid) * 4;
        float4 v = *(const float4*)(dpw + i);
        ushort4 o; o.x = f2b(v.x); o.y = f2b(v.y); o.z = f2b(v.z); o.w = f2b(v.w);
        *(ushort4*)(dpwb + i) = o;
    } else if (bid < 1200) {
        int wv   = tid >> 6;
        int lane = tid & 63;
        int idx  = (bid - 1136) * 4 + wv;
        int c = idx & 7, b = idx >> 3;
        const float* p = xe + ((size_t)b * LSEQ) * ENC_IN + c;
        float vals[8];
        float s = 0.f, s2 = 0.f;
#pragma unroll
        for (int i = 0; i < 8; ++i) {
            float v = p[(size_t)(lane + i * 64) * ENC_IN];
            vals[i] = v; s += v; s2 += v * v;
        }
#pragma unroll
        for (int off = 32; off; off >>= 1) {
            s  += __shfl_xor(s,  off);
            s2 += __shfl_xor(s2, off);
        }
        float mean = s * (1.f / LSEQ);
        float var  = s2 * (1.f / LSEQ) - mean * mean;
        float sd   = sqrtf(var + 1e-5f);
        float rstd = 1.f / sd;
        if (lane == 0) { meanv[b * ENC_IN + c] = mean; stdv[b * ENC_IN + c] = sd; }
#pragma unroll
        for (int i = 0; i < 8; ++i)
            xn[((size_t)b * LSEQ + lane + i * 64) * ENC_IN + c] = (vals[i] - mean) * rstd;
    } else {
        for (int i = tid; i < BATCH * PREDLEN; i += 256) oacc[i] = 0.f;
    }
}

// ============ k_front2: build_x + fusew2 ============
__global__ __launch_bounds__(256) void k_front2(const float* __restrict__ xn,
                                                const float* __restrict__ xmark,
                                                const float* __restrict__ convw,
                                                const float* __restrict__ tempw,
                                                const float* __restrict__ wfp,
                                                unsigned short* __restrict__ xb,
                                                float* __restrict__ wfv) {
    int bid = blockIdx.x;
    int tid = threadIdx.x;
    if (bid >= 32768) {
        int i = (bid - 32768) * 256 + tid;
        wfv[i] = wfp[i] + wfp[DINNER + i] + wfp[2 * DINNER + i] + wfp[3 * DINNER + i];
        return;
    }
    int d = (bid & 1) * 256 + tid;
    int l = (bid >> 1) & (LSEQ - 1);
    int b = bid >> 10;
    int lm = (l + LSEQ - 1) & (LSEQ - 1);
    int lp = (l + 1) & (LSEQ - 1);
    const float* r0 = xn + ((size_t)b * LSEQ + lm) * ENC_IN;
    const float* r1 = xn + ((size_t)b * LSEQ + l ) * ENC_IN;
    const float* r2 = xn + ((size_t)b * LSEQ + lp) * ENC_IN;
    const float* w  = convw + (size_t)d * (ENC_IN * 3);
    float acc = 0.f;
#pragma unroll
    for (int i = 0; i < ENC_IN; ++i)
        acc += r0[i] * w[i * 3 + 0] + r1[i] * w[i * 3 + 1] + r2[i] * w[i * 3 + 2];
    const float* tw = tempw + (size_t)d * MARKD;
    const float* xm = xmark + ((size_t)b * LSEQ + l) * MARKD;
    acc += xm[0] * tw[0] + xm[1] * tw[1] + xm[2] * tw[2] + xm[3] * tw[3];
    float freq = __expf(-(float)(d & ~1) * (9.210340371976184f / (float)DMODEL));
    float rev  = (float)l * freq * 0.15915494309189535f;
    rev = rev - floorf(rev);
    acc += (d & 1) ? __builtin_amdgcn_cosf(rev) : __builtin_amdgcn_sinf(rev);
    xb[((size_t)b * LSEQ + l) * DMODEL + d] = f2b(acc);
}

// ============ Kernel C1: xi-side in_proj GEMM, 256x256 tile, 512 thr, BK=64 ============
// grid (4, 64) = 256 blocks = 1/CU.  Staged traffic halved vs 128-tile.
#define XI_TS 264   // transpose stride (shorts)
__global__ __launch_bounds__(512) void k_gemm_xi(const unsigned short* __restrict__ xb,
                                                 const unsigned short* __restrict__ wb,
                                                 unsigned short* __restrict__ xiT) {
    __shared__ uint4 smem4[4096];          // 64 KB: A[2048] + B[2048]
    uint4* As4 = smem4;
    uint4* Bs4 = smem4 + 2048;
    unsigned short* T = (unsigned short*)smem4;   // epilogue transpose (64 x 264)

    int tid  = threadIdx.x;
    int lane = tid & 63;
    int w    = tid >> 6;                   // 0..7
    int wm   = (w & 3) * 64;               // wave row offset (4 waves x 64 = 256)
    int wn   = (w >> 2) * 128;             // wave col offset (2 waves x 128 = 256)
    int n0 = blockIdx.x * 256;
    int m0 = blockIdx.y * 256;
    int quad = lane >> 4;
    int col  = lane & 15;

    f32x4 acc[4][8] = {};

    for (int k0 = 0; k0 < DMODEL; k0 += 64) {
        // stage A,B: 2048 chunks each of 16B; 4 async instr per wave per matrix
#pragma unroll
        for (int i = 0; i < 4; ++i) {
            int c  = w * 256 + i * 64 + lane;      // 0..2047
            int ks = c >> 10;                       // k-subblock 0/1
            int fi = (c >> 6) & 15;                 // frag index
            int lc = c & 63;
            int r  = fi * 16 + (lc & 15);
            int kq = lc >> 4;
            ASYNC_LDS16(xb + (size_t)(m0 + r) * DMODEL + k0 + ks * 32 + kq * 8,
                        As4 + (w * 256 + i * 64));
            ASYNC_LDS16(wb + (size_t)(n0 + r) * DMODEL + k0 + ks * 32 + kq * 8,
                        Bs4 + (w * 256 + i * 64));
        }
        __syncthreads();
#pragma unroll
        for (int ks = 0; ks < 2; ++ks) {
            bf16_8 af[4];
#pragma unroll
            for (int i = 0; i < 4; ++i)
                af[i] = ((const bf16_8*)As4)[ks * 1024 + ((wm >> 4) + i) * 64 + lane];
#pragma unroll
            for (int j = 0; j < 8; ++j) {
                bf16_8 bf = ((const bf16_8*)Bs4)[ks * 1024 + ((wn >> 4) + j) * 64 + lane];
#pragma unroll
                for (int i = 0; i < 4; ++i)
                    acc[i][j] = __builtin_amdgcn_mfma_f32_16x16x32_bf16(af[i], bf, acc[i][j], 0, 0, 0);
            }
        }
        __syncthreads();
    }

    // epilogue: 4 passes of 64 n-rows through LDS transpose, coalesced writes
    int bI = m0 >> 9;
    int tglob = m0 & (LSEQ - 1);
#pragma unroll
    for (int p = 0; p < 4; ++p) {
        if ((w >> 2) == (p >> 1)) {
            int jbase = (p & 1) * 4;
#pragma unroll
            for (int i = 0; i < 4; ++i) {
#pragma unroll
                for (int jj = 0; jj < 4; ++jj) {
                    int j = jbase + jj;
                    int nn = jj * 16 + col;
                    int mm = wm + i * 16 + quad * 4;
                    ushort4 o;
                    o.x = f2b(acc[i][j][0]); o.y = f2b(acc[i][j][1]);
                    o.z = f2b(acc[i][j][2]); o.w = f2b(acc[i][j][3]);
                    *(ushort4*)&T[nn * XI_TS + mm] = o;
                }
            }
        }
        __syncthreads();
#pragma unroll
        for (int it = 0; it < 4; ++it) {
            int c  = tid + it * 512;       // 0..2047
            int nn = c >> 5;               // 0..63
            int tc = c & 31;               // 0..31 (8-t chunks over 256 t)
            uint4 v = *(const uint4*)&T[nn * XI_TS + tc * 8];
            *(uint4*)(xiT + ((size_t)bI * DINNER + n0 + p * 64 + nn) * LSEQ + tglob + tc * 8) = v;
        }
        __syncthreads();
    }
}

// ============ Kernel C2: z-side in_proj GEMM (only t in [384,512)), 128x128 tile ============
// grid (8, 32): n0 = 1024 + bx*128, m0 = by*512 + 384.  Writes silu(z)*... -> gsT.
__global__ __launch_bounds__(256) void k_gemm_z(const unsigned short* __restrict__ xb,
                                                const unsigned short* __restrict__ wb,
                                                float* __restrict__ gsT) {
    __shared__ uint4 As4[512];   // 8 KB
    __shared__ uint4 Bs4[512];   // 8 KB
    int n0 = 1024 + blockIdx.x * 128;
    int m0 = blockIdx.y * 512 + 384;
    int tid  = threadIdx.x;
    int lane = tid & 63;
    int w    = tid >> 6;
    int wm   = (w & 1) * 64;
    int wn   = (w >> 1) * 64;
    f32x4 acc[4][4] = {};

    for (int k0 = 0; k0 < DMODEL; k0 += 32) {
#pragma unroll
        for (int hh = 0; hh < 2; ++hh) {
            int c  = tid + hh * 256;
            int im = c >> 6;
            int lc = c & 63;
            int r  = im * 16 + (lc & 15);
            int kq = lc >> 4;
            ASYNC_LDS16(xb + (size_t)(m0 + r) * DMODEL + k0 + kq * 8,
                        As4 + (w * 64 + hh * 256));
            ASYNC_LDS16(wb + (size_t)(n0 + r) * DMODEL + k0 + kq * 8,
                        Bs4 + (w * 64 + hh * 256));
        }
        __syncthreads();
        bf16_8 af[4], bf[4];
#pragma unroll
        for (int i = 0; i < 4; ++i) {
            af[i] = ((const bf16_8*)As4)[((wm >> 4) + i) * 64 + lane];
            bf[i] = ((const bf16_8*)Bs4)[((wn >> 4) + i) * 64 + lane];
        }
#pragma unroll
        for (int i = 0; i < 4; ++i)
#pragma unroll
            for (int j = 0; j < 4; ++j)
                acc[i][j] = __builtin_amdgcn_mfma_f32_16x16x32_bf16(af[i], bf[j], acc[i][j], 0, 0, 0);
        __syncthreads();
    }

    int col  = lane & 15;
    int quad = lane >> 4;
#pragma unroll
    for (int i = 0; i < 4; ++i) {
#pragma unroll
        for (int j = 0; j < 4; ++j) {
            int m = m0 + wm + i * 16 + quad * 4;
            int t = m & (LSEQ - 1);
            if (t < TSTART) continue;
            int b = m >> 9;
            int nz = n0 - DINNER + wn + j * 16 + col;
            float4 g;
            float v0 = acc[i][j][0], v1 = acc[i][j][1], v2 = acc[i][j][2], v3 = acc[i][j][3];
            g.x = v0 / (1.f + __expf(-v0));
            g.y = v1 / (1.f + __expf(-v1));
            g.z = v2 / (1.f + __expf(-v2));
            g.w = v3 / (1.f + __expf(-v3));
            *(float4*)(gsT + ((size_t)b * DINNER + nz) * PREDLEN + (t - TSTART)) = g;
        }
    }
}

// ============ Kernel D: depthwise conv + silu; gw=g*wf in place; c0=u*D*g*wf ============
__global__ __launch_bounds__(256) void k_dwconv_silu(const unsigned short* __restrict__ xiT,
                                                     const float* __restrict__ cw,
                                                     const float* __restrict__ cb,
                                                     const float* __restrict__ wfv,
                                                     const float* __restrict__ Dvec,
                                                     float* __restrict__ gsT,
                                                     unsigned short* __restrict__ c0,
                                                     unsigned short* __restrict__ uT) {
    int lane = threadIdx.x & 63;
    int w    = threadIdx.x >> 6;
    int d = blockIdx.x * 4 + w;
    int b = blockIdx.y;
    const unsigned short* src = xiT + ((size_t)b * DINNER + d) * LSEQ;
    uint4 cur = *(const uint4*)(src + lane * 8);
    unsigned pw = (unsigned)__shfl_up((int)cur.w, 1);
    unsigned pz = (unsigned)__shfl_up((int)cur.z, 1);
    if (lane == 0) { pw = 0u; pz = 0u; }
    float4 w4 = *(const float4*)(cw + (size_t)d * 4);
    float bias = cb[d];
    float win[11];
    win[0] = bhi(pz); win[1] = blo(pw); win[2] = bhi(pw);
    const unsigned* cp = (const unsigned*)&cur;
#pragma unroll
    for (int q = 0; q < 4; ++q) {
        win[3 + 2 * q] = blo(cp[q]);
        win[4 + 2 * q] = bhi(cp[q]);
    }
    float uvf[8];
    unsigned ov[4];
#pragma unroll
    for (int tt = 0; tt < 8; ++tt) {
        float a = bias + win[tt] * w4.x + win[tt + 1] * w4.y
                       + win[tt + 2] * w4.z + win[tt + 3] * w4.w;
        float uv = a / (1.f + __expf(-a));
        uvf[tt] = uv;
        unsigned short us = f2b(uv);
        if (tt & 1) ov[tt >> 1] |= ((unsigned)us) << 16;
        else        ov[tt >> 1]  = us;
    }
    *(uint4*)(uT + ((size_t)b * DINNER + d) * LSEQ + lane * 8) = *(uint4*)ov;
    if (lane >= 52) {
        int tl0 = lane * 8 - TSTART;
        float wfd = wfv[d];
        float Dd  = Dvec[d];
        float* gp = gsT + ((size_t)b * DINNER + d) * PREDLEN + tl0;
        float4 g0 = *(const float4*)gp;
        float4 g1 = *(const float4*)(gp + 4);
        float gg[8] = {g0.x, g0.y, g0.z, g0.w, g1.x, g1.y, g1.z, g1.w};
        unsigned cv[4];
#pragma unroll
        for (int j = 0; j < 8; ++j) {
            float gw = gg[j] * wfd;
            gg[j] = gw;
            unsigned short us = f2b(uvf[j] * Dd * gw);
            if (j & 1) cv[j >> 1] |= ((unsigned)us) << 16;
            else       cv[j >> 1]  = us;
        }
        *(float4*)gp       = make_float4(gg[0], gg[1], gg[2], gg[3]);
        *(float4*)(gp + 4) = make_float4(gg[4], gg[5], gg[6], gg[7]);
        *(uint4*)(c0 + ((size_t)b * DINNER + d) * PREDLEN + tl0) = *(uint4*)cv;
    }
}

// ============ Kernel E: x_proj GEMM via bf16 MFMA; B/C stored [b][t][s] ============
#define XPS 66
__global__ __launch_bounds__(256) void k_gemm_xproj2(const unsigned short* __restrict__ uT,
                                                     const unsigned short* __restrict__ wbx,
                                                     unsigned short* __restrict__ dt_in,
                                                     float* __restrict__ Bt2,
                                                     float* __restrict__ Ct2) {
    __shared__ unsigned short Asl[32 * XPS];
    int tid  = threadIdx.x;
    int lane = tid & 63;
    int w    = tid >> 6;
    int quad = lane >> 4;
    int col  = lane & 15;
    int m0 = blockIdx.x * 64;
    int b  = m0 >> 9;
    int t0 = m0 & (LSEQ - 1);
    int sk  = tid >> 3;
    int smc = (tid & 7) * 8;
    f32x4 acc[4] = {};
    uint4 v = *(const uint4*)(uT + ((size_t)b * DINNER + sk) * LSEQ + t0 + smc);
    for (int k0 = 0; k0 < DINNER; k0 += 32) {
        unsigned* dst = (unsigned*)&Asl[sk * XPS + smc];
        dst[0] = v.x; dst[1] = v.y; dst[2] = v.z; dst[3] = v.w;
        __syncthreads();
        if (k0 + 32 < DINNER)
            v = *(const uint4*)(uT + ((size_t)b * DINNER + k0 + 32 + sk) * LSEQ + t0 + smc);
        bf16_8 bf[4];
#pragma unroll
        for (int j = 0; j < 4; ++j)
            bf[j] = *((const bf16_8*)(wbx + (size_t)(j * 16 + col) * DINNER + k0 + quad * 8));
        union { bf16_8 v; unsigned short u[8]; } af;
#pragma unroll
        for (int j8 = 0; j8 < 8; ++j8)
            af.u[j8] = Asl[(quad * 8 + j8) * XPS + w * 16 + col];
#pragma unroll
        for (int j = 0; j < 4; ++j)
            acc[j] = __builtin_amdgcn_mfma_f32_16x16x32_bf16(af.v, bf[j], acc[j], 0, 0, 0);
        __syncthreads();
    }
    int mrow = m0 + w * 16 + quad * 4;
#pragma unroll
    for (int j = 0; j < 2; ++j)
#pragma unroll
        for (int r = 0; r < 4; ++r)
            dt_in[(size_t)(mrow + r) * DTRANK + j * 16 + col] = f2b(acc[j][r]);
    int t = t0 + w * 16 + quad * 4;
#pragma unroll
    for (int r = 0; r < 4; ++r) {
        Bt2[((size_t)b * LSEQ + t + r) * DSTATE + col] = acc[2][r];
        Ct2[((size_t)b * LSEQ + t + r) * DSTATE + col] = acc[3][r];
    }
}

// ============ Kernel F: dt_proj as MFMA GEMM (K=32) + softplus + transpose store ============
#define TP_STRIDE 136
__global__ __launch_bounds__(256) void k_dtproj2(const unsigned short* __restrict__ dt_in,
                                                 const unsigned short* __restrict__ dpwb,
                                                 const float* __restrict__ dpb,
                                                 unsigned short* __restrict__ dtT) {
    __shared__ unsigned char smem[128 * TP_STRIDE * 2];
    uint4* As4 = (uint4*)smem;
    uint4* Bs4 = As4 + 512;
    unsigned short* T = (unsigned short*)smem;
    int tid  = threadIdx.x;
    int lane = tid & 63;
    int w    = tid >> 6;
    int wm   = (w & 1) * 64;
    int wn   = (w >> 1) * 64;
    int n0 = blockIdx.x * 128;
    int m0 = blockIdx.y * 128;
#pragma unroll
    for (int hh = 0; hh < 2; ++hh) {
        int c  = tid + hh * 256;
        int im = c >> 6;
        int lc = c & 63;
        int r  = im * 16 + (lc & 15);
        int kq = lc >> 4;
        As4[c] = *(const uint4*)(dt_in + (size_t)(m0 + r) * DTRANK + kq * 8);
        Bs4[c] = *(const uint4*)(dpwb + (size_t)(n0 + r) * DTRANK + kq * 8);
    }
    __syncthreads();
    f32x4 acc[4][4] = {};
    bf16_8 af[4], bf[4];
#pragma unroll
    for (int i = 0; i < 4; ++i) {
        af[i] = ((const bf16_8*)As4)[((wm >> 4) + i) * 64 + lane];
        bf[i] = ((const bf16_8*)Bs4)[((wn >> 4) + i) * 64 + lane];
    }
#pragma unroll
    for (int i = 0; i < 4; ++i)
#pragma unroll
        for (int j = 0; j < 4; ++j)
            acc[i][j] = __builtin_amdgcn_mfma_f32_16x16x32_bf16(af[i], bf[j], acc[i][j], 0, 0, 0);
    __syncthreads();
    int col  = lane & 15;
    int quad = lane >> 4;
#pragma unroll
    for (int i = 0; i < 4; ++i) {
#pragma unroll
        for (int j = 0; j < 4; ++j) {
            int nn = wn + j * 16 + col;
            int mm = wm + i * 16 + quad * 4;
            float bias = dpb[n0 + nn];
            ushort4 o;
            unsigned short* op = (unsigned short*)&o;
#pragma unroll
            for (int r = 0; r < 4; ++r) {
                float a = acc[i][j][r] + bias;
                float sp = (a > 20.f) ? a
                         : 0.6931471805599453f * LOG2F(1.f + EXP2F(a * 1.44269504088896f));
                op[r] = f2b(sp);
            }
            *(ushort4*)&T[nn * TP_STRIDE + mm] = o;
        }
    }
    __syncthreads();
    int bI = m0 >> 9;
    int tglob = m0 & (LSEQ - 1);
#pragma unroll
    for (int it = 0; it < 8; ++it) {
        int c  = tid + it * 256;
        int nn = c >> 4;
        int tc = c & 15;
        uint4 v = *(const uint4*)&T[nn * TP_STRIDE + tc * 8];
        *(uint4*)(dtT + ((size_t)bI * DINNER + n0 + nn) * LSEQ + tglob + tc * 8) = v;
    }
}

// ============ Kernel G1: scan phase 1 — group-parallel exps, B from [b][t][s] ============
__global__ __launch_bounds__(256) void k_scan_p1(const unsigned short* __restrict__ uT,
                                                 const unsigned short* __restrict__ dtT,
                                                 const float* __restrict__ Bt2,
                                                 const float* __restrict__ A_log,
                                                 float2* __restrict__ ab) {
    int b = blockIdx.y;
    int c = blockIdx.z;
    int tid  = threadIdx.x;
    int lane = tid & 63;
    int w    = tid >> 6;
    int q    = lane & 3;
    int dloc = lane >> 2;
    int d    = blockIdx.x * 64 + w * 16 + dloc;
    float4 al = *(const float4*)(A_log + (size_t)d * DSTATE + q * 4);
    float As2[4];
    As2[0] = -__expf(al.x) * 1.44269504088896f;
    As2[1] = -__expf(al.y) * 1.44269504088896f;
    As2[2] = -__expf(al.z) * 1.44269504088896f;
    As2[3] = -__expf(al.w) * 1.44269504088896f;
    float beta[4] = {0.f, 0.f, 0.f, 0.f};
    float asum = 0.f;
    const unsigned short* up = uT  + ((size_t)b * DINNER + d) * LSEQ;
    const unsigned short* dp = dtT + ((size_t)b * DINNER + d) * LSEQ;
    const float* Bp = Bt2 + (size_t)b * LSEQ * DSTATE + q * 4;
    int tbeg = c * CHUNKT;
    for (int t8 = tbeg; t8 < tbeg + CHUNKT; t8 += 8) {
        uint4 uq = *(const uint4*)(up + t8);
        uint4 dq = *(const uint4*)(dp + t8);
        float4 Bq[8];
#pragma unroll
        for (int j = 0; j < 8; ++j)
            Bq[j] = *(const float4*)(Bp + (size_t)(t8 + j) * DSTATE);
        float uu[8], dd[8];
        const unsigned* uqp = (const unsigned*)&uq;
        const unsigned* dqp = (const unsigned*)&dq;
#pragma unroll
        for (int p = 0; p < 4; ++p) {
            uu[p * 2] = blo(uqp[p]); uu[p * 2 + 1] = bhi(uqp[p]);
            dd[p * 2] = blo(dqp[p]); dd[p * 2 + 1] = bhi(dqp[p]);
        }
        float S[8];
        S[0] = dd[0];
#pragma unroll
        for (int j = 1; j < 8; ++j) S[j] = S[j - 1] + dd[j];
        float G = S[7];
        float g0 = 0.f, g1 = 0.f, g2 = 0.f, g3 = 0.f;
#pragma unroll
        for (int j = 0; j < 8; ++j) {
            float w8 = dd[j] * uu[j];
            float p8 = G - S[j];
            g0 += EXP2F(As2[0] * p8) * (w8 * Bq[j].x);
            g1 += EXP2F(As2[1] * p8) * (w8 * Bq[j].y);
            g2 += EXP2F(As2[2] * p8) * (w8 * Bq[j].z);
            g3 += EXP2F(As2[3] * p8) * (w8 * Bq[j].w);
        }
        beta[0] = EXP2F(As2[0] * G) * beta[0] + g0;
        beta[1] = EXP2F(As2[1] * G) * beta[1] + g1;
        beta[2] = EXP2F(As2[2] * G) * beta[2] + g2;
        beta[3] = EXP2F(As2[3] * G) * beta[3] + g3;
        asum += G;
    }
    float2* abp = ab + ((size_t)(b * DINNER + d) * NCHUNK + c) * DSTATE + q * 4;
#pragma unroll
    for (int si = 0; si < 4; ++si)
        abp[si] = make_float2(EXP2F(asum * As2[si]), beta[si]);
}

// ============ Kernel G2: stitch h(416), run [416,512); LDS B/C; block-reduce + atomic ============
__global__ __launch_bounds__(256) void k_scan_p3(const unsigned short* __restrict__ uT,
                                                 const unsigned short* __restrict__ dtT,
                                                 const float* __restrict__ Bt2,
                                                 const float* __restrict__ Ct2,
                                                 const float* __restrict__ A_log,
                                                 const float* __restrict__ gsT,
                                                 const unsigned short* __restrict__ c0,
                                                 const float2* __restrict__ ab,
                                                 float* __restrict__ oacc) {
    __shared__ float BsL[PREDLEN * DSTATE];
    __shared__ float CsL[PREDLEN * DSTATE];
    __shared__ float accL[16][100];
    int b    = blockIdx.y;
    int tid  = threadIdx.x;
    int s    = tid & 15;
    int dloc = (tid >> 4) & 3;
    int w    = tid >> 6;
    int d    = blockIdx.x * 16 + (tid >> 4);
    for (int i = tid; i < (PREDLEN * DSTATE) / 4; i += 256) {
        ((float4*)BsL)[i] = *((const float4*)(Bt2 + ((size_t)b * LSEQ + TSTART) * DSTATE) + i);
        ((float4*)CsL)[i] = *((const float4*)(Ct2 + ((size_t)b * LSEQ + TSTART) * DSTATE) + i);
    }
    float As2 = -__expf(A_log[(size_t)d * DSTATE + s]) * 1.44269504088896f;
    const float2* abp = ab + (size_t)(b * DINNER + d) * NCHUNK * DSTATE + s;
    float h = 0.f;
#pragma unroll
    for (int c = 0; c < NCHUNK; ++c) {
        float2 v = abp[c * DSTATE];
        h = v.y + v.x * h;
    }
    const unsigned short* up = uT  + ((size_t)b * DINNER + d) * LSEQ;
    const unsigned short* dp = dtT + ((size_t)b * DINNER + d) * LSEQ;
    const float* gp = gsT + ((size_t)b * DINNER + d) * PREDLEN;
    const unsigned short* cp0 = c0 + ((size_t)b * DINNER + d) * PREDLEN;
    __syncthreads();
    for (int t8 = TSTART; t8 < LSEQ; t8 += 8) {
        int tl0 = t8 - TSTART;
        uint4 uq = *(const uint4*)(up + t8);
        uint4 dq = *(const uint4*)(dp + t8);
        float4 g0 = *(const float4*)(gp + tl0);
        float4 g1 = *(const float4*)(gp + tl0 + 4);
        uint4 cq = *(const uint4*)(cp0 + tl0);
        float Bv[8], Cv[8];
#pragma unroll
        for (int j = 0; j < 8; ++j) {
            Bv[j] = BsL[(tl0 + j) * DSTATE + s];
            Cv[j] = CsL[(tl0 + j) * DSTATE + s];
        }
        float uu[8], dd[8];
        const unsigned* uqp = (const unsigned*)&uq;
        const unsigned* dqp = (const unsigned*)&dq;
#pragma unroll
        for (int p = 0; p < 4; ++p) {
            uu[p * 2] = blo(uqp[p]); uu[p * 2 + 1] = bhi(uqp[p]);
            dd[p * 2] = blo(dqp[p]); dd[p * 2 + 1] = bhi(dqp[p]);
        }
        float y[8];
#pragma unroll
        for (int j = 0; j < 8; ++j) {
            h = EXP2F(dd[j] * As2) * h + (dd[j] * uu[j]) * Bv[j];
            y[j] = h * Cv[j];
        }
#pragma unroll
        for (int j = 0; j < 8; ++j) y[j] += __shfl_xor(y[j], 1);
#pragma unroll
        for (int j = 0; j < 8; ++j) y[j] += __shfl_xor(y[j], 2);
#pragma unroll
        for (int j = 0; j < 8; ++j) y[j] += __shfl_xor(y[j], 4);
#pragma unroll
        for (int j = 0; j < 8; ++j) y[j] += __shfl_xor(y[j], 8);
        float gv[8] = {g0.x, g0.y, g0.z, g0.w, g1.x, g1.y, g1.z, g1.w};
        const unsigned* cqp = (const unsigned*)&cq;
#pragma unroll
        for (int j = 0; j < 8; ++j) {
            float cf = (j & 1) ? bhi(cqp[j >> 1]) : blo(cqp[j >> 1]);
            float z  = y[j] * gv[j] + cf;
            if (s == 0) accL[w * 4 + dloc][tl0 + j] = z;
        }
    }
    __syncthreads();
    if (tid < PREDLEN) {
        float tot = 0.f;
#pragma unroll
        for (int k = 0; k < 16; ++k) tot += accL[k][tid];
        atomicAdd(&oacc[b * PREDLEN + tid], tot);
    }
}

// ============ Kernel H: scale accumulated outputs + de-normalize ============
__global__ __launch_bounds__(256) void k_final3(const float* __restrict__ oacc,
                                                const float* __restrict__ meanv,
                                                const float* __restrict__ stdv,
                                                float* __restrict__ out) {
    int idx = blockIdx.x * 256 + threadIdx.x;
    int b = idx / PREDLEN;
    out[idx] = oacc[idx] * stdv[b * ENC_IN] + meanv[b * ENC_IN];
}

// ---------------- launch ----------------
extern "C" void kernel_launch(void* const* d_in, const int* in_sizes, int n_in,
                              void* d_out, int out_size, void* d_ws, size_t ws_size,
                              hipStream_t stream) {
    const float* x_enc     = (const float*)d_in[0];
    const float* x_mark    = (const float*)d_in[1];
    const float* conv_w    = (const float*)d_in[2];
    const float* temp_w    = (const float*)d_in[3];
    const float* in_proj_w = (const float*)d_in[4];
    const float* conv1d_w  = (const float*)d_in[5];
    const float* conv1d_b  = (const float*)d_in[6];
    const float* x_proj_w  = (const float*)d_in[7];
    const float* dt_proj_w = (const float*)d_in[8];
    const float* dt_proj_b = (const float*)d_in[9];
    const float* A_log     = (const float*)d_in[10];
    const float* Dvec      = (const float*)d_in[11];
    const float* out_proj_w= (const float*)d_in[12];
    const float* out_w     = (const float*)d_in[13];
    float* ws  = (float*)d_ws;
    float* out = (float*)d_out;

    float* xn    = ws + OFF_XN;
    float* meanv = ws + OFF_MEAN;
    float* stdv  = ws + OFF_STD;
    float* wfv   = ws + OFF_WF;
    float* wfp   = ws + OFF_WFP;
    float* oacc  = ws + OFF_OACC;
    float* Btv   = ws + OFF_BT;
    float* Ctv   = ws + OFF_CT;
    float* gsT   = ws + OFF_GST;
    unsigned short* xb    = (unsigned short*)(ws + OFF_XB);
    unsigned short* wb    = (unsigned short*)(ws + OFF_WB);
    unsigned short* wbx   = (unsigned short*)(ws + OFF_WBX);
    unsigned short* dpwb  = (unsigned short*)(ws + OFF_DPWB);
    unsigned short* dtinb = (unsigned short*)(ws + OFF_DTIN);
    unsigned short* xiT   = (unsigned short*)(ws + OFF_XIT);
    unsigned short* uT    = (unsigned short*)(ws + OFF_UT);
    unsigned short* dtT   = (unsigned short*)(ws + OFF_DTT);
    unsigned short* c0    = (unsigned short*)(ws + OFF_C0);
    float2* ab = (float2*)(ws + OFF_AB);

    k_front<<<dim3(1201), 256, 0, stream>>>(out_proj_w, out_w, in_proj_w, x_proj_w, dt_proj_w,
                                            x_enc, wfp, wb, wbx, dpwb, xn, meanv, stdv, oacc);
    k_front2<<<dim3(32772), 256, 0, stream>>>(xn, x_mark, conv_w, temp_w, wfp, xb, wfv);
    k_gemm_xi<<<dim3(4, 64), 512, 0, stream>>>(xb, wb, xiT);
    k_gemm_z<<<dim3(8, 32), 256, 0, stream>>>(xb, wb, gsT);
    k_dwconv_silu<<<dim3(DINNER / 4, BATCH), 256, 0, stream>>>(xiT, conv1d_w, conv1d_b,
                                                               wfv, Dvec, gsT, c0, uT);
    k_gemm_xproj2<<<dim3(MROWS / 64), 256, 0, stream>>>(uT, wbx, dtinb, Btv, Ctv);
    k_dtproj2<<<dim3(8, 128), 256, 0, stream>>>(dtinb, dpwb, dt_proj_b, dtT);
    k_scan_p1<<<dim3(DINNER / 64, BATCH, NCHUNK), 256, 0, stream>>>(uT, dtT, Btv, A_log, ab);
    k_scan_p3<<<dim3(DINNER / 16, BATCH), 256, 0, stream>>>(uT, dtT, Btv, Ctv, A_log,
                                                            gsT, c0, ab, oacc);
    k_final3<<<dim3((BATCH * PREDLEN) / 256), 256, 0, stream>>>(oacc, meanv, stdv, out);
}

// Round 15
// 323.029 us; speedup vs baseline: 1.4805x; 1.0366x over previous
//
#include <hip/hip_runtime.h>
#include <hip/hip_bf16.h>
#include <math.h>

// ---------------- problem constants ----------------
#define BATCH   32
#define LSEQ    512
#define ENC_IN  8
#define MARKD   4
#define DMODEL  512
#define DSTATE  16
#define DINNER  1024
#define DTRANK  32
#define PREDLEN 96
#define MROWS   (BATCH * LSEQ)          // 16384
#define TSTART  (LSEQ - PREDLEN)        // 416
#define NCHUNK  4                       // 4 x 104 steps over [0,416)
#define CHUNKT  104

// ---------------- workspace layout (float units), total 107.5 MiB ----------------
#define OFF_XN    ((size_t)0)            // 131072
#define OFF_MEAN  ((size_t)131072)       // 256
#define OFF_STD   ((size_t)131328)       // 256
#define OFF_WF    ((size_t)131584)       // 1024
#define OFF_WBX   ((size_t)132608)       // x_proj_w bf16: 32768 f
#define OFF_DPWB  ((size_t)165376)       // dt_proj_w bf16: 16384 f
#define OFF_OACC  ((size_t)181760)       // 32*96 fp32 atomic accumulator = 3072 f
#define OFF_XB    ((size_t)919040)       // 16384x512 bf16 = 4194304 f (ab overlays)
#define OFF_WB    ((size_t)5113344)      // 2048x512 bf16 = 524288 f
#define OFF_DTIN  ((size_t)5637632)      // dt_in bf16 = 262144 f (wfp overlays early)
#define OFF_BT    ((size_t)6161920)      // B [b][t][s] fp32 = 262144 f
#define OFF_CT    ((size_t)6424064)      // C [b][t][s] fp32 = 262144 f
#define OFF_GST   ((size_t)6686208)      // 32x1024x96 fp32 (g -> gw, read-only in scan)
#define OFF_XIT   ((size_t)9831936)      // [b][d][t] bf16 = 8388608 f (dtT overlays)
#define OFF_UT    ((size_t)18220544)     // [b][d][t] bf16 = 8388608 f
#define OFF_C0    ((size_t)26609152)     // 32x1024x96 bf16 = 1572864 f
#define OFF_DTT   OFF_XIT
#define OFF_AB    OFF_XB                 // 32*1024*4*16*2 fp32 = 4194304 f exact fit
#define OFF_WFP   OFF_DTIN
// end: 28182016 floats = 107.5 MiB

typedef __bf16 bf16_8 __attribute__((ext_vector_type(8)));
typedef float  f32x4  __attribute__((ext_vector_type(4)));

#define EXP2F(x) __builtin_amdgcn_exp2f(x)
#define LOG2F(x) __builtin_amdgcn_logf(x)

typedef __attribute__((address_space(3))) unsigned lds_u32;
typedef const __attribute__((address_space(1))) unsigned glb_u32;
#define ASYNC_LDS16(gsrc, ldst) \
    __builtin_amdgcn_global_load_lds((glb_u32*)(gsrc), (lds_u32*)(ldst), 16, 0, 0)

static __device__ __forceinline__ float b2f(unsigned short h) {
    union { float f; unsigned u; } v; v.u = ((unsigned)h) << 16; return v.f;
}
static __device__ __forceinline__ unsigned short f2b(float f) {
    __hip_bfloat16 h = __float2bfloat16(f);   // RNE
    union { __hip_bfloat16 b; unsigned short s; } v; v.b = h; return v.s;
}
static __device__ __forceinline__ float blo(unsigned v) {
    union { float f; unsigned u; } x; x.u = v << 16; return x.f;
}
static __device__ __forceinline__ float bhi(unsigned v) {
    union { float f; unsigned u; } x; x.u = v & 0xffff0000u; return x.f;
}

// ============ k_front: fusew-partials | w2b x3 | norm | zero oacc ============
__global__ __launch_bounds__(256) void k_front(const float* __restrict__ opw,
                                               const float* __restrict__ ow,
                                               const float* __restrict__ in_proj_w,
                                               const float* __restrict__ x_proj_w,
                                               const float* __restrict__ dpw,
                                               const float* __restrict__ xe,
                                               float* __restrict__ wfp,
                                               unsigned short* __restrict__ wb,
                                               unsigned short* __restrict__ wbx,
                                               unsigned short* __restrict__ dpwb,
                                               float* __restrict__ xn,
                                               float* __restrict__ meanv,
                                               float* __restrict__ stdv,
                                               float* __restrict__ oacc) {
    int bid = blockIdx.x;
    int tid = threadIdx.x;
    if (bid < 16) {
        int q = bid >> 2;
        int i = (bid & 3) * 256 + tid;
        float acc = 0.f;
        for (int dd = q * 128; dd < q * 128 + 128; ++dd)
            acc += opw[(size_t)dd * DINNER + i] * ow[dd];
        wfp[(size_t)q * DINNER + i] = acc;
    } else if (bid < 1040) {
        int i = ((bid - 16) * 256 + tid) * 4;
        float4 v = *(const float4*)(in_proj_w + i);
        ushort4 o; o.x = f2b(v.x); o.y = f2b(v.y); o.z = f2b(v.z); o.w = f2b(v.w);
        *(ushort4*)(wb + i) = o;
    } else if (bid < 1104) {
        int i = ((bid - 1040) * 256 + tid) * 4;
        float4 v = *(const float4*)(x_proj_w + i);
        ushort4 o; o.x = f2b(v.x); o.y = f2b(v.y); o.z = f2b(v.z); o.w = f2b(v.w);
        *(ushort4*)(wbx + i) = o;
    } else if (bid < 1136) {
        int i = ((bid - 1104) * 256 + tid) * 4;
        float4 v = *(const float4*)(dpw + i);
        ushort4 o; o.x = f2b(v.x); o.y = f2b(v.y); o.z = f2b(v.z); o.w = f2b(v.w);
        *(ushort4*)(dpwb + i) = o;
    } else if (bid < 1200) {
        int wv   = tid >> 6;
        int lane = tid & 63;
        int idx  = (bid - 1136) * 4 + wv;
        int c = idx & 7, b = idx >> 3;
        const float* p = xe + ((size_t)b * LSEQ) * ENC_IN + c;
        float vals[8];
        float s = 0.f, s2 = 0.f;
#pragma unroll
        for (int i = 0; i < 8; ++i) {
            float v = p[(size_t)(lane + i * 64) * ENC_IN];
            vals[i] = v; s += v; s2 += v * v;
        }
#pragma unroll
        for (int off = 32; off; off >>= 1) {
            s  += __shfl_xor(s,  off);
            s2 += __shfl_xor(s2, off);
        }
        float mean = s * (1.f / LSEQ);
        float var  = s2 * (1.f / LSEQ) - mean * mean;
        float sd   = sqrtf(var + 1e-5f);
        float rstd = 1.f / sd;
        if (lane == 0) { meanv[b * ENC_IN + c] = mean; stdv[b * ENC_IN + c] = sd; }
#pragma unroll
        for (int i = 0; i < 8; ++i)
            xn[((size_t)b * LSEQ + lane + i * 64) * ENC_IN + c] = (vals[i] - mean) * rstd;
    } else {
        for (int i = tid; i < BATCH * PREDLEN; i += 256) oacc[i] = 0.f;
    }
}

// ============ k_front2: build_x + fusew2 ============
__global__ __launch_bounds__(256) void k_front2(const float* __restrict__ xn,
                                                const float* __restrict__ xmark,
                                                const float* __restrict__ convw,
                                                const float* __restrict__ tempw,
                                                const float* __restrict__ wfp,
                                                unsigned short* __restrict__ xb,
                                                float* __restrict__ wfv) {
    int bid = blockIdx.x;
    int tid = threadIdx.x;
    if (bid >= 32768) {
        int i = (bid - 32768) * 256 + tid;
        wfv[i] = wfp[i] + wfp[DINNER + i] + wfp[2 * DINNER + i] + wfp[3 * DINNER + i];
        return;
    }
    int d = (bid & 1) * 256 + tid;
    int l = (bid >> 1) & (LSEQ - 1);
    int b = bid >> 10;
    int lm = (l + LSEQ - 1) & (LSEQ - 1);
    int lp = (l + 1) & (LSEQ - 1);
    const float* r0 = xn + ((size_t)b * LSEQ + lm) * ENC_IN;
    const float* r1 = xn + ((size_t)b * LSEQ + l ) * ENC_IN;
    const float* r2 = xn + ((size_t)b * LSEQ + lp) * ENC_IN;
    const float* w  = convw + (size_t)d * (ENC_IN * 3);
    float acc = 0.f;
#pragma unroll
    for (int i = 0; i < ENC_IN; ++i)
        acc += r0[i] * w[i * 3 + 0] + r1[i] * w[i * 3 + 1] + r2[i] * w[i * 3 + 2];
    const float* tw = tempw + (size_t)d * MARKD;
    const float* xm = xmark + ((size_t)b * LSEQ + l) * MARKD;
    acc += xm[0] * tw[0] + xm[1] * tw[1] + xm[2] * tw[2] + xm[3] * tw[3];
    float freq = __expf(-(float)(d & ~1) * (9.210340371976184f / (float)DMODEL));
    float rev  = (float)l * freq * 0.15915494309189535f;
    rev = rev - floorf(rev);
    acc += (d & 1) ? __builtin_amdgcn_cosf(rev) : __builtin_amdgcn_sinf(rev);
    xb[((size_t)b * LSEQ + l) * DMODEL + d] = f2b(acc);
}

// ============ Kernel C1: xi-side in_proj GEMM, 256x256 tile, 512 thr, BK=64 ============
#define XI_TS 264
__global__ __launch_bounds__(512) void k_gemm_xi(const unsigned short* __restrict__ xb,
                                                 const unsigned short* __restrict__ wb,
                                                 unsigned short* __restrict__ xiT) {
    __shared__ uint4 smem4[4096];          // 64 KB: A[2048] + B[2048]
    uint4* As4 = smem4;
    uint4* Bs4 = smem4 + 2048;
    unsigned short* T = (unsigned short*)smem4;

    int tid  = threadIdx.x;
    int lane = tid & 63;
    int w    = tid >> 6;
    int wm   = (w & 3) * 64;
    int wn   = (w >> 2) * 128;
    int n0 = blockIdx.x * 256;
    int m0 = blockIdx.y * 256;
    int quad = lane >> 4;
    int col  = lane & 15;

    f32x4 acc[4][8] = {};

    for (int k0 = 0; k0 < DMODEL; k0 += 64) {
#pragma unroll
        for (int i = 0; i < 4; ++i) {
            int c  = w * 256 + i * 64 + lane;
            int ks = c >> 10;
            int fi = (c >> 6) & 15;
            int lc = c & 63;
            int r  = fi * 16 + (lc & 15);
            int kq = lc >> 4;
            ASYNC_LDS16(xb + (size_t)(m0 + r) * DMODEL + k0 + ks * 32 + kq * 8,
                        As4 + (w * 256 + i * 64));
            ASYNC_LDS16(wb + (size_t)(n0 + r) * DMODEL + k0 + ks * 32 + kq * 8,
                        Bs4 + (w * 256 + i * 64));
        }
        __syncthreads();
#pragma unroll
        for (int ks = 0; ks < 2; ++ks) {
            bf16_8 af[4];
#pragma unroll
            for (int i = 0; i < 4; ++i)
                af[i] = ((const bf16_8*)As4)[ks * 1024 + ((wm >> 4) + i) * 64 + lane];
#pragma unroll
            for (int j = 0; j < 8; ++j) {
                bf16_8 bf = ((const bf16_8*)Bs4)[ks * 1024 + ((wn >> 4) + j) * 64 + lane];
#pragma unroll
                for (int i = 0; i < 4; ++i)
                    acc[i][j] = __builtin_amdgcn_mfma_f32_16x16x32_bf16(af[i], bf, acc[i][j], 0, 0, 0);
            }
        }
        __syncthreads();
    }

    int bI = m0 >> 9;
    int tglob = m0 & (LSEQ - 1);
#pragma unroll
    for (int p = 0; p < 4; ++p) {
        if ((w >> 2) == (p >> 1)) {
            int jbase = (p & 1) * 4;
#pragma unroll
            for (int i = 0; i < 4; ++i) {
#pragma unroll
                for (int jj = 0; jj < 4; ++jj) {
                    int j = jbase + jj;
                    int nn = jj * 16 + col;
                    int mm = wm + i * 16 + quad * 4;
                    ushort4 o;
                    o.x = f2b(acc[i][j][0]); o.y = f2b(acc[i][j][1]);
                    o.z = f2b(acc[i][j][2]); o.w = f2b(acc[i][j][3]);
                    *(ushort4*)&T[nn * XI_TS + mm] = o;
                }
            }
        }
        __syncthreads();
#pragma unroll
        for (int it = 0; it < 4; ++it) {
            int c  = tid + it * 512;
            int nn = c >> 5;
            int tc = c & 31;
            uint4 v = *(const uint4*)&T[nn * XI_TS + tc * 8];
            *(uint4*)(xiT + ((size_t)bI * DINNER + n0 + p * 64 + nn) * LSEQ + tglob + tc * 8) = v;
        }
        __syncthreads();
    }
}

// ============ Kernel C2: z-side in_proj GEMM (only t in [384,512)), 128x128 tile ============
__global__ __launch_bounds__(256) void k_gemm_z(const unsigned short* __restrict__ xb,
                                                const unsigned short* __restrict__ wb,
                                                float* __restrict__ gsT) {
    __shared__ uint4 As4[512];
    __shared__ uint4 Bs4[512];
    int n0 = 1024 + blockIdx.x * 128;
    int m0 = blockIdx.y * 512 + 384;
    int tid  = threadIdx.x;
    int lane = tid & 63;
    int w    = tid >> 6;
    int wm   = (w & 1) * 64;
    int wn   = (w >> 1) * 64;
    f32x4 acc[4][4] = {};

    for (int k0 = 0; k0 < DMODEL; k0 += 32) {
#pragma unroll
        for (int hh = 0; hh < 2; ++hh) {
            int c  = tid + hh * 256;
            int im = c >> 6;
            int lc = c & 63;
            int r  = im * 16 + (lc & 15);
            int kq = lc >> 4;
            ASYNC_LDS16(xb + (size_t)(m0 + r) * DMODEL + k0 + kq * 8,
                        As4 + (w * 64 + hh * 256));
            ASYNC_LDS16(wb + (size_t)(n0 + r) * DMODEL + k0 + kq * 8,
                        Bs4 + (w * 64 + hh * 256));
        }
        __syncthreads();
        bf16_8 af[4], bf[4];
#pragma unroll
        for (int i = 0; i < 4; ++i) {
            af[i] = ((const bf16_8*)As4)[((wm >> 4) + i) * 64 + lane];
            bf[i] = ((const bf16_8*)Bs4)[((wn >> 4) + i) * 64 + lane];
        }
#pragma unroll
        for (int i = 0; i < 4; ++i)
#pragma unroll
            for (int j = 0; j < 4; ++j)
                acc[i][j] = __builtin_amdgcn_mfma_f32_16x16x32_bf16(af[i], bf[j], acc[i][j], 0, 0, 0);
        __syncthreads();
    }

    int col  = lane & 15;
    int quad = lane >> 4;
#pragma unroll
    for (int i = 0; i < 4; ++i) {
#pragma unroll
        for (int j = 0; j < 4; ++j) {
            int m = m0 + wm + i * 16 + quad * 4;
            int t = m & (LSEQ - 1);
            if (t < TSTART) continue;
            int b = m >> 9;
            int nz = n0 - DINNER + wn + j * 16 + col;
            float4 g;
            float v0 = acc[i][j][0], v1 = acc[i][j][1], v2 = acc[i][j][2], v3 = acc[i][j][3];
            g.x = v0 / (1.f + __expf(-v0));
            g.y = v1 / (1.f + __expf(-v1));
            g.z = v2 / (1.f + __expf(-v2));
            g.w = v3 / (1.f + __expf(-v3));
            *(float4*)(gsT + ((size_t)b * DINNER + nz) * PREDLEN + (t - TSTART)) = g;
        }
    }
}

// ============ Kernel D: depthwise conv + silu; gw=g*wf in place; c0=u*D*g*wf ============
__global__ __launch_bounds__(256) void k_dwconv_silu(const unsigned short* __restrict__ xiT,
                                                     const float* __restrict__ cw,
                                                     const float* __restrict__ cb,
                                                     const float* __restrict__ wfv,
                                                     const float* __restrict__ Dvec,
                                                     float* __restrict__ gsT,
                                                     unsigned short* __restrict__ c0,
                                                     unsigned short* __restrict__ uT) {
    int lane = threadIdx.x & 63;
    int w    = threadIdx.x >> 6;
    int d = blockIdx.x * 4 + w;
    int b = blockIdx.y;
    const unsigned short* src = xiT + ((size_t)b * DINNER + d) * LSEQ;
    uint4 cur = *(const uint4*)(src + lane * 8);
    unsigned pw = (unsigned)__shfl_up((int)cur.w, 1);
    unsigned pz = (unsigned)__shfl_up((int)cur.z, 1);
    if (lane == 0) { pw = 0u; pz = 0u; }
    float4 w4 = *(const float4*)(cw + (size_t)d * 4);
    float bias = cb[d];
    float win[11];
    win[0] = bhi(pz); win[1] = blo(pw); win[2] = bhi(pw);
    const unsigned* cp = (const unsigned*)&cur;
#pragma unroll
    for (int q = 0; q < 4; ++q) {
        win[3 + 2 * q] = blo(cp[q]);
        win[4 + 2 * q] = bhi(cp[q]);
    }
    float uvf[8];
    unsigned ov[4];
#pragma unroll
    for (int tt = 0; tt < 8; ++tt) {
        float a = bias + win[tt] * w4.x + win[tt + 1] * w4.y
                       + win[tt + 2] * w4.z + win[tt + 3] * w4.w;
        float uv = a / (1.f + __expf(-a));
        uvf[tt] = uv;
        unsigned short us = f2b(uv);
        if (tt & 1) ov[tt >> 1] |= ((unsigned)us) << 16;
        else        ov[tt >> 1]  = us;
    }
    *(uint4*)(uT + ((size_t)b * DINNER + d) * LSEQ + lane * 8) = *(uint4*)ov;
    if (lane >= 52) {
        int tl0 = lane * 8 - TSTART;
        float wfd = wfv[d];
        float Dd  = Dvec[d];
        float* gp = gsT + ((size_t)b * DINNER + d) * PREDLEN + tl0;
        float4 g0 = *(const float4*)gp;
        float4 g1 = *(const float4*)(gp + 4);
        float gg[8] = {g0.x, g0.y, g0.z, g0.w, g1.x, g1.y, g1.z, g1.w};
        unsigned cv[4];
#pragma unroll
        for (int j = 0; j < 8; ++j) {
            float gw = gg[j] * wfd;
            gg[j] = gw;
            unsigned short us = f2b(uvf[j] * Dd * gw);
            if (j & 1) cv[j >> 1] |= ((unsigned)us) << 16;
            else       cv[j >> 1]  = us;
        }
        *(float4*)gp       = make_float4(gg[0], gg[1], gg[2], gg[3]);
        *(float4*)(gp + 4) = make_float4(gg[4], gg[5], gg[6], gg[7]);
        *(uint4*)(c0 + ((size_t)b * DINNER + d) * PREDLEN + tl0) = *(uint4*)cv;
    }
}

// ============ Kernel E: x_proj GEMM; wbx k-slice staged in LDS (80B rows) ============
#define XPS 66
#define WLS 40   // shorts per wbx LDS row (80 B, 16-B aligned, ~2-way)
__global__ __launch_bounds__(256) void k_gemm_xproj2(const unsigned short* __restrict__ uT,
                                                     const unsigned short* __restrict__ wbx,
                                                     unsigned short* __restrict__ dt_in,
                                                     float* __restrict__ Bt2,
                                                     float* __restrict__ Ct2) {
    __shared__ unsigned short Asl[32 * XPS];     // 4224 B
    __shared__ unsigned short WL[64 * WLS];      // 5120 B
    int tid  = threadIdx.x;
    int lane = tid & 63;
    int w    = tid >> 6;
    int quad = lane >> 4;
    int col  = lane & 15;
    int m0 = blockIdx.x * 64;
    int b  = m0 >> 9;
    int t0 = m0 & (LSEQ - 1);
    int sk  = tid >> 3;
    int smc = (tid & 7) * 8;
    int wrow = tid >> 2;          // 0..63
    int wcq  = (tid & 3) * 8;     // 0,8,16,24 shorts
    f32x4 acc[4] = {};
    uint4 v = *(const uint4*)(uT + ((size_t)b * DINNER + sk) * LSEQ + t0 + smc);
    for (int k0 = 0; k0 < DINNER; k0 += 32) {
        unsigned* dst = (unsigned*)&Asl[sk * XPS + smc];
        dst[0] = v.x; dst[1] = v.y; dst[2] = v.z; dst[3] = v.w;
        // stage wbx slice: 64 n-rows x 32 k (4 uint4 per row)
        *(uint4*)&WL[wrow * WLS + wcq] =
            *(const uint4*)(wbx + (size_t)wrow * DINNER + k0 + wcq);
        __syncthreads();
        if (k0 + 32 < DINNER)
            v = *(const uint4*)(uT + ((size_t)b * DINNER + k0 + 32 + sk) * LSEQ + t0 + smc);
        bf16_8 bf[4];
#pragma unroll
        for (int j = 0; j < 4; ++j)
            bf[j] = *((const bf16_8*)&WL[(j * 16 + col) * WLS + quad * 8]);
        union { bf16_8 v; unsigned short u[8]; } af;
#pragma unroll
        for (int j8 = 0; j8 < 8; ++j8)
            af.u[j8] = Asl[(quad * 8 + j8) * XPS + w * 16 + col];
#pragma unroll
        for (int j = 0; j < 4; ++j)
            acc[j] = __builtin_amdgcn_mfma_f32_16x16x32_bf16(af.v, bf[j], acc[j], 0, 0, 0);
        __syncthreads();
    }
    int mrow = m0 + w * 16 + quad * 4;
#pragma unroll
    for (int j = 0; j < 2; ++j)
#pragma unroll
        for (int r = 0; r < 4; ++r)
            dt_in[(size_t)(mrow + r) * DTRANK + j * 16 + col] = f2b(acc[j][r]);
    int t = t0 + w * 16 + quad * 4;
#pragma unroll
    for (int r = 0; r < 4; ++r) {
        Bt2[((size_t)b * LSEQ + t + r) * DSTATE + col] = acc[2][r];
        Ct2[((size_t)b * LSEQ + t + r) * DSTATE + col] = acc[3][r];
    }
}

// ============ Kernel F: dt_proj as MFMA GEMM (K=32) + softplus + transpose store ============
#define TP_STRIDE 136
__global__ __launch_bounds__(256) void k_dtproj2(const unsigned short* __restrict__ dt_in,
                                                 const unsigned short* __restrict__ dpwb,
                                                 const float* __restrict__ dpb,
                                                 unsigned short* __restrict__ dtT) {
    __shared__ unsigned char smem[128 * TP_STRIDE * 2];
    uint4* As4 = (uint4*)smem;
    uint4* Bs4 = As4 + 512;
    unsigned short* T = (unsigned short*)smem;
    int tid  = threadIdx.x;
    int lane = tid & 63;
    int w    = tid >> 6;
    int wm   = (w & 1) * 64;
    int wn   = (w >> 1) * 64;
    int n0 = blockIdx.x * 128;
    int m0 = blockIdx.y * 128;
#pragma unroll
    for (int hh = 0; hh < 2; ++hh) {
        int c  = tid + hh * 256;
        int im = c >> 6;
        int lc = c & 63;
        int r  = im * 16 + (lc & 15);
        int kq = lc >> 4;
        As4[c] = *(const uint4*)(dt_in + (size_t)(m0 + r) * DTRANK + kq * 8);
        Bs4[c] = *(const uint4*)(dpwb + (size_t)(n0 + r) * DTRANK + kq * 8);
    }
    __syncthreads();
    f32x4 acc[4][4] = {};
    bf16_8 af[4], bf[4];
#pragma unroll
    for (int i = 0; i < 4; ++i) {
        af[i] = ((const bf16_8*)As4)[((wm >> 4) + i) * 64 + lane];
        bf[i] = ((const bf16_8*)Bs4)[((wn >> 4) + i) * 64 + lane];
    }
#pragma unroll
    for (int i = 0; i < 4; ++i)
#pragma unroll
        for (int j = 0; j < 4; ++j)
            acc[i][j] = __builtin_amdgcn_mfma_f32_16x16x32_bf16(af[i], bf[j], acc[i][j], 0, 0, 0);
    __syncthreads();
    int col  = lane & 15;
    int quad = lane >> 4;
#pragma unroll
    for (int i = 0; i < 4; ++i) {
#pragma unroll
        for (int j = 0; j < 4; ++j) {
            int nn = wn + j * 16 + col;
            int mm = wm + i * 16 + quad * 4;
            float bias = dpb[n0 + nn];
            ushort4 o;
            unsigned short* op = (unsigned short*)&o;
#pragma unroll
            for (int r = 0; r < 4; ++r) {
                float a = acc[i][j][r] + bias;
                float sp = (a > 20.f) ? a
                         : 0.6931471805599453f * LOG2F(1.f + EXP2F(a * 1.44269504088896f));
                op[r] = f2b(sp);
            }
            *(ushort4*)&T[nn * TP_STRIDE + mm] = o;
        }
    }
    __syncthreads();
    int bI = m0 >> 9;
    int tglob = m0 & (LSEQ - 1);
#pragma unroll
    for (int it = 0; it < 8; ++it) {
        int c  = tid + it * 256;
        int nn = c >> 4;
        int tc = c & 15;
        uint4 v = *(const uint4*)&T[nn * TP_STRIDE + tc * 8];
        *(uint4*)(dtT + ((size_t)bI * DINNER + n0 + nn) * LSEQ + tglob + tc * 8) = v;
    }
}

// ============ Kernel G1: scan phase 1 — u/dt/B staged in LDS ============
#define P1S 112   // shorts per u/dt LDS row (224 B, 16-B aligned, 4-way worst)
__global__ __launch_bounds__(256) void k_scan_p1(const unsigned short* __restrict__ uT,
                                                 const unsigned short* __restrict__ dtT,
                                                 const float* __restrict__ Bt2,
                                                 const float* __restrict__ A_log,
                                                 float2* __restrict__ ab) {
    __shared__ unsigned short uL[64 * P1S];   // 14336 B
    __shared__ unsigned short dL[64 * P1S];   // 14336 B
    __shared__ float BL[CHUNKT * DSTATE];     // 6656 B
    int b = blockIdx.y;
    int c = blockIdx.z;
    int tid  = threadIdx.x;
    int lane = tid & 63;
    int w    = tid >> 6;
    int q    = lane & 3;
    int dloc = lane >> 2;
    int d0   = blockIdx.x * 64;
    int d    = d0 + w * 16 + dloc;
    int tbeg = c * CHUNKT;
    // stage u/dt: 64 rows x 13 uint4 (104 shorts)
    for (int i = tid; i < 64 * 13; i += 256) {
        int row = i / 13;
        int col = i - row * 13;
        *(uint4*)&uL[row * P1S + col * 8] =
            *(const uint4*)(uT + ((size_t)b * DINNER + d0 + row) * LSEQ + tbeg + col * 8);
        *(uint4*)&dL[row * P1S + col * 8] =
            *(const uint4*)(dtT + ((size_t)b * DINNER + d0 + row) * LSEQ + tbeg + col * 8);
    }
    // stage B: 104 x 16 fp32 = 416 float4
    for (int i = tid; i < CHUNKT * 4; i += 256)
        ((float4*)BL)[i] = *((const float4*)(Bt2 + ((size_t)b * LSEQ + tbeg) * DSTATE) + i);
    float4 al = *(const float4*)(A_log + (size_t)d * DSTATE + q * 4);
    float As2[4];
    As2[0] = -__expf(al.x) * 1.44269504088896f;
    As2[1] = -__expf(al.y) * 1.44269504088896f;
    As2[2] = -__expf(al.z) * 1.44269504088896f;
    As2[3] = -__expf(al.w) * 1.44269504088896f;
    float beta[4] = {0.f, 0.f, 0.f, 0.f};
    float asum = 0.f;
    const unsigned short* upL = uL + (w * 16 + dloc) * P1S;
    const unsigned short* dpL = dL + (w * 16 + dloc) * P1S;
    __syncthreads();
    for (int t8 = 0; t8 < CHUNKT; t8 += 8) {
        uint4 uq = *(const uint4*)(upL + t8);
        uint4 dq = *(const uint4*)(dpL + t8);
        float4 Bq[8];
#pragma unroll
        for (int j = 0; j < 8; ++j)
            Bq[j] = *(const float4*)&BL[(t8 + j) * DSTATE + q * 4];
        float uu[8], dd[8];
        const unsigned* uqp = (const unsigned*)&uq;
        const unsigned* dqp = (const unsigned*)&dq;
#pragma unroll
        for (int p = 0; p < 4; ++p) {
            uu[p * 2] = blo(uqp[p]); uu[p * 2 + 1] = bhi(uqp[p]);
            dd[p * 2] = blo(dqp[p]); dd[p * 2 + 1] = bhi(dqp[p]);
        }
        float S[8];
        S[0] = dd[0];
#pragma unroll
        for (int j = 1; j < 8; ++j) S[j] = S[j - 1] + dd[j];
        float G = S[7];
        float g0 = 0.f, g1 = 0.f, g2 = 0.f, g3 = 0.f;
#pragma unroll
        for (int j = 0; j < 8; ++j) {
            float w8 = dd[j] * uu[j];
            float p8 = G - S[j];
            g0 += EXP2F(As2[0] * p8) * (w8 * Bq[j].x);
            g1 += EXP2F(As2[1] * p8) * (w8 * Bq[j].y);
            g2 += EXP2F(As2[2] * p8) * (w8 * Bq[j].z);
            g3 += EXP2F(As2[3] * p8) * (w8 * Bq[j].w);
        }
        beta[0] = EXP2F(As2[0] * G) * beta[0] + g0;
        beta[1] = EXP2F(As2[1] * G) * beta[1] + g1;
        beta[2] = EXP2F(As2[2] * G) * beta[2] + g2;
        beta[3] = EXP2F(As2[3] * G) * beta[3] + g3;
        asum += G;
    }
    float2* abp = ab + ((size_t)(b * DINNER + d) * NCHUNK + c) * DSTATE + q * 4;
#pragma unroll
    for (int si = 0; si < 4; ++si)
        abp[si] = make_float2(EXP2F(asum * As2[si]), beta[si]);
}

// ============ Kernel G2: stitch h(416), run [416,512); LDS B/C; block-reduce + atomic ============
__global__ __launch_bounds__(256) void k_scan_p3(const unsigned short* __restrict__ uT,
                                                 const unsigned short* __restrict__ dtT,
                                                 const float* __restrict__ Bt2,
                                                 const float* __restrict__ Ct2,
                                                 const float* __restrict__ A_log,
                                                 const float* __restrict__ gsT,
                                                 const unsigned short* __restrict__ c0,
                                                 const float2* __restrict__ ab,
                                                 float* __restrict__ oacc) {
    __shared__ float BsL[PREDLEN * DSTATE];
    __shared__ float CsL[PREDLEN * DSTATE];
    __shared__ float accL[16][100];
    int b    = blockIdx.y;
    int tid  = threadIdx.x;
    int s    = tid & 15;
    int dloc = (tid >> 4) & 3;
    int w    = tid >> 6;
    int d    = blockIdx.x * 16 + (tid >> 4);
    for (int i = tid; i < (PREDLEN * DSTATE) / 4; i += 256) {
        ((float4*)BsL)[i] = *((const float4*)(Bt2 + ((size_t)b * LSEQ + TSTART) * DSTATE) + i);
        ((float4*)CsL)[i] = *((const float4*)(Ct2 + ((size_t)b * LSEQ + TSTART) * DSTATE) + i);
    }
    float As2 = -__expf(A_log[(size_t)d * DSTATE + s]) * 1.44269504088896f;
    const float2* abp = ab + (size_t)(b * DINNER + d) * NCHUNK * DSTATE + s;
    float h = 0.f;
#pragma unroll
    for (int c = 0; c < NCHUNK; ++c) {
        float2 v = abp[c * DSTATE];
        h = v.y + v.x * h;
    }
    const unsigned short* up = uT  + ((size_t)b * DINNER + d) * LSEQ;
    const unsigned short* dp = dtT + ((size_t)b * DINNER + d) * LSEQ;
    const float* gp = gsT + ((size_t)b * DINNER + d) * PREDLEN;
    const unsigned short* cp0 = c0 + ((size_t)b * DINNER + d) * PREDLEN;
    __syncthreads();
    for (int t8 = TSTART; t8 < LSEQ; t8 += 8) {
        int tl0 = t8 - TSTART;
        uint4 uq = *(const uint4*)(up + t8);
        uint4 dq = *(const uint4*)(dp + t8);
        float4 g0 = *(const float4*)(gp + tl0);
        float4 g1 = *(const float4*)(gp + tl0 + 4);
        uint4 cq = *(const uint4*)(cp0 + tl0);
        float Bv[8], Cv[8];
#pragma unroll
        for (int j = 0; j < 8; ++j) {
            Bv[j] = BsL[(tl0 + j) * DSTATE + s];
            Cv[j] = CsL[(tl0 + j) * DSTATE + s];
        }
        float uu[8], dd[8];
        const unsigned* uqp = (const unsigned*)&uq;
        const unsigned* dqp = (const unsigned*)&dq;
#pragma unroll
        for (int p = 0; p < 4; ++p) {
            uu[p * 2] = blo(uqp[p]); uu[p * 2 + 1] = bhi(uqp[p]);
            dd[p * 2] = blo(dqp[p]); dd[p * 2 + 1] = bhi(dqp[p]);
        }
        float y[8];
#pragma unroll
        for (int j = 0; j < 8; ++j) {
            h = EXP2F(dd[j] * As2) * h + (dd[j] * uu[j]) * Bv[j];
            y[j] = h * Cv[j];
        }
#pragma unroll
        for (int j = 0; j < 8; ++j) y[j] += __shfl_xor(y[j], 1);
#pragma unroll
        for (int j = 0; j < 8; ++j) y[j] += __shfl_xor(y[j], 2);
#pragma unroll
        for (int j = 0; j < 8; ++j) y[j] += __shfl_xor(y[j], 4);
#pragma unroll
        for (int j = 0; j < 8; ++j) y[j] += __shfl_xor(y[j], 8);
        float gv[8] = {g0.x, g0.y, g0.z, g0.w, g1.x, g1.y, g1.z, g1.w};
        const unsigned* cqp = (const unsigned*)&cq;
#pragma unroll
        for (int j = 0; j < 8; ++j) {
            float cf = (j & 1) ? bhi(cqp[j >> 1]) : blo(cqp[j >> 1]);
            float z  = y[j] * gv[j] + cf;
            if (s == 0) accL[w * 4 + dloc][tl0 + j] = z;
        }
    }
    __syncthreads();
    if (tid < PREDLEN) {
        float tot = 0.f;
#pragma unroll
        for (int k = 0; k < 16; ++k) tot += accL[k][tid];
        atomicAdd(&oacc[b * PREDLEN + tid], tot);
    }
}

// ============ Kernel H: scale accumulated outputs + de-normalize ============
__global__ __launch_bounds__(256) void k_final3(const float* __restrict__ oacc,
                                                const float* __restrict__ meanv,
                                                const float* __restrict__ stdv,
                                                float* __restrict__ out) {
    int idx = blockIdx.x * 256 + threadIdx.x;
    int b = idx / PREDLEN;
    out[idx] = oacc[idx] * stdv[b * ENC_IN] + meanv[b * ENC_IN];
}

// ---------------- launch ----------------
extern "C" void kernel_launch(void* const* d_in, const int* in_sizes, int n_in,
                              void* d_out, int out_size, void* d_ws, size_t ws_size,
                              hipStream_t stream) {
    const float* x_enc     = (const float*)d_in[0];
    const float* x_mark    = (const float*)d_in[1];
    const float* conv_w    = (const float*)d_in[2];
    const float* temp_w    = (const float*)d_in[3];
    const float* in_proj_w = (const float*)d_in[4];
    const float* conv1d_w  = (const float*)d_in[5];
    const float* conv1d_b  = (const float*)d_in[6];
    const float* x_proj_w  = (const float*)d_in[7];
    const float* dt_proj_w = (const float*)d_in[8];
    const float* dt_proj_b = (const float*)d_in[9];
    const float* A_log     = (const float*)d_in[10];
    const float* Dvec      = (const float*)d_in[11];
    const float* out_proj_w= (const float*)d_in[12];
    const float* out_w     = (const float*)d_in[13];
    float* ws  = (float*)d_ws;
    float* out = (float*)d_out;

    float* xn    = ws + OFF_XN;
    float* meanv = ws + OFF_MEAN;
    float* stdv  = ws + OFF_STD;
    float* wfv   = ws + OFF_WF;
    float* wfp   = ws + OFF_WFP;
    float* oacc  = ws + OFF_OACC;
    float* Btv   = ws + OFF_BT;
    float* Ctv   = ws + OFF_CT;
    float* gsT   = ws + OFF_GST;
    unsigned short* xb    = (unsigned short*)(ws + OFF_XB);
    unsigned short* wb    = (unsigned short*)(ws + OFF_WB);
    unsigned short* wbx   = (unsigned short*)(ws + OFF_WBX);
    unsigned short* dpwb  = (unsigned short*)(ws + OFF_DPWB);
    unsigned short* dtinb = (unsigned short*)(ws + OFF_DTIN);
    unsigned short* xiT   = (unsigned short*)(ws + OFF_XIT);
    unsigned short* uT    = (unsigned short*)(ws + OFF_UT);
    unsigned short* dtT   = (unsigned short*)(ws + OFF_DTT);
    unsigned short* c0    = (unsigned short*)(ws + OFF_C0);
    float2* ab = (float2*)(ws + OFF_AB);

    k_front<<<dim3(1201), 256, 0, stream>>>(out_proj_w, out_w, in_proj_w, x_proj_w, dt_proj_w,
                                            x_enc, wfp, wb, wbx, dpwb, xn, meanv, stdv, oacc);
    k_front2<<<dim3(32772), 256, 0, stream>>>(xn, x_mark, conv_w, temp_w, wfp, xb, wfv);
    k_gemm_xi<<<dim3(4, 64), 512, 0, stream>>>(xb, wb, xiT);
    k_gemm_z<<<dim3(8, 32), 256, 0, stream>>>(xb, wb, gsT);
    k_dwconv_silu<<<dim3(DINNER / 4, BATCH), 256, 0, stream>>>(xiT, conv1d_w, conv1d_b,
                                                               wfv, Dvec, gsT, c0, uT);
    k_gemm_xproj2<<<dim3(MROWS / 64), 256, 0, stream>>>(uT, wbx, dtinb, Btv, Ctv);
    k_dtproj2<<<dim3(8, 128), 256, 0, stream>>>(dtinb, dpwb, dt_proj_b, dtT);
    k_scan_p1<<<dim3(DINNER / 64, BATCH, NCHUNK), 256, 0, stream>>>(uT, dtT, Btv, A_log, ab);
    k_scan_p3<<<dim3(DINNER / 16, BATCH), 256, 0, stream>>>(uT, dtT, Btv, Ctv, A_log,
                                                            gsT, c0, ab, oacc);
    k_final3<<<dim3((BATCH * PREDLEN) / 256), 256, 0, stream>>>(oacc, meanv, stdv, out);
}

// Round 16
// 322.658 us; speedup vs baseline: 1.4822x; 1.0011x over previous
//
#include <hip/hip_runtime.h>
#include <hip/hip_bf16.h>
#include <math.h>

// ---------------- problem constants ----------------
#define BATCH   32
#define LSEQ    512
#define ENC_IN  8
#define MARKD   4
#define DMODEL  512
#define DSTATE  16
#define DINNER  1024
#define DTRANK  32
#define PREDLEN 96
#define MROWS   (BATCH * LSEQ)          // 16384
#define TSTART  (LSEQ - PREDLEN)        // 416
#define NCHUNK  4                       // stitch chunks: 4 x 104 over [0,416)
#define CHUNKT  104

// ---------------- workspace layout (float units), total 111.5 MiB ----------------
#define OFF_XN    ((size_t)0)            // 131072
#define OFF_MEAN  ((size_t)131072)       // 256
#define OFF_STD   ((size_t)131328)       // 256
#define OFF_WF    ((size_t)131584)       // 1024
#define OFF_WBX   ((size_t)132608)       // x_proj_w bf16: 32768 f
#define OFF_DPWB  ((size_t)165376)       // dt_proj_w bf16: 16384 f
#define OFF_OACC  ((size_t)181760)       // 32*96 fp32 atomic accumulator = 3072 f
#define OFF_XB    ((size_t)919040)       // 16384x512 bf16 = 4194304 f (ab overlays)
#define OFF_WB    ((size_t)5113344)      // 2048x512 bf16 = 524288 f
#define OFF_DTIN  ((size_t)5637632)      // dt_in bf16 = 262144 f (wfp overlays early)
#define OFF_BT    ((size_t)6161920)      // B [b][t][s] fp32 = 262144 f
#define OFF_CT    ((size_t)6424064)      // C [b][t][s] fp32 = 262144 f
#define OFF_GST   ((size_t)6686208)      // 32x1024x96 fp32 (g -> gw, read-only in scan)
#define OFF_XIT   ((size_t)9831936)      // [b][d][t] bf16 = 8388608 f (dtT overlays)
#define OFF_UT    ((size_t)18220544)     // [b][d][t] bf16 = 8388608 f
#define OFF_C0    ((size_t)26609152)     // 32x1024x96 bf16 = 1572864 f
#define OFF_AB2   ((size_t)28182016)     // chunk-4 (alpha,beta): 32*1024*16*2 = 1048576 f
#define OFF_DTT   OFF_XIT
#define OFF_AB    OFF_XB                 // 4 chunks (alpha,beta) = 4194304 f exact fit
#define OFF_WFP   OFF_DTIN
// end: 29230592 floats = 111.5 MiB (<= 112.7 known-good)

typedef __bf16 bf16_8 __attribute__((ext_vector_type(8)));
typedef float  f32x4  __attribute__((ext_vector_type(4)));

#define EXP2F(x) __builtin_amdgcn_exp2f(x)
#define LOG2F(x) __builtin_amdgcn_logf(x)

typedef __attribute__((address_space(3))) unsigned lds_u32;
typedef const __attribute__((address_space(1))) unsigned glb_u32;
#define ASYNC_LDS16(gsrc, ldst) \
    __builtin_amdgcn_global_load_lds((glb_u32*)(gsrc), (lds_u32*)(ldst), 16, 0, 0)

static __device__ __forceinline__ float b2f(unsigned short h) {
    union { float f; unsigned u; } v; v.u = ((unsigned)h) << 16; return v.f;
}
static __device__ __forceinline__ unsigned short f2b(float f) {
    __hip_bfloat16 h = __float2bfloat16(f);   // RNE
    union { __hip_bfloat16 b; unsigned short s; } v; v.b = h; return v.s;
}
static __device__ __forceinline__ float blo(unsigned v) {
    union { float f; unsigned u; } x; x.u = v << 16; return x.f;
}
static __device__ __forceinline__ float bhi(unsigned v) {
    union { float f; unsigned u; } x; x.u = v & 0xffff0000u; return x.f;
}

// ============ k_front: fusew-partials | w2b x3 | norm | zero oacc ============
__global__ __launch_bounds__(256) void k_front(const float* __restrict__ opw,
                                               const float* __restrict__ ow,
                                               const float* __restrict__ in_proj_w,
                                               const float* __restrict__ x_proj_w,
                                               const float* __restrict__ dpw,
                                               const float* __restrict__ xe,
                                               float* __restrict__ wfp,
                                               unsigned short* __restrict__ wb,
                                               unsigned short* __restrict__ wbx,
                                               unsigned short* __restrict__ dpwb,
                                               float* __restrict__ xn,
                                               float* __restrict__ meanv,
                                               float* __restrict__ stdv,
                                               float* __restrict__ oacc) {
    int bid = blockIdx.x;
    int tid = threadIdx.x;
    if (bid < 16) {
        int q = bid >> 2;
        int i = (bid & 3) * 256 + tid;
        float acc = 0.f;
        for (int dd = q * 128; dd < q * 128 + 128; ++dd)
            acc += opw[(size_t)dd * DINNER + i] * ow[dd];
        wfp[(size_t)q * DINNER + i] = acc;
    } else if (bid < 1040) {
        int i = ((bid - 16) * 256 + tid) * 4;
        float4 v = *(const float4*)(in_proj_w + i);
        ushort4 o; o.x = f2b(v.x); o.y = f2b(v.y); o.z = f2b(v.z); o.w = f2b(v.w);
        *(ushort4*)(wb + i) = o;
    } else if (bid < 1104) {
        int i = ((bid - 1040) * 256 + tid) * 4;
        float4 v = *(const float4*)(x_proj_w + i);
        ushort4 o; o.x = f2b(v.x); o.y = f2b(v.y); o.z = f2b(v.z); o.w = f2b(v.w);
        *(ushort4*)(wbx + i) = o;
    } else if (bid < 1136) {
        int i = ((bid - 1104) * 256 + tid) * 4;
        float4 v = *(const float4*)(dpw + i);
        ushort4 o; o.x = f2b(v.x); o.y = f2b(v.y); o.z = f2b(v.z); o.w = f2b(v.w);
        *(ushort4*)(dpwb + i) = o;
    } else if (bid < 1200) {
        int wv   = tid >> 6;
        int lane = tid & 63;
        int idx  = (bid - 1136) * 4 + wv;
        int c = idx & 7, b = idx >> 3;
        const float* p = xe + ((size_t)b * LSEQ) * ENC_IN + c;
        float vals[8];
        float s = 0.f, s2 = 0.f;
#pragma unroll
        for (int i = 0; i < 8; ++i) {
            float v = p[(size_t)(lane + i * 64) * ENC_IN];
            vals[i] = v; s += v; s2 += v * v;
        }
#pragma unroll
        for (int off = 32; off; off >>= 1) {
            s  += __shfl_xor(s,  off);
            s2 += __shfl_xor(s2, off);
        }
        float mean = s * (1.f / LSEQ);
        float var  = s2 * (1.f / LSEQ) - mean * mean;
        float sd   = sqrtf(var + 1e-5f);
        float rstd = 1.f / sd;
        if (lane == 0) { meanv[b * ENC_IN + c] = mean; stdv[b * ENC_IN + c] = sd; }
#pragma unroll
        for (int i = 0; i < 8; ++i)
            xn[((size_t)b * LSEQ + lane + i * 64) * ENC_IN + c] = (vals[i] - mean) * rstd;
    } else {
        for (int i = tid; i < BATCH * PREDLEN; i += 256) oacc[i] = 0.f;
    }
}

// ============ k_front2: build_x + fusew2 ============
__global__ __launch_bounds__(256) void k_front2(const float* __restrict__ xn,
                                                const float* __restrict__ xmark,
                                                const float* __restrict__ convw,
                                                const float* __restrict__ tempw,
                                                const float* __restrict__ wfp,
                                                unsigned short* __restrict__ xb,
                                                float* __restrict__ wfv) {
    int bid = blockIdx.x;
    int tid = threadIdx.x;
    if (bid >= 32768) {
        int i = (bid - 32768) * 256 + tid;
        wfv[i] = wfp[i] + wfp[DINNER + i] + wfp[2 * DINNER + i] + wfp[3 * DINNER + i];
        return;
    }
    int d = (bid & 1) * 256 + tid;
    int l = (bid >> 1) & (LSEQ - 1);
    int b = bid >> 10;
    int lm = (l + LSEQ - 1) & (LSEQ - 1);
    int lp = (l + 1) & (LSEQ - 1);
    const float* r0 = xn + ((size_t)b * LSEQ + lm) * ENC_IN;
    const float* r1 = xn + ((size_t)b * LSEQ + l ) * ENC_IN;
    const float* r2 = xn + ((size_t)b * LSEQ + lp) * ENC_IN;
    const float* w  = convw + (size_t)d * (ENC_IN * 3);
    float acc = 0.f;
#pragma unroll
    for (int i = 0; i < ENC_IN; ++i)
        acc += r0[i] * w[i * 3 + 0] + r1[i] * w[i * 3 + 1] + r2[i] * w[i * 3 + 2];
    const float* tw = tempw + (size_t)d * MARKD;
    const float* xm = xmark + ((size_t)b * LSEQ + l) * MARKD;
    acc += xm[0] * tw[0] + xm[1] * tw[1] + xm[2] * tw[2] + xm[3] * tw[3];
    float freq = __expf(-(float)(d & ~1) * (9.210340371976184f / (float)DMODEL));
    float rev  = (float)l * freq * 0.15915494309189535f;
    rev = rev - floorf(rev);
    acc += (d & 1) ? __builtin_amdgcn_cosf(rev) : __builtin_amdgcn_sinf(rev);
    xb[((size_t)b * LSEQ + l) * DMODEL + d] = f2b(acc);
}

// ============ Kernel C1: xi-side in_proj GEMM, 256x256 tile, 512 thr, BK=64 ============
#define XI_TS 264
__global__ __launch_bounds__(512) void k_gemm_xi(const unsigned short* __restrict__ xb,
                                                 const unsigned short* __restrict__ wb,
                                                 unsigned short* __restrict__ xiT) {
    __shared__ uint4 smem4[4096];
    uint4* As4 = smem4;
    uint4* Bs4 = smem4 + 2048;
    unsigned short* T = (unsigned short*)smem4;

    int tid  = threadIdx.x;
    int lane = tid & 63;
    int w    = tid >> 6;
    int wm   = (w & 3) * 64;
    int wn   = (w >> 2) * 128;
    int n0 = blockIdx.x * 256;
    int m0 = blockIdx.y * 256;
    int quad = lane >> 4;
    int col  = lane & 15;

    f32x4 acc[4][8] = {};

    for (int k0 = 0; k0 < DMODEL; k0 += 64) {
#pragma unroll
        for (int i = 0; i < 4; ++i) {
            int c  = w * 256 + i * 64 + lane;
            int ks = c >> 10;
            int fi = (c >> 6) & 15;
            int lc = c & 63;
            int r  = fi * 16 + (lc & 15);
            int kq = lc >> 4;
            ASYNC_LDS16(xb + (size_t)(m0 + r) * DMODEL + k0 + ks * 32 + kq * 8,
                        As4 + (w * 256 + i * 64));
            ASYNC_LDS16(wb + (size_t)(n0 + r) * DMODEL + k0 + ks * 32 + kq * 8,
                        Bs4 + (w * 256 + i * 64));
        }
        __syncthreads();
#pragma unroll
        for (int ks = 0; ks < 2; ++ks) {
            bf16_8 af[4];
#pragma unroll
            for (int i = 0; i < 4; ++i)
                af[i] = ((const bf16_8*)As4)[ks * 1024 + ((wm >> 4) + i) * 64 + lane];
#pragma unroll
            for (int j = 0; j < 8; ++j) {
                bf16_8 bf = ((const bf16_8*)Bs4)[ks * 1024 + ((wn >> 4) + j) * 64 + lane];
#pragma unroll
                for (int i = 0; i < 4; ++i)
                    acc[i][j] = __builtin_amdgcn_mfma_f32_16x16x32_bf16(af[i], bf, acc[i][j], 0, 0, 0);
            }
        }
        __syncthreads();
    }

    int bI = m0 >> 9;
    int tglob = m0 & (LSEQ - 1);
#pragma unroll
    for (int p = 0; p < 4; ++p) {
        if ((w >> 2) == (p >> 1)) {
            int jbase = (p & 1) * 4;
#pragma unroll
            for (int i = 0; i < 4; ++i) {
#pragma unroll
                for (int jj = 0; jj < 4; ++jj) {
                    int j = jbase + jj;
                    int nn = jj * 16 + col;
                    int mm = wm + i * 16 + quad * 4;
                    ushort4 o;
                    o.x = f2b(acc[i][j][0]); o.y = f2b(acc[i][j][1]);
                    o.z = f2b(acc[i][j][2]); o.w = f2b(acc[i][j][3]);
                    *(ushort4*)&T[nn * XI_TS + mm] = o;
                }
            }
        }
        __syncthreads();
#pragma unroll
        for (int it = 0; it < 4; ++it) {
            int c  = tid + it * 512;
            int nn = c >> 5;
            int tc = c & 31;
            uint4 v = *(const uint4*)&T[nn * XI_TS + tc * 8];
            *(uint4*)(xiT + ((size_t)bI * DINNER + n0 + p * 64 + nn) * LSEQ + tglob + tc * 8) = v;
        }
        __syncthreads();
    }
}

// ============ Kernel C2: z-side in_proj GEMM (only t in [384,512)), 128x128 tile ============
__global__ __launch_bounds__(256) void k_gemm_z(const unsigned short* __restrict__ xb,
                                                const unsigned short* __restrict__ wb,
                                                float* __restrict__ gsT) {
    __shared__ uint4 As4[512];
    __shared__ uint4 Bs4[512];
    int n0 = 1024 + blockIdx.x * 128;
    int m0 = blockIdx.y * 512 + 384;
    int tid  = threadIdx.x;
    int lane = tid & 63;
    int w    = tid >> 6;
    int wm   = (w & 1) * 64;
    int wn   = (w >> 1) * 64;
    f32x4 acc[4][4] = {};

    for (int k0 = 0; k0 < DMODEL; k0 += 32) {
#pragma unroll
        for (int hh = 0; hh < 2; ++hh) {
            int c  = tid + hh * 256;
            int im = c >> 6;
            int lc = c & 63;
            int r  = im * 16 + (lc & 15);
            int kq = lc >> 4;
            ASYNC_LDS16(xb + (size_t)(m0 + r) * DMODEL + k0 + kq * 8,
                        As4 + (w * 64 + hh * 256));
            ASYNC_LDS16(wb + (size_t)(n0 + r) * DMODEL + k0 + kq * 8,
                        Bs4 + (w * 64 + hh * 256));
        }
        __syncthreads();
        bf16_8 af[4], bf[4];
#pragma unroll
        for (int i = 0; i < 4; ++i) {
            af[i] = ((const bf16_8*)As4)[((wm >> 4) + i) * 64 + lane];
            bf[i] = ((const bf16_8*)Bs4)[((wn >> 4) + i) * 64 + lane];
        }
#pragma unroll
        for (int i = 0; i < 4; ++i)
#pragma unroll
            for (int j = 0; j < 4; ++j)
                acc[i][j] = __builtin_amdgcn_mfma_f32_16x16x32_bf16(af[i], bf[j], acc[i][j], 0, 0, 0);
        __syncthreads();
    }

    int col  = lane & 15;
    int quad = lane >> 4;
#pragma unroll
    for (int i = 0; i < 4; ++i) {
#pragma unroll
        for (int j = 0; j < 4; ++j) {
            int m = m0 + wm + i * 16 + quad * 4;
            int t = m & (LSEQ - 1);
            if (t < TSTART) continue;
            int b = m >> 9;
            int nz = n0 - DINNER + wn + j * 16 + col;
            float4 g;
            float v0 = acc[i][j][0], v1 = acc[i][j][1], v2 = acc[i][j][2], v3 = acc[i][j][3];
            g.x = v0 / (1.f + __expf(-v0));
            g.y = v1 / (1.f + __expf(-v1));
            g.z = v2 / (1.f + __expf(-v2));
            g.w = v3 / (1.f + __expf(-v3));
            *(float4*)(gsT + ((size_t)b * DINNER + nz) * PREDLEN + (t - TSTART)) = g;
        }
    }
}

// ============ Kernel D: depthwise conv + silu; gw=g*wf in place; c0=u*D*g*wf ============
__global__ __launch_bounds__(256) void k_dwconv_silu(const unsigned short* __restrict__ xiT,
                                                     const float* __restrict__ cw,
                                                     const float* __restrict__ cb,
                                                     const float* __restrict__ wfv,
                                                     const float* __restrict__ Dvec,
                                                     float* __restrict__ gsT,
                                                     unsigned short* __restrict__ c0,
                                                     unsigned short* __restrict__ uT) {
    int lane = threadIdx.x & 63;
    int w    = threadIdx.x >> 6;
    int d = blockIdx.x * 4 + w;
    int b = blockIdx.y;
    const unsigned short* src = xiT + ((size_t)b * DINNER + d) * LSEQ;
    uint4 cur = *(const uint4*)(src + lane * 8);
    unsigned pw = (unsigned)__shfl_up((int)cur.w, 1);
    unsigned pz = (unsigned)__shfl_up((int)cur.z, 1);
    if (lane == 0) { pw = 0u; pz = 0u; }
    float4 w4 = *(const float4*)(cw + (size_t)d * 4);
    float bias = cb[d];
    float win[11];
    win[0] = bhi(pz); win[1] = blo(pw); win[2] = bhi(pw);
    const unsigned* cp = (const unsigned*)&cur;
#pragma unroll
    for (int q = 0; q < 4; ++q) {
        win[3 + 2 * q] = blo(cp[q]);
        win[4 + 2 * q] = bhi(cp[q]);
    }
    float uvf[8];
    unsigned ov[4];
#pragma unroll
    for (int tt = 0; tt < 8; ++tt) {
        float a = bias + win[tt] * w4.x + win[tt + 1] * w4.y
                       + win[tt + 2] * w4.z + win[tt + 3] * w4.w;
        float uv = a / (1.f + __expf(-a));
        uvf[tt] = uv;
        unsigned short us = f2b(uv);
        if (tt & 1) ov[tt >> 1] |= ((unsigned)us) << 16;
        else        ov[tt >> 1]  = us;
    }
    *(uint4*)(uT + ((size_t)b * DINNER + d) * LSEQ + lane * 8) = *(uint4*)ov;
    if (lane >= 52) {
        int tl0 = lane * 8 - TSTART;
        float wfd = wfv[d];
        float Dd  = Dvec[d];
        float* gp = gsT + ((size_t)b * DINNER + d) * PREDLEN + tl0;
        float4 g0 = *(const float4*)gp;
        float4 g1 = *(const float4*)(gp + 4);
        float gg[8] = {g0.x, g0.y, g0.z, g0.w, g1.x, g1.y, g1.z, g1.w};
        unsigned cv[4];
#pragma unroll
        for (int j = 0; j < 8; ++j) {
            float gw = gg[j] * wfd;
            gg[j] = gw;
            unsigned short us = f2b(uvf[j] * Dd * gw);
            if (j & 1) cv[j >> 1] |= ((unsigned)us) << 16;
            else       cv[j >> 1]  = us;
        }
        *(float4*)gp       = make_float4(gg[0], gg[1], gg[2], gg[3]);
        *(float4*)(gp + 4) = make_float4(gg[4], gg[5], gg[6], gg[7]);
        *(uint4*)(c0 + ((size_t)b * DINNER + d) * PREDLEN + tl0) = *(uint4*)cv;
    }
}

// ============ Kernel E: x_proj GEMM; wbx k-slice staged in LDS ============
#define XPS 66
#define WLS 40
__global__ __launch_bounds__(256) void k_gemm_xproj2(const unsigned short* __restrict__ uT,
                                                     const unsigned short* __restrict__ wbx,
                                                     unsigned short* __restrict__ dt_in,
                                                     float* __restrict__ Bt2,
                                                     float* __restrict__ Ct2) {
    __shared__ unsigned short Asl[32 * XPS];
    __shared__ unsigned short WL[64 * WLS];
    int tid  = threadIdx.x;
    int lane = tid & 63;
    int w    = tid >> 6;
    int quad = lane >> 4;
    int col  = lane & 15;
    int m0 = blockIdx.x * 64;
    int b  = m0 >> 9;
    int t0 = m0 & (LSEQ - 1);
    int sk  = tid >> 3;
    int smc = (tid & 7) * 8;
    int wrow = tid >> 2;
    int wcq  = (tid & 3) * 8;
    f32x4 acc[4] = {};
    uint4 v = *(const uint4*)(uT + ((size_t)b * DINNER + sk) * LSEQ + t0 + smc);
    for (int k0 = 0; k0 < DINNER; k0 += 32) {
        unsigned* dst = (unsigned*)&Asl[sk * XPS + smc];
        dst[0] = v.x; dst[1] = v.y; dst[2] = v.z; dst[3] = v.w;
        *(uint4*)&WL[wrow * WLS + wcq] =
            *(const uint4*)(wbx + (size_t)wrow * DINNER + k0 + wcq);
        __syncthreads();
        if (k0 + 32 < DINNER)
            v = *(const uint4*)(uT + ((size_t)b * DINNER + k0 + 32 + sk) * LSEQ + t0 + smc);
        bf16_8 bf[4];
#pragma unroll
        for (int j = 0; j < 4; ++j)
            bf[j] = *((const bf16_8*)&WL[(j * 16 + col) * WLS + quad * 8]);
        union { bf16_8 v; unsigned short u[8]; } af;
#pragma unroll
        for (int j8 = 0; j8 < 8; ++j8)
            af.u[j8] = Asl[(quad * 8 + j8) * XPS + w * 16 + col];
#pragma unroll
        for (int j = 0; j < 4; ++j)
            acc[j] = __builtin_amdgcn_mfma_f32_16x16x32_bf16(af.v, bf[j], acc[j], 0, 0, 0);
        __syncthreads();
    }
    int mrow = m0 + w * 16 + quad * 4;
#pragma unroll
    for (int j = 0; j < 2; ++j)
#pragma unroll
        for (int r = 0; r < 4; ++r)
            dt_in[(size_t)(mrow + r) * DTRANK + j * 16 + col] = f2b(acc[j][r]);
    int t = t0 + w * 16 + quad * 4;
#pragma unroll
    for (int r = 0; r < 4; ++r) {
        Bt2[((size_t)b * LSEQ + t + r) * DSTATE + col] = acc[2][r];
        Ct2[((size_t)b * LSEQ + t + r) * DSTATE + col] = acc[3][r];
    }
}

// ============ Kernel F: dt_proj as MFMA GEMM (K=32) + softplus + transpose store ============
#define TP_STRIDE 136
__global__ __launch_bounds__(256) void k_dtproj2(const unsigned short* __restrict__ dt_in,
                                                 const unsigned short* __restrict__ dpwb,
                                                 const float* __restrict__ dpb,
                                                 unsigned short* __restrict__ dtT) {
    __shared__ unsigned char smem[128 * TP_STRIDE * 2];
    uint4* As4 = (uint4*)smem;
    uint4* Bs4 = As4 + 512;
    unsigned short* T = (unsigned short*)smem;
    int tid  = threadIdx.x;
    int lane = tid & 63;
    int w    = tid >> 6;
    int wm   = (w & 1) * 64;
    int wn   = (w >> 1) * 64;
    int n0 = blockIdx.x * 128;
    int m0 = blockIdx.y * 128;
#pragma unroll
    for (int hh = 0; hh < 2; ++hh) {
        int c  = tid + hh * 256;
        int im = c >> 6;
        int lc = c & 63;
        int r  = im * 16 + (lc & 15);
        int kq = lc >> 4;
        As4[c] = *(const uint4*)(dt_in + (size_t)(m0 + r) * DTRANK + kq * 8);
        Bs4[c] = *(const uint4*)(dpwb + (size_t)(n0 + r) * DTRANK + kq * 8);
    }
    __syncthreads();
    f32x4 acc[4][4] = {};
    bf16_8 af[4], bf[4];
#pragma unroll
    for (int i = 0; i < 4; ++i) {
        af[i] = ((const bf16_8*)As4)[((wm >> 4) + i) * 64 + lane];
        bf[i] = ((const bf16_8*)Bs4)[((wn >> 4) + i) * 64 + lane];
    }
#pragma unroll
    for (int i = 0; i < 4; ++i)
#pragma unroll
        for (int j = 0; j < 4; ++j)
            acc[i][j] = __builtin_amdgcn_mfma_f32_16x16x32_bf16(af[i], bf[j], acc[i][j], 0, 0, 0);
    __syncthreads();
    int col  = lane & 15;
    int quad = lane >> 4;
#pragma unroll
    for (int i = 0; i < 4; ++i) {
#pragma unroll
        for (int j = 0; j < 4; ++j) {
            int nn = wn + j * 16 + col;
            int mm = wm + i * 16 + quad * 4;
            float bias = dpb[n0 + nn];
            ushort4 o;
            unsigned short* op = (unsigned short*)&o;
#pragma unroll
            for (int r = 0; r < 4; ++r) {
                float a = acc[i][j][r] + bias;
                float sp = (a > 20.f) ? a
                         : 0.6931471805599453f * LOG2F(1.f + EXP2F(a * 1.44269504088896f));
                op[r] = f2b(sp);
            }
            *(ushort4*)&T[nn * TP_STRIDE + mm] = o;
        }
    }
    __syncthreads();
    int bI = m0 >> 9;
    int tglob = m0 & (LSEQ - 1);
#pragma unroll
    for (int it = 0; it < 8; ++it) {
        int c  = tid + it * 256;
        int nn = c >> 4;
        int tc = c & 15;
        uint4 v = *(const uint4*)&T[nn * TP_STRIDE + tc * 8];
        *(uint4*)(dtT + ((size_t)bI * DINNER + n0 + nn) * LSEQ + tglob + tc * 8) = v;
    }
}

// ============ Kernel G1: scan phase 1 — u/dt/B staged in LDS; 5 chunks ============
// c<4: 104-step chunks over [0,416) -> ab.  c==4: 48-step chunk [416,464) -> ab2.
#define P1S 112
__global__ __launch_bounds__(256) void k_scan_p1(const unsigned short* __restrict__ uT,
                                                 const unsigned short* __restrict__ dtT,
                                                 const float* __restrict__ Bt2,
                                                 const float* __restrict__ A_log,
                                                 float2* __restrict__ ab,
                                                 float2* __restrict__ ab2) {
    __shared__ unsigned short uL[64 * P1S];
    __shared__ unsigned short dL[64 * P1S];
    __shared__ float BL[CHUNKT * DSTATE];
    int b = blockIdx.y;
    int c = blockIdx.z;
    int tid  = threadIdx.x;
    int lane = tid & 63;
    int w    = tid >> 6;
    int q    = lane & 3;
    int dloc = lane >> 2;
    int d0   = blockIdx.x * 64;
    int d    = d0 + w * 16 + dloc;
    int tbeg = (c < 4) ? c * CHUNKT : TSTART;
    int tlen = (c < 4) ? CHUNKT : 48;
    int nch8 = tlen >> 3;
    for (int i = tid; i < 64 * nch8; i += 256) {
        int row = i / nch8;
        int col = i - row * nch8;
        *(uint4*)&uL[row * P1S + col * 8] =
            *(const uint4*)(uT + ((size_t)b * DINNER + d0 + row) * LSEQ + tbeg + col * 8);
        *(uint4*)&dL[row * P1S + col * 8] =
            *(const uint4*)(dtT + ((size_t)b * DINNER + d0 + row) * LSEQ + tbeg + col * 8);
    }
    for (int i = tid; i < tlen * 4; i += 256)
        ((float4*)BL)[i] = *((const float4*)(Bt2 + ((size_t)b * LSEQ + tbeg) * DSTATE) + i);
    float4 al = *(const float4*)(A_log + (size_t)d * DSTATE + q * 4);
    float As2[4];
    As2[0] = -__expf(al.x) * 1.44269504088896f;
    As2[1] = -__expf(al.y) * 1.44269504088896f;
    As2[2] = -__expf(al.z) * 1.44269504088896f;
    As2[3] = -__expf(al.w) * 1.44269504088896f;
    float beta[4] = {0.f, 0.f, 0.f, 0.f};
    float asum = 0.f;
    const unsigned short* upL = uL + (w * 16 + dloc) * P1S;
    const unsigned short* dpL = dL + (w * 16 + dloc) * P1S;
    __syncthreads();
    for (int t8 = 0; t8 < tlen; t8 += 8) {
        uint4 uq = *(const uint4*)(upL + t8);
        uint4 dq = *(const uint4*)(dpL + t8);
        float4 Bq[8];
#pragma unroll
        for (int j = 0; j < 8; ++j)
            Bq[j] = *(const float4*)&BL[(t8 + j) * DSTATE + q * 4];
        float uu[8], dd[8];
        const unsigned* uqp = (const unsigned*)&uq;
        const unsigned* dqp = (const unsigned*)&dq;
#pragma unroll
        for (int p = 0; p < 4; ++p) {
            uu[p * 2] = blo(uqp[p]); uu[p * 2 + 1] = bhi(uqp[p]);
            dd[p * 2] = blo(dqp[p]); dd[p * 2 + 1] = bhi(dqp[p]);
        }
        float S[8];
        S[0] = dd[0];
#pragma unroll
        for (int j = 1; j < 8; ++j) S[j] = S[j - 1] + dd[j];
        float G = S[7];
        float g0 = 0.f, g1 = 0.f, g2 = 0.f, g3 = 0.f;
#pragma unroll
        for (int j = 0; j < 8; ++j) {
            float w8 = dd[j] * uu[j];
            float p8 = G - S[j];
            g0 += EXP2F(As2[0] * p8) * (w8 * Bq[j].x);
            g1 += EXP2F(As2[1] * p8) * (w8 * Bq[j].y);
            g2 += EXP2F(As2[2] * p8) * (w8 * Bq[j].z);
            g3 += EXP2F(As2[3] * p8) * (w8 * Bq[j].w);
        }
        beta[0] = EXP2F(As2[0] * G) * beta[0] + g0;
        beta[1] = EXP2F(As2[1] * G) * beta[1] + g1;
        beta[2] = EXP2F(As2[2] * G) * beta[2] + g2;
        beta[3] = EXP2F(As2[3] * G) * beta[3] + g3;
        asum += G;
    }
    if (c < 4) {
        float2* abp = ab + ((size_t)(b * DINNER + d) * NCHUNK + c) * DSTATE + q * 4;
#pragma unroll
        for (int si = 0; si < 4; ++si)
            abp[si] = make_float2(EXP2F(asum * As2[si]), beta[si]);
    } else {
        float2* abp = ab2 + (size_t)(b * DINNER + d) * DSTATE + q * 4;
#pragma unroll
        for (int si = 0; si < 4; ++si)
            abp[si] = make_float2(EXP2F(asum * As2[si]), beta[si]);
    }
}

// ============ Kernel G2: two 48-step output halves; LDS B/C; block-reduce + atomic ============
__global__ __launch_bounds__(256) void k_scan_p3(const unsigned short* __restrict__ uT,
                                                 const unsigned short* __restrict__ dtT,
                                                 const float* __restrict__ Bt2,
                                                 const float* __restrict__ Ct2,
                                                 const float* __restrict__ A_log,
                                                 const float* __restrict__ gsT,
                                                 const unsigned short* __restrict__ c0,
                                                 const float2* __restrict__ ab,
                                                 const float2* __restrict__ ab2,
                                                 float* __restrict__ oacc) {
    __shared__ float BsL[48 * DSTATE];          // 3 KB
    __shared__ float CsL[48 * DSTATE];          // 3 KB
    __shared__ float accL[16][52];              // 3.3 KB
    int b    = blockIdx.y;
    int zh   = blockIdx.z;                      // 0: [416,464), 1: [464,512)
    int tid  = threadIdx.x;
    int s    = tid & 15;
    int dloc = (tid >> 4) & 3;
    int w    = tid >> 6;
    int d    = blockIdx.x * 16 + (tid >> 4);
    int tb   = TSTART + zh * 48;
    for (int i = tid; i < (48 * DSTATE) / 4; i += 256) {
        ((float4*)BsL)[i] = *((const float4*)(Bt2 + ((size_t)b * LSEQ + tb) * DSTATE) + i);
        ((float4*)CsL)[i] = *((const float4*)(Ct2 + ((size_t)b * LSEQ + tb) * DSTATE) + i);
    }
    float As2 = -__expf(A_log[(size_t)d * DSTATE + s]) * 1.44269504088896f;
    const float2* abp = ab + (size_t)(b * DINNER + d) * NCHUNK * DSTATE + s;
    float h = 0.f;
#pragma unroll
    for (int c = 0; c < NCHUNK; ++c) {
        float2 v = abp[c * DSTATE];
        h = v.y + v.x * h;
    }
    if (zh == 1) {
        float2 v4 = ab2[(size_t)(b * DINNER + d) * DSTATE + s];
        h = v4.y + v4.x * h;
    }
    const unsigned short* up = uT  + ((size_t)b * DINNER + d) * LSEQ;
    const unsigned short* dp = dtT + ((size_t)b * DINNER + d) * LSEQ;
    const float* gp = gsT + ((size_t)b * DINNER + d) * PREDLEN;
    const unsigned short* cp0 = c0 + ((size_t)b * DINNER + d) * PREDLEN;
    __syncthreads();
    for (int t8 = tb; t8 < tb + 48; t8 += 8) {
        int tl0  = t8 - TSTART;   // global output index
        int tloc = t8 - tb;       // LDS index
        uint4 uq = *(const uint4*)(up + t8);
        uint4 dq = *(const uint4*)(dp + t8);
        float4 g0 = *(const float4*)(gp + tl0);
        float4 g1 = *(const float4*)(gp + tl0 + 4);
        uint4 cq = *(const uint4*)(cp0 + tl0);
        float Bv[8], Cv[8];
#pragma unroll
        for (int j = 0; j < 8; ++j) {
            Bv[j] = BsL[(tloc + j) * DSTATE + s];
            Cv[j] = CsL[(tloc + j) * DSTATE + s];
        }
        float uu[8], dd[8];
        const unsigned* uqp = (const unsigned*)&uq;
        const unsigned* dqp = (const unsigned*)&dq;
#pragma unroll
        for (int p = 0; p < 4; ++p) {
            uu[p * 2] = blo(uqp[p]); uu[p * 2 + 1] = bhi(uqp[p]);
            dd[p * 2] = blo(dqp[p]); dd[p * 2 + 1] = bhi(dqp[p]);
        }
        float y[8];
#pragma unroll
        for (int j = 0; j < 8; ++j) {
            h = EXP2F(dd[j] * As2) * h + (dd[j] * uu[j]) * Bv[j];
            y[j] = h * Cv[j];
        }
#pragma unroll
        for (int j = 0; j < 8; ++j) y[j] += __shfl_xor(y[j], 1);
#pragma unroll
        for (int j = 0; j < 8; ++j) y[j] += __shfl_xor(y[j], 2);
#pragma unroll
        for (int j = 0; j < 8; ++j) y[j] += __shfl_xor(y[j], 4);
#pragma unroll
        for (int j = 0; j < 8; ++j) y[j] += __shfl_xor(y[j], 8);
        float gv[8] = {g0.x, g0.y, g0.z, g0.w, g1.x, g1.y, g1.z, g1.w};
        const unsigned* cqp = (const unsigned*)&cq;
#pragma unroll
        for (int j = 0; j < 8; ++j) {
            float cf = (j & 1) ? bhi(cqp[j >> 1]) : blo(cqp[j >> 1]);
            float z  = y[j] * gv[j] + cf;
            if (s == 0) accL[w * 4 + dloc][tloc + j] = z;
        }
    }
    __syncthreads();
    if (tid < 48) {
        float tot = 0.f;
#pragma unroll
        for (int k = 0; k < 16; ++k) tot += accL[k][tid];
        atomicAdd(&oacc[b * PREDLEN + zh * 48 + tid], tot);
    }
}

// ============ Kernel H: scale accumulated outputs + de-normalize ============
__global__ __launch_bounds__(256) void k_final3(const float* __restrict__ oacc,
                                                const float* __restrict__ meanv,
                                                const float* __restrict__ stdv,
                                                float* __restrict__ out) {
    int idx = blockIdx.x * 256 + threadIdx.x;
    int b = idx / PREDLEN;
    out[idx] = oacc[idx] * stdv[b * ENC_IN] + meanv[b * ENC_IN];
}

// ---------------- launch ----------------
extern "C" void kernel_launch(void* const* d_in, const int* in_sizes, int n_in,
                              void* d_out, int out_size, void* d_ws, size_t ws_size,
                              hipStream_t stream) {
    const float* x_enc     = (const float*)d_in[0];
    const float* x_mark    = (const float*)d_in[1];
    const float* conv_w    = (const float*)d_in[2];
    const float* temp_w    = (const float*)d_in[3];
    const float* in_proj_w = (const float*)d_in[4];
    const float* conv1d_w  = (const float*)d_in[5];
    const float* conv1d_b  = (const float*)d_in[6];
    const float* x_proj_w  = (const float*)d_in[7];
    const float* dt_proj_w = (const float*)d_in[8];
    const float* dt_proj_b = (const float*)d_in[9];
    const float* A_log     = (const float*)d_in[10];
    const float* Dvec      = (const float*)d_in[11];
    const float* out_proj_w= (const float*)d_in[12];
    const float* out_w     = (const float*)d_in[13];
    float* ws  = (float*)d_ws;
    float* out = (float*)d_out;

    float* xn    = ws + OFF_XN;
    float* meanv = ws + OFF_MEAN;
    float* stdv  = ws + OFF_STD;
    float* wfv   = ws + OFF_WF;
    float* wfp   = ws + OFF_WFP;
    float* oacc  = ws + OFF_OACC;
    float* Btv   = ws + OFF_BT;
    float* Ctv   = ws + OFF_CT;
    float* gsT   = ws + OFF_GST;
    unsigned short* xb    = (unsigned short*)(ws + OFF_XB);
    unsigned short* wb    = (unsigned short*)(ws + OFF_WB);
    unsigned short* wbx   = (unsigned short*)(ws + OFF_WBX);
    unsigned short* dpwb  = (unsigned short*)(ws + OFF_DPWB);
    unsigned short* dtinb = (unsigned short*)(ws + OFF_DTIN);
    unsigned short* xiT   = (unsigned short*)(ws + OFF_XIT);
    unsigned short* uT    = (unsigned short*)(ws + OFF_UT);
    unsigned short* dtT   = (unsigned short*)(ws + OFF_DTT);
    unsigned short* c0    = (unsigned short*)(ws + OFF_C0);
    float2* ab  = (float2*)(ws + OFF_AB);
    float2* ab2 = (float2*)(ws + OFF_AB2);

    k_front<<<dim3(1201), 256, 0, stream>>>(out_proj_w, out_w, in_proj_w, x_proj_w, dt_proj_w,
                                            x_enc, wfp, wb, wbx, dpwb, xn, meanv, stdv, oacc);
    k_front2<<<dim3(32772), 256, 0, stream>>>(xn, x_mark, conv_w, temp_w, wfp, xb, wfv);
    k_gemm_xi<<<dim3(4, 64), 512, 0, stream>>>(xb, wb, xiT);
    k_gemm_z<<<dim3(8, 32), 256, 0, stream>>>(xb, wb, gsT);
    k_dwconv_silu<<<dim3(DINNER / 4, BATCH), 256, 0, stream>>>(xiT, conv1d_w, conv1d_b,
                                                               wfv, Dvec, gsT, c0, uT);
    k_gemm_xproj2<<<dim3(MROWS / 64), 256, 0, stream>>>(uT, wbx, dtinb, Btv, Ctv);
    k_dtproj2<<<dim3(8, 128), 256, 0, stream>>>(dtinb, dpwb, dt_proj_b, dtT);
    k_scan_p1<<<dim3(DINNER / 64, BATCH, 5), 256, 0, stream>>>(uT, dtT, Btv, A_log, ab, ab2);
    k_scan_p3<<<dim3(DINNER / 16, BATCH, 2), 256, 0, stream>>>(uT, dtT, Btv, Ctv, A_log,
                                                               gsT, c0, ab, ab2, oacc);
    k_final3<<<dim3((BATCH * PREDLEN) / 256), 256, 0, stream>>>(oacc, meanv, stdv, out);
}